// Round 3
// baseline (37152.475 us; speedup 1.0000x reference)
//
#include <hip/hip_runtime.h>
#include <stdint.h>
#include <math.h>

typedef unsigned int uint;
typedef unsigned long long ull;

#define BATCH 2
#define ATOTAL 242991
#define KSEL 4741
#define NW 75
#define POST_NMS 1000

// level constants (host + compile-time device use)
constexpr int cH[5]       = {200,100,50,25,13};
constexpr int cW[5]       = {304,152,76,38,19};
constexpr int cStrideL[5] = {4,8,16,32,64};
constexpr int cSizeL[5]   = {32,64,128,256,512};
constexpr int cLoff[5]    = {0,182400,228000,239400,242250};
constexpr int cCount[5]   = {182400,45600,11400,2850,741};
constexpr int cSeg[5]     = {0,1000,2000,3000,4000};
constexpr int cSegK[5]    = {1000,1000,1000,1000,741};

// runtime-indexed device copies
__device__ __constant__ int dLoff[5]  = {0,182400,228000,239400,242250};
__device__ __constant__ int dCount[5] = {182400,45600,11400,2850,741};
__device__ __constant__ int dSeg[5]   = {0,1000,2000,3000,4000};
__device__ __constant__ int dSegK[5]  = {1000,1000,1000,1000,741};

__device__ __forceinline__ uint fkey(float f) {
    uint u = __float_as_uint(f);
    return (u & 0x80000000u) ? ~u : (u | 0x80000000u);
}

// ---------------- weight relayout: conv_w [O=256][K=2304] -> wT2 [ocg2][K][128] ----------------
__global__ __launch_bounds__(256) void wt_kernel(const float* __restrict__ conv_w,
                                                 float* __restrict__ wT2) {
    int t = blockIdx.x * 256 + threadIdx.x;
    if (t < 2304 * 256) {
        int ocp = t / 2304;           // 0..255
        int k   = t - ocp * 2304;     // lane-consecutive -> coalesced read
        int ocg = ocp >> 7, ocl = ocp & 127;
        wT2[((size_t)ocg * 2304 + k) * 128 + ocl] = conv_w[(size_t)ocp * 2304 + k];
    }
}

// ---------------- fused conv3x3+relu + 1x1 heads (f64) + decode (f64) + clip ----------------
// tile: 8 rows x 16 cols = 128 px. 256 threads: og=tid>>4 (16 oc-groups of 8),
// ty=(tid>>2)&3 (2 rows each), tx=tid&3 (4 cols each). K-chunk = 4 ic, reg-prefetched.
template <int LVL>
__global__ __launch_bounds__(256, 3) void conv_fused(
    const float* __restrict__ feat, const float* __restrict__ wT2,
    const float* __restrict__ conv_b,
    const float* __restrict__ cls_w, const float* __restrict__ cls_b,
    const float* __restrict__ box_w, const float* __restrict__ box_b,
    float* __restrict__ scoresA, float* __restrict__ boxesA)
{
    constexpr int H = cH[LVL], W = cW[LVL];
    constexpr int STRIDE = cStrideL[LVL], SZ = cSizeL[LVL], LOFF = cLoff[LVL];
    constexpr int TILESX = (W + 15) / 16;

    const int tile = blockIdx.x;
    const int b    = blockIdx.y;
    const int ty0  = (tile / TILESX) * 8;
    const int tx0  = (tile % TILESX) * 16;
    const int tid  = threadIdx.x;

    __shared__ float hwS[256 * 16];                 // [oc][16 heads] 16 KiB
    __shared__ __align__(16) char uni[32768];       // union region
    float*  inS   = (float*)uni;                    // [4ic][10][20]  (3200 B)
    float*  wS    = (float*)(uni + 3200);           // [36k][128oc]   (18432 B)
    float*  tS    = (float*)uni;                    // [128px][64oc]  (32768 B, swizzled)
    double* houtD = (double*)uni;                   // [128px][16]    (16384 B)

    // stage head weights once
    for (int e = tid; e < 256 * 16; e += 256) {
        int oc = e >> 4, h = e & 15;
        float v = 0.f;
        if (h < 3)        v = cls_w[h * 256 + oc];
        else if (h < 15)  v = box_w[(h - 3) * 256 + oc];
        hwS[e] = v;
    }

    const int og  = tid >> 4;        // 0..15 oc-group (8 oc)
    const int ty  = (tid >> 2) & 3;  // 0..3 (2 rows each)
    const int tx  = tid & 3;         // 0..3 (4 cols each)
    const int ty2 = ty * 2;
    const int tx4 = tx * 4;
    const int og8 = og * 8;

    const float* fb = feat + (size_t)b * 256 * H * W;

    // precompute input staging coords (constant across chunks)
    int  ioff[3]; int idst[3]; bool ival[3];
#pragma unroll
    for (int j = 0; j < 3; ++j) {
        int e = tid + j * 256;
        ival[j] = false; ioff[j] = 0; idst[j] = -1;
        if (e < 720) {
            int ic = e / 180, rem = e - ic * 180;
            int row = rem / 18, col = rem - row * 18;
            int gy = ty0 + row - 1, gx = tx0 + col - 1;
            idst[j] = (ic * 10 + row) * 20 + col;
            if (gy >= 0 && gy < H && gx >= 0 && gx < W) {
                ival[j] = true; ioff[j] = (ic * H + gy) * W + gx;
            }
        }
    }

    double hacc[8] = {0,0,0,0,0,0,0,0};   // per-thread f64 head accumulators

    float4 wreg[5];
    float  ireg[3];

    for (int ocg = 0; ocg < 2; ++ocg) {
        const float* wTg = wT2 + (size_t)ocg * 2304 * 128;

        float acc[2][4][8];
#pragma unroll
        for (int rr = 0; rr < 2; ++rr)
#pragma unroll
            for (int cc = 0; cc < 4; ++cc)
#pragma unroll
                for (int oo = 0; oo < 8; ++oo) acc[rr][cc][oo] = 0.f;

        // ---- K loop: 64 chunks of 4 ic (36 k) ----
        // prologue: load chunk 0
        {
            const float* wb = wTg;
#pragma unroll
            for (int j = 0; j < 4; ++j) wreg[j] = *(const float4*)(wb + (size_t)(tid + j*256) * 4);
            wreg[4] = (tid < 128) ? *(const float4*)(wb + (size_t)(1024 + tid) * 4)
                                  : make_float4(0.f,0.f,0.f,0.f);
#pragma unroll
            for (int j = 0; j < 3; ++j) ireg[j] = ival[j] ? fb[ioff[j]] : 0.f;
        }
        __syncthreads();   // previous phase's LDS reads (tS/houtD) complete
        {
#pragma unroll
            for (int j = 0; j < 4; ++j) *(float4*)(wS + (tid + j*256)*4) = wreg[j];
            if (tid < 128) *(float4*)(wS + (1024 + tid)*4) = wreg[4];
#pragma unroll
            for (int j = 0; j < 3; ++j) if (idst[j] >= 0) inS[idst[j]] = ireg[j];
        }
        __syncthreads();   // chunk 0 ready

        for (int c = 0; c < 64; ++c) {
            // prefetch chunk c+1 into registers (latency hides under compute)
            if (c + 1 < 64) {
                const float* wb = wTg + (size_t)(c + 1) * 36 * 128;
                const float* fc = fb + (size_t)(c + 1) * 4 * H * W;
#pragma unroll
                for (int j = 0; j < 4; ++j) wreg[j] = *(const float4*)(wb + (size_t)(tid + j*256) * 4);
                if (tid < 128) wreg[4] = *(const float4*)(wb + (size_t)(1024 + tid) * 4);
#pragma unroll
                for (int j = 0; j < 3; ++j) ireg[j] = ival[j] ? fc[ioff[j]] : 0.f;
            }
            // compute current chunk
#pragma unroll
            for (int ic = 0; ic < 4; ++ic) {
#pragma unroll
                for (int dy = 0; dy < 3; ++dy) {
                    const float* ip0 = &inS[((ic * 10) + ty2 + dy) * 20 + tx4];
                    float4 a0 = *(const float4*)ip0;
                    float2 b0 = *(const float2*)(ip0 + 4);
                    float4 a1 = *(const float4*)(ip0 + 20);
                    float2 b1 = *(const float2*)(ip0 + 24);
                    float i0[6] = {a0.x, a0.y, a0.z, a0.w, b0.x, b0.y};
                    float i1[6] = {a1.x, a1.y, a1.z, a1.w, b1.x, b1.y};
                    const int kb = (ic * 9 + dy * 3) * 128 + og8;
#pragma unroll
                    for (int dx = 0; dx < 3; ++dx) {
                        float4 w0 = *(const float4*)&wS[kb + dx * 128];
                        float4 w1 = *(const float4*)&wS[kb + dx * 128 + 4];
                        float wv[8] = {w0.x,w0.y,w0.z,w0.w,w1.x,w1.y,w1.z,w1.w};
#pragma unroll
                        for (int cc = 0; cc < 4; ++cc) {
                            float v0 = i0[cc + dx];
                            float v1 = i1[cc + dx];
#pragma unroll
                            for (int oo = 0; oo < 8; ++oo) {
                                acc[0][cc][oo] = fmaf(v0, wv[oo], acc[0][cc][oo]);
                                acc[1][cc][oo] = fmaf(v1, wv[oo], acc[1][cc][oo]);
                            }
                        }
                    }
                }
            }
            __syncthreads();   // all LDS reads of this chunk done
            if (c + 1 < 64) {
#pragma unroll
                for (int j = 0; j < 4; ++j) *(float4*)(wS + (tid + j*256)*4) = wreg[j];
                if (tid < 128) *(float4*)(wS + (1024 + tid)*4) = wreg[4];
#pragma unroll
                for (int j = 0; j < 3; ++j) if (idst[j] >= 0) inS[idst[j]] = ireg[j];
                __syncthreads();   // next chunk ready
            }
        }

        // ---- head contraction, 2 substeps of 64 oc (oc ascending), f64 ----
        float4 cb0 = *(const float4*)&conv_b[ocg * 128 + og8];
        float4 cb1 = *(const float4*)&conv_b[ocg * 128 + og8 + 4];
        float cbv[8] = {cb0.x,cb0.y,cb0.z,cb0.w,cb1.x,cb1.y,cb1.z,cb1.w};

        for (int s = 0; s < 2; ++s) {
            // writers: og>>3 == s  (oc_local s*64 .. s*64+63)
            if ((og >> 3) == s) {
                const int g0 = (og & 7) * 2;
#pragma unroll
                for (int rr = 0; rr < 2; ++rr)
#pragma unroll
                    for (int cc = 0; cc < 4; ++cc) {
                        int px = (ty2 + rr) * 16 + tx4 + cc;
                        int sw = px & 15;
                        float4 t0, t1;
                        t0.x = fmaxf(acc[rr][cc][0] + cbv[0], 0.f);
                        t0.y = fmaxf(acc[rr][cc][1] + cbv[1], 0.f);
                        t0.z = fmaxf(acc[rr][cc][2] + cbv[2], 0.f);
                        t0.w = fmaxf(acc[rr][cc][3] + cbv[3], 0.f);
                        t1.x = fmaxf(acc[rr][cc][4] + cbv[4], 0.f);
                        t1.y = fmaxf(acc[rr][cc][5] + cbv[5], 0.f);
                        t1.z = fmaxf(acc[rr][cc][6] + cbv[6], 0.f);
                        t1.w = fmaxf(acc[rr][cc][7] + cbv[7], 0.f);
                        *(float4*)&tS[px * 64 + ((g0    ) ^ sw) * 4] = t0;
                        *(float4*)&tS[px * 64 + ((g0 + 1) ^ sw) * 4] = t1;
                    }
            }
            __syncthreads();
            // accumulate: px = tid&127, head-half = tid>>7
            {
                const int px = tid & 127;
                const int hh = tid >> 7;
                const int sw = px & 15;
                const int ocb = ocg * 128 + s * 64;
#pragma unroll
                for (int j4 = 0; j4 < 16; ++j4) {
                    float4 t4 = *(const float4*)&tS[px * 64 + (j4 ^ sw) * 4];
                    float tv[4] = {t4.x, t4.y, t4.z, t4.w};
#pragma unroll
                    for (int jj = 0; jj < 4; ++jj) {
                        const float* hb = &hwS[(ocb + j4 * 4 + jj) * 16 + hh * 8];
                        float4 h0 = *(const float4*)hb;
                        float4 h1 = *(const float4*)(hb + 4);
                        double tv_d = (double)tv[jj];
                        hacc[0] += tv_d * (double)h0.x;
                        hacc[1] += tv_d * (double)h0.y;
                        hacc[2] += tv_d * (double)h0.z;
                        hacc[3] += tv_d * (double)h0.w;
                        hacc[4] += tv_d * (double)h1.x;
                        hacc[5] += tv_d * (double)h1.y;
                        hacc[6] += tv_d * (double)h1.z;
                        hacc[7] += tv_d * (double)h1.w;
                    }
                }
            }
            __syncthreads();
        }
    }

    // ---- write head outputs to LDS (f64) ----
    {
        const int px = tid & 127;
        const int hh = tid >> 7;
#pragma unroll
        for (int j = 0; j < 8; ++j) houtD[px * 16 + hh * 8 + j] = hacc[j];
    }
    __syncthreads();

    // ---- decode + clip in f64, store f32 ----
    if (tid < 128) {
        const int px = tid;
        const int gy = ty0 + (px >> 4);
        const int gx = tx0 + (px & 15);
        if (gy < H && gx < W) {
#pragma unroll
            for (int a = 0; a < 3; ++a) {
                double score = houtD[px * 16 + a] + (double)cls_b[a];
                double rg0 = houtD[px * 16 + 3 + a * 4 + 0] + (double)box_b[a * 4 + 0];
                double rg1 = houtD[px * 16 + 3 + a * 4 + 1] + (double)box_b[a * 4 + 1];
                double rg2 = houtD[px * 16 + 3 + a * 4 + 2] + (double)box_b[a * 4 + 2];
                double rg3 = houtD[px * 16 + 3 + a * 4 + 3] + (double)box_b[a * 4 + 3];
                double ratio = (a == 0) ? 0.5 : ((a == 1) ? 1.0 : 2.0);
                double hr = sqrt(ratio), wr = 1.0 / hr;
                double wsd = wr * (double)SZ, hsd = hr * (double)SZ;
                double sx = (double)(gx * STRIDE), sy = (double)(gy * STRIDE);
                float ax0 = (float)(sx - 0.5 * wsd);
                float ay0 = (float)(sy - 0.5 * hsd);
                float ax1 = (float)(sx + 0.5 * wsd);
                float ay1 = (float)(sy + 0.5 * hsd);
                double wa = (double)ax1 - (double)ax0, ha = (double)ay1 - (double)ay0;
                double cxa = (double)ax0 + 0.5 * wa, cya = (double)ay0 + 0.5 * ha;
                double dwv = fmin(rg2, 4.135166556742356);
                double dhv = fmin(rg3, 4.135166556742356);
                double cx = rg0 * wa + cxa, cy = rg1 * ha + cya;
                double w = exp(dwv) * wa, h = exp(dhv) * ha;
                double x0 = cx - 0.5 * w, y0 = cy - 0.5 * h;
                double x1 = cx + 0.5 * w, y1 = cy + 0.5 * h;
                x0 = fmin(fmax(x0, 0.0), 1216.0);
                y0 = fmin(fmax(y0, 0.0), 800.0);
                x1 = fmin(fmax(x1, 0.0), 1216.0);
                y1 = fmin(fmax(y1, 0.0), 800.0);
                int gidx = LOFF + (gy * W + gx) * 3 + a;
                scoresA[(size_t)b * ATOTAL + gidx] = (float)score;
                float4 bx = make_float4((float)x0, (float)y0, (float)x1, (float)y1);
                *(float4*)&boxesA[((size_t)b * ATOTAL + gidx) * 4] = bx;
            }
        }
    }
}

// ---------------- per-(batch,level) top-k via 3-pass radix threshold ----------------
__global__ __launch_bounds__(256) void topk_kernel(
    const float* __restrict__ scoresA, const float* __restrict__ boxesA,
    float* __restrict__ selScore, float* __restrict__ selBox,
    int* __restrict__ selValid, int* __restrict__ selAnchor)
{
    const int lvl = blockIdx.x, b = blockIdx.y;
    const int n = dCount[lvl], loff = dLoff[lvl], seg = dSeg[lvl], k = dSegK[lvl];
    const float* sc = scoresA + (size_t)b * ATOTAL + loff;
    const int tid = threadIdx.x;

    float* oS = selScore + b * KSEL;
    float* oB = selBox + (size_t)b * KSEL * 4;
    int* oV = selValid + b * KSEL;
    int* oA = selAnchor + b * KSEL;

    auto emit = [&](int slot, int i) {
        int g = loff + i;
        float s = sc[i];
        float4 bx = *(const float4*)&boxesA[((size_t)b * ATOTAL + g) * 4];
        oS[seg + slot] = s;
        *(float4*)&oB[(size_t)(seg + slot) * 4] = bx;
        oV[seg + slot] = ((bx.z - bx.x) >= 1e-3f && (bx.w - bx.y) >= 1e-3f) ? 1 : 0;
        oA[seg + slot] = g;
    };

    if (n <= k) {
        for (int i = tid; i < n; i += 256) emit(i, i);
        return;
    }

    __shared__ uint hist[2048];
    __shared__ uint sh_bin, sh_krem;
    __shared__ uint cntG, cntE;
    __shared__ int stash[64];

    uint krem = (uint)k;
    uint prefix = 0;
    for (int pass = 0; pass < 3; ++pass) {
        for (int e = tid; e < 2048; e += 256) hist[e] = 0;
        __syncthreads();
        for (int i = tid; i < n; i += 256) {
            uint key = fkey(sc[i]);
            uint bin; bool sel;
            if (pass == 0)      { sel = true;                      bin = key >> 21; }
            else if (pass == 1) { sel = ((key >> 21) == prefix);   bin = (key >> 10) & 0x7FFu; }
            else                { sel = ((key >> 10) == prefix);   bin = key & 0x3FFu; }
            if (sel) atomicAdd(&hist[bin], 1u);
        }
        __syncthreads();
        if (tid == 0) {
            int nb = (pass == 2) ? 1024 : 2048;
            uint c = 0;
            for (int x = nb - 1; x >= 0; --x) {
                uint h = hist[x];
                if (c + h >= krem) { sh_bin = (uint)x; sh_krem = krem - c; break; }
                c += h;
            }
        }
        __syncthreads();
        uint bin = sh_bin; krem = sh_krem;
        if (pass == 0)      prefix = bin;
        else if (pass == 1) prefix = (prefix << 11) | bin;
        else                prefix = (prefix << 10) | bin;
        __syncthreads();
    }
    const uint T = prefix;
    const uint need_eq = krem;
    if (tid == 0) { cntG = 0; cntE = 0; }
    __syncthreads();
    for (int i = tid; i < n; i += 256) {
        uint key = fkey(sc[i]);
        if (key > T) {
            uint pos = atomicAdd(&cntG, 1u);
            emit((int)pos, i);
        } else if (key == T) {
            uint e = atomicAdd(&cntE, 1u);
            if (e < 64) stash[e] = i;
        }
    }
    __syncthreads();
    if (tid == 0) {
        uint ne = cntE < 64u ? cntE : 64u;
        uint base = cntG;   // == k - need_eq
        for (uint t2 = 0; t2 < need_eq; ++t2) {
            int best = -1, bj = -1;
            for (uint j2 = 0; j2 < ne; ++j2) {
                int v = stash[j2];
                if (v >= 0 && (best < 0 || v < best)) { best = v; bj = j2; }
            }
            if (bj >= 0) { stash[bj] = -1; emit((int)(base + t2), best); }
            else emit((int)(base + t2), 0);   // pathological fallback, never expected
        }
    }
}

// ---------------- per-batch descending sort (score, then anchor-idx asc) ----------------
__global__ __launch_bounds__(1024) void sort_kernel(
    const float* __restrict__ selScore, const float* __restrict__ selBox,
    const int* __restrict__ selValid, const int* __restrict__ selAnchor,
    int* __restrict__ sortedSlot, float* __restrict__ sortedBoxOff,
    ull* __restrict__ validMask)
{
    const int b = blockIdx.x, tid = threadIdx.x;
    __shared__ ull  skey[8192];
    __shared__ uint spay[8192];
    __shared__ ull  svm[NW];

    for (int i = tid; i < 8192; i += 1024) {
        ull kk2; uint pp;
        if (i < KSEL) {
            float s = selScore[b * KSEL + i];
            int v = selValid[b * KSEL + i];
            uint k32 = v ? fkey(s) : 0x007FFFFFu;   // invalid => key(-inf)
            uint a32 = 0xFFFFFFFFu - (uint)selAnchor[b * KSEL + i];
            kk2 = ((ull)k32 << 32) | a32; pp = (uint)i;
        } else { kk2 = 0ull; pp = 0xFFFFFFFFu; }
        skey[i] = kk2; spay[i] = pp;
    }
    __syncthreads();
    for (uint kk = 2; kk <= 8192; kk <<= 1) {
        for (uint j = kk >> 1; j > 0; j >>= 1) {
            for (int i = tid; i < 8192; i += 1024) {
                uint ixj = (uint)i ^ j;
                if (ixj > (uint)i) {
                    bool up = ((((uint)i) & kk) == 0);
                    ull a = skey[i], c = skey[ixj];
                    bool sw = up ? (a < c) : (a > c);   // flipped comparators -> descending
                    if (sw) {
                        skey[i] = c; skey[ixj] = a;
                        uint tp = spay[i]; spay[i] = spay[ixj]; spay[ixj] = tp;
                    }
                }
            }
            __syncthreads();
        }
    }
    for (int i = tid; i < NW; i += 1024) svm[i] = 0ull;
    __syncthreads();
    for (int i = tid; i < KSEL; i += 1024) {
        uint slot = spay[i];
        sortedSlot[b * KSEL + i] = (int)slot;
        int v = selValid[b * KSEL + slot];
        if (v) atomicOr(&svm[i >> 6], 1ull << (i & 63));
        int lvl = (int)slot / 1000;
        float off = 1217.0f * (float)lvl;
        float4 bx = *(const float4*)&selBox[((size_t)b * KSEL + slot) * 4];
        bx.x += off; bx.y += off; bx.z += off; bx.w += off;
        *(float4*)&sortedBoxOff[((size_t)b * KSEL + i) * 4] = bx;
    }
    __syncthreads();
    for (int i = tid; i < NW; i += 1024) validMask[b * NW + i] = svm[i];
}

// ---------------- NMS pairwise suppression bitmask ----------------
__global__ __launch_bounds__(64) void nms_mask(const float* __restrict__ sortedBoxOff,
                                               ull* __restrict__ mat)
{
    const int jb = blockIdx.x, ib = blockIdx.y, b = blockIdx.z;
    const int tid = threadIdx.x;
    __shared__ float4 bj[64];
    __shared__ float  aj[64];
    const int j0 = jb * 64;
    const int jn = (KSEL - j0) < 64 ? (KSEL - j0) : 64;
    if (tid < jn) {
        float4 v = *(const float4*)&sortedBoxOff[((size_t)b * KSEL + j0 + tid) * 4];
        bj[tid] = v; aj[tid] = (v.z - v.x) * (v.w - v.y);
    }
    __syncthreads();
    const int i = ib * 64 + tid;
    if (i >= KSEL) return;
    float4 bi = *(const float4*)&sortedBoxOff[((size_t)b * KSEL + i) * 4];
    float ai = (bi.z - bi.x) * (bi.w - bi.y);
    ull m = 0ull;
    for (int jj = 0; jj < jn; ++jj) {
        int j = j0 + jj;
        if (j <= i) continue;
        float4 bb = bj[jj];
        float ltx = fmaxf(bi.x, bb.x), lty = fmaxf(bi.y, bb.y);
        float rbx = fminf(bi.z, bb.z), rby = fminf(bi.w, bb.w);
        float wx = fmaxf(rbx - ltx, 0.f), wy = fmaxf(rby - lty, 0.f);
        float inter = wx * wy;
        float iou = inter / (ai + aj[jj] - inter + 1e-9f);
        if (iou > 0.7f) m |= (1ull << jj);
    }
    mat[((size_t)b * KSEL + i) * NW + jb] = m;
}

// ---------------- greedy scan (1 wave per batch, register-resident bitset) ----------------
__global__ __launch_bounds__(64) void nms_scan(const ull* __restrict__ mat,
                                               const ull* __restrict__ validMask,
                                               int* __restrict__ keptPos,
                                               int* __restrict__ nkOut)
{
    const int b = blockIdx.x, lane = threadIdx.x;
    ull v0 = validMask[b * NW + lane];
    ull v1 = (lane < NW - 64) ? validMask[b * NW + 64 + lane] : 0ull;
    ull s0 = 0ull, s1 = 0ull;
    int nk = 0;
    const ull* mb = mat + (size_t)b * KSEL * NW;
    const int NG = (KSEL + 7) / 8;
    for (int g = 0; g < NG; ++g) {
        ull rA[8], rB[8];
#pragma unroll
        for (int d = 0; d < 8; ++d) {
            int i = g * 8 + d;
            if (i < KSEL) {
                rA[d] = mb[(size_t)i * NW + lane];
                rB[d] = (lane < NW - 64) ? mb[(size_t)i * NW + 64 + lane] : 0ull;
            } else { rA[d] = 0ull; rB[d] = 0ull; }
        }
#pragma unroll
        for (int d = 0; d < 8; ++d) {
            int i = g * 8 + d;
            if (i >= KSEL) break;
            int wi = i >> 6;
            ull a0 = v0 & ~s0, a1 = v1 & ~s1;
            ull aw = (wi < 64) ? __shfl(a0, wi, 64) : __shfl(a1, wi - 64, 64);
            if ((aw >> (i & 63)) & 1ull) {
                s0 |= rA[d]; s1 |= rB[d];
                if (lane == 0) keptPos[b * POST_NMS + nk] = i;
                ++nk;
                if (nk == POST_NMS) { if (lane == 0) nkOut[b] = nk; return; }
            }
        }
    }
    if (lane == 0) nkOut[b] = nk;
}

// ---------------- final output ----------------
__global__ __launch_bounds__(256) void out_kernel(
    const int* __restrict__ keptPos, const int* __restrict__ nkOut,
    const int* __restrict__ sortedSlot,
    const float* __restrict__ selBox, const float* __restrict__ selScore,
    float* __restrict__ out)
{
    int t = blockIdx.x * 256 + threadIdx.x;
    if (t >= BATCH * POST_NMS) return;
    int b = t / POST_NMS, row = t - b * POST_NMS;
    float4 bx = make_float4(0.f, 0.f, 0.f, 0.f);
    float sc = -1e9f;
    if (row < nkOut[b]) {
        int i = keptPos[b * POST_NMS + row];
        int slot = sortedSlot[b * KSEL + i];
        bx = *(const float4*)&selBox[((size_t)b * KSEL + slot) * 4];
        sc = selScore[b * KSEL + slot];
    }
    *(float4*)&out[(size_t)t * 4] = bx;
    out[BATCH * POST_NMS * 4 + t] = sc;
}

// ---------------- host launch ----------------
extern "C" void kernel_launch(void* const* d_in, const int* in_sizes, int n_in,
                              void* d_out, int out_size, void* d_ws, size_t ws_size,
                              hipStream_t stream)
{
    (void)in_sizes; (void)n_in; (void)out_size; (void)ws_size;
    const float* feat[5] = {(const float*)d_in[0], (const float*)d_in[1],
                            (const float*)d_in[2], (const float*)d_in[3],
                            (const float*)d_in[4]};
    const float* conv_w = (const float*)d_in[5];
    const float* conv_b = (const float*)d_in[6];
    const float* cls_w  = (const float*)d_in[7];
    const float* cls_b  = (const float*)d_in[8];
    const float* box_w  = (const float*)d_in[9];
    const float* box_b  = (const float*)d_in[10];
    float* out = (float*)d_out;

    char* ws = (char*)d_ws;
    size_t off = 0;
    auto carve = [&](size_t bytes) -> void* {
        void* p = (void*)(ws + off);
        off += (bytes + 255) & ~(size_t)255;
        return p;
    };
    float* wT2         = (float*)carve((size_t)2 * 2304 * 128 * 4);
    float* scoresA     = (float*)carve((size_t)BATCH * ATOTAL * 4);
    float* boxesA      = (float*)carve((size_t)BATCH * ATOTAL * 16);
    float* selScore    = (float*)carve((size_t)BATCH * KSEL * 4);
    float* selBox      = (float*)carve((size_t)BATCH * KSEL * 16);
    int*   selValid    = (int*)  carve((size_t)BATCH * KSEL * 4);
    int*   selAnchor   = (int*)  carve((size_t)BATCH * KSEL * 4);
    int*   sortedSlot  = (int*)  carve((size_t)BATCH * KSEL * 4);
    float* sortedBoxOff= (float*)carve((size_t)BATCH * KSEL * 16);
    ull*   validMask   = (ull*)  carve((size_t)BATCH * NW * 8);
    ull*   mat         = (ull*)  carve((size_t)BATCH * KSEL * NW * 8);
    int*   keptPos     = (int*)  carve((size_t)BATCH * POST_NMS * 4);
    int*   nkOut       = (int*)  carve(64);

    wt_kernel<<<2304, 256, 0, stream>>>(conv_w, wT2);

    {
        constexpr int t0 = ((cH[0]+7)/8) * ((cW[0]+15)/16);
        conv_fused<0><<<dim3(t0, BATCH), 256, 0, stream>>>(feat[0], wT2, conv_b, cls_w, cls_b, box_w, box_b, scoresA, boxesA);
    }
    {
        constexpr int t1 = ((cH[1]+7)/8) * ((cW[1]+15)/16);
        conv_fused<1><<<dim3(t1, BATCH), 256, 0, stream>>>(feat[1], wT2, conv_b, cls_w, cls_b, box_w, box_b, scoresA, boxesA);
    }
    {
        constexpr int t2 = ((cH[2]+7)/8) * ((cW[2]+15)/16);
        conv_fused<2><<<dim3(t2, BATCH), 256, 0, stream>>>(feat[2], wT2, conv_b, cls_w, cls_b, box_w, box_b, scoresA, boxesA);
    }
    {
        constexpr int t3 = ((cH[3]+7)/8) * ((cW[3]+15)/16);
        conv_fused<3><<<dim3(t3, BATCH), 256, 0, stream>>>(feat[3], wT2, conv_b, cls_w, cls_b, box_w, box_b, scoresA, boxesA);
    }
    {
        constexpr int t4 = ((cH[4]+7)/8) * ((cW[4]+15)/16);
        conv_fused<4><<<dim3(t4, BATCH), 256, 0, stream>>>(feat[4], wT2, conv_b, cls_w, cls_b, box_w, box_b, scoresA, boxesA);
    }

    topk_kernel<<<dim3(5, BATCH), 256, 0, stream>>>(scoresA, boxesA, selScore, selBox, selValid, selAnchor);
    sort_kernel<<<dim3(BATCH), 1024, 0, stream>>>(selScore, selBox, selValid, selAnchor, sortedSlot, sortedBoxOff, validMask);
    nms_mask<<<dim3(NW, NW, BATCH), 64, 0, stream>>>(sortedBoxOff, mat);
    nms_scan<<<dim3(BATCH), 64, 0, stream>>>(mat, validMask, keptPos, nkOut);
    out_kernel<<<dim3((BATCH * POST_NMS + 255) / 256), 256, 0, stream>>>(keptPos, nkOut, sortedSlot, selBox, selScore, out);
}

// Round 4
// 9961.607 us; speedup vs baseline: 3.7296x; 3.7296x over previous
//
#include <hip/hip_runtime.h>
#include <stdint.h>
#include <math.h>

typedef unsigned int uint;
typedef unsigned long long ull;

#define BATCH 2
#define ATOTAL 242991
#define KSEL 4741
#define NW 75
#define POST_NMS 1000

// level constants (host + compile-time device use)
constexpr int cH[5]       = {200,100,50,25,13};
constexpr int cW[5]       = {304,152,76,38,19};
constexpr int cStrideL[5] = {4,8,16,32,64};
constexpr int cSizeL[5]   = {32,64,128,256,512};
constexpr int cLoff[5]    = {0,182400,228000,239400,242250};
constexpr int cCount[5]   = {182400,45600,11400,2850,741};
constexpr int cSeg[5]     = {0,1000,2000,3000,4000};
constexpr int cSegK[5]    = {1000,1000,1000,1000,741};

// runtime-indexed device copies
__device__ __constant__ int dLoff[5]  = {0,182400,228000,239400,242250};
__device__ __constant__ int dCount[5] = {182400,45600,11400,2850,741};
__device__ __constant__ int dSeg[5]   = {0,1000,2000,3000,4000};
__device__ __constant__ int dSegK[5]  = {1000,1000,1000,1000,741};

__device__ __forceinline__ uint fkey(float f) {
    uint u = __float_as_uint(f);
    return (u & 0x80000000u) ? ~u : (u | 0x80000000u);
}

// ---------------- weight relayout: conv_w [O=256][K=2304] -> wT2 [ocg2][K][128] ----------------
__global__ __launch_bounds__(256) void wt_kernel(const float* __restrict__ conv_w,
                                                 float* __restrict__ wT2) {
    int t = blockIdx.x * 256 + threadIdx.x;
    if (t < 2304 * 256) {
        int ocp = t / 2304;           // 0..255
        int k   = t - ocp * 2304;     // lane-consecutive -> coalesced read
        int ocg = ocp >> 7, ocl = ocp & 127;
        wT2[((size_t)ocg * 2304 + k) * 128 + ocl] = conv_w[(size_t)ocp * 2304 + k];
    }
}

// ---------------- fused conv3x3+relu + 1x1 heads (f64) + decode (f64) + clip ----------------
// tile: 8 rows x 16 cols = 128 px. 256 threads: og=tid>>4 (16 oc-groups of 8),
// ty=(tid>>2)&3 (2 rows each), tx=tid&3 (4 cols each). K-chunk = 4 ic, reg-prefetched.
// NOTE: no min-occupancy in __launch_bounds__ — round-3's (256,3) capped VGPRs at 84
// and spilled the 64-float accumulator to scratch (42 GB/dispatch of HBM writes).
template <int LVL>
__global__ __launch_bounds__(256) void conv_fused(
    const float* __restrict__ feat, const float* __restrict__ wT2,
    const float* __restrict__ conv_b,
    const float* __restrict__ cls_w, const float* __restrict__ cls_b,
    const float* __restrict__ box_w, const float* __restrict__ box_b,
    float* __restrict__ scoresA, float* __restrict__ boxesA)
{
    constexpr int H = cH[LVL], W = cW[LVL];
    constexpr int STRIDE = cStrideL[LVL], SZ = cSizeL[LVL], LOFF = cLoff[LVL];
    constexpr int TILESX = (W + 15) / 16;

    const int tile = blockIdx.x;
    const int b    = blockIdx.y;
    const int ty0  = (tile / TILESX) * 8;
    const int tx0  = (tile % TILESX) * 16;
    const int tid  = threadIdx.x;

    __shared__ float hwS[256 * 16];                 // [oc][16 heads] 16 KiB
    __shared__ __align__(16) char uni[32768];       // union region
    float*  inS   = (float*)uni;                    // [4ic][10][20]  (3200 B)
    float*  wS    = (float*)(uni + 3200);           // [36k][128oc]   (18432 B)
    float*  tS    = (float*)uni;                    // [128px][64oc]  (32768 B, swizzled)
    double* houtD = (double*)uni;                   // [128px][16]    (16384 B)

    // stage head weights once
    for (int e = tid; e < 256 * 16; e += 256) {
        int oc = e >> 4, h = e & 15;
        float v = 0.f;
        if (h < 3)        v = cls_w[h * 256 + oc];
        else if (h < 15)  v = box_w[(h - 3) * 256 + oc];
        hwS[e] = v;
    }

    const int og  = tid >> 4;        // 0..15 oc-group (8 oc)
    const int ty  = (tid >> 2) & 3;  // 0..3 (2 rows each)
    const int tx  = tid & 3;         // 0..3 (4 cols each)
    const int ty2 = ty * 2;
    const int tx4 = tx * 4;
    const int og8 = og * 8;

    const float* fb = feat + (size_t)b * 256 * H * W;

    // precompute input staging coords (constant across chunks)
    int  ioff[3]; int idst[3]; bool ival[3];
#pragma unroll
    for (int j = 0; j < 3; ++j) {
        int e = tid + j * 256;
        ival[j] = false; ioff[j] = 0; idst[j] = -1;
        if (e < 720) {
            int ic = e / 180, rem = e - ic * 180;
            int row = rem / 18, col = rem - row * 18;
            int gy = ty0 + row - 1, gx = tx0 + col - 1;
            idst[j] = (ic * 10 + row) * 20 + col;
            if (gy >= 0 && gy < H && gx >= 0 && gx < W) {
                ival[j] = true; ioff[j] = (ic * H + gy) * W + gx;
            }
        }
    }

    double hacc[8] = {0,0,0,0,0,0,0,0};   // per-thread f64 head accumulators

    float4 wreg[5];
    float  ireg[3];

    for (int ocg = 0; ocg < 2; ++ocg) {
        const float* wTg = wT2 + (size_t)ocg * 2304 * 128;

        float acc[2][4][8];
#pragma unroll
        for (int rr = 0; rr < 2; ++rr)
#pragma unroll
            for (int cc = 0; cc < 4; ++cc)
#pragma unroll
                for (int oo = 0; oo < 8; ++oo) acc[rr][cc][oo] = 0.f;

        // ---- K loop: 64 chunks of 4 ic (36 k) ----
        // prologue: load chunk 0
        {
            const float* wb = wTg;
#pragma unroll
            for (int j = 0; j < 4; ++j) wreg[j] = *(const float4*)(wb + (size_t)(tid + j*256) * 4);
            wreg[4] = (tid < 128) ? *(const float4*)(wb + (size_t)(1024 + tid) * 4)
                                  : make_float4(0.f,0.f,0.f,0.f);
#pragma unroll
            for (int j = 0; j < 3; ++j) ireg[j] = ival[j] ? fb[ioff[j]] : 0.f;
        }
        __syncthreads();   // previous phase's LDS reads (tS/houtD) complete
        {
#pragma unroll
            for (int j = 0; j < 4; ++j) *(float4*)(wS + (tid + j*256)*4) = wreg[j];
            if (tid < 128) *(float4*)(wS + (1024 + tid)*4) = wreg[4];
#pragma unroll
            for (int j = 0; j < 3; ++j) if (idst[j] >= 0) inS[idst[j]] = ireg[j];
        }
        __syncthreads();   // chunk 0 ready

        for (int c = 0; c < 64; ++c) {
            // prefetch chunk c+1 into registers (latency hides under compute)
            if (c + 1 < 64) {
                const float* wb = wTg + (size_t)(c + 1) * 36 * 128;
                const float* fc = fb + (size_t)(c + 1) * 4 * H * W;
#pragma unroll
                for (int j = 0; j < 4; ++j) wreg[j] = *(const float4*)(wb + (size_t)(tid + j*256) * 4);
                if (tid < 128) wreg[4] = *(const float4*)(wb + (size_t)(1024 + tid) * 4);
#pragma unroll
                for (int j = 0; j < 3; ++j) ireg[j] = ival[j] ? fc[ioff[j]] : 0.f;
            }
            // compute current chunk
#pragma unroll
            for (int ic = 0; ic < 4; ++ic) {
#pragma unroll
                for (int dy = 0; dy < 3; ++dy) {
                    const float* ip0 = &inS[((ic * 10) + ty2 + dy) * 20 + tx4];
                    float4 a0 = *(const float4*)ip0;
                    float2 b0 = *(const float2*)(ip0 + 4);
                    float4 a1 = *(const float4*)(ip0 + 20);
                    float2 b1 = *(const float2*)(ip0 + 24);
                    float i0[6] = {a0.x, a0.y, a0.z, a0.w, b0.x, b0.y};
                    float i1[6] = {a1.x, a1.y, a1.z, a1.w, b1.x, b1.y};
                    const int kb = (ic * 9 + dy * 3) * 128 + og8;
#pragma unroll
                    for (int dx = 0; dx < 3; ++dx) {
                        float4 w0 = *(const float4*)&wS[kb + dx * 128];
                        float4 w1 = *(const float4*)&wS[kb + dx * 128 + 4];
                        float wv[8] = {w0.x,w0.y,w0.z,w0.w,w1.x,w1.y,w1.z,w1.w};
#pragma unroll
                        for (int cc = 0; cc < 4; ++cc) {
                            float v0 = i0[cc + dx];
                            float v1 = i1[cc + dx];
#pragma unroll
                            for (int oo = 0; oo < 8; ++oo) {
                                acc[0][cc][oo] = fmaf(v0, wv[oo], acc[0][cc][oo]);
                                acc[1][cc][oo] = fmaf(v1, wv[oo], acc[1][cc][oo]);
                            }
                        }
                    }
                }
            }
            __syncthreads();   // all LDS reads of this chunk done
            if (c + 1 < 64) {
#pragma unroll
                for (int j = 0; j < 4; ++j) *(float4*)(wS + (tid + j*256)*4) = wreg[j];
                if (tid < 128) *(float4*)(wS + (1024 + tid)*4) = wreg[4];
#pragma unroll
                for (int j = 0; j < 3; ++j) if (idst[j] >= 0) inS[idst[j]] = ireg[j];
                __syncthreads();   // next chunk ready
            }
        }

        // ---- head contraction, 2 substeps of 64 oc (oc ascending), f64 ----
        float4 cb0 = *(const float4*)&conv_b[ocg * 128 + og8];
        float4 cb1 = *(const float4*)&conv_b[ocg * 128 + og8 + 4];
        float cbv[8] = {cb0.x,cb0.y,cb0.z,cb0.w,cb1.x,cb1.y,cb1.z,cb1.w};

        for (int s = 0; s < 2; ++s) {
            // writers: og>>3 == s  (oc_local s*64 .. s*64+63)
            if ((og >> 3) == s) {
                const int g0 = (og & 7) * 2;
#pragma unroll
                for (int rr = 0; rr < 2; ++rr)
#pragma unroll
                    for (int cc = 0; cc < 4; ++cc) {
                        int px = (ty2 + rr) * 16 + tx4 + cc;
                        int sw = px & 15;
                        float4 t0, t1;
                        t0.x = fmaxf(acc[rr][cc][0] + cbv[0], 0.f);
                        t0.y = fmaxf(acc[rr][cc][1] + cbv[1], 0.f);
                        t0.z = fmaxf(acc[rr][cc][2] + cbv[2], 0.f);
                        t0.w = fmaxf(acc[rr][cc][3] + cbv[3], 0.f);
                        t1.x = fmaxf(acc[rr][cc][4] + cbv[4], 0.f);
                        t1.y = fmaxf(acc[rr][cc][5] + cbv[5], 0.f);
                        t1.z = fmaxf(acc[rr][cc][6] + cbv[6], 0.f);
                        t1.w = fmaxf(acc[rr][cc][7] + cbv[7], 0.f);
                        *(float4*)&tS[px * 64 + ((g0    ) ^ sw) * 4] = t0;
                        *(float4*)&tS[px * 64 + ((g0 + 1) ^ sw) * 4] = t1;
                    }
            }
            __syncthreads();
            // accumulate: px = tid&127, head-half = tid>>7
            {
                const int px = tid & 127;
                const int hh = tid >> 7;
                const int sw = px & 15;
                const int ocb = ocg * 128 + s * 64;
#pragma unroll
                for (int j4 = 0; j4 < 16; ++j4) {
                    float4 t4 = *(const float4*)&tS[px * 64 + (j4 ^ sw) * 4];
                    float tv[4] = {t4.x, t4.y, t4.z, t4.w};
#pragma unroll
                    for (int jj = 0; jj < 4; ++jj) {
                        const float* hb = &hwS[(ocb + j4 * 4 + jj) * 16 + hh * 8];
                        float4 h0 = *(const float4*)hb;
                        float4 h1 = *(const float4*)(hb + 4);
                        double tv_d = (double)tv[jj];
                        hacc[0] += tv_d * (double)h0.x;
                        hacc[1] += tv_d * (double)h0.y;
                        hacc[2] += tv_d * (double)h0.z;
                        hacc[3] += tv_d * (double)h0.w;
                        hacc[4] += tv_d * (double)h1.x;
                        hacc[5] += tv_d * (double)h1.y;
                        hacc[6] += tv_d * (double)h1.z;
                        hacc[7] += tv_d * (double)h1.w;
                    }
                }
            }
            __syncthreads();
        }
    }

    // ---- write head outputs to LDS (f64) ----
    {
        const int px = tid & 127;
        const int hh = tid >> 7;
#pragma unroll
        for (int j = 0; j < 8; ++j) houtD[px * 16 + hh * 8 + j] = hacc[j];
    }
    __syncthreads();

    // ---- decode + clip in f64, store f32 ----
    if (tid < 128) {
        const int px = tid;
        const int gy = ty0 + (px >> 4);
        const int gx = tx0 + (px & 15);
        if (gy < H && gx < W) {
#pragma unroll
            for (int a = 0; a < 3; ++a) {
                double score = houtD[px * 16 + a] + (double)cls_b[a];
                double rg0 = houtD[px * 16 + 3 + a * 4 + 0] + (double)box_b[a * 4 + 0];
                double rg1 = houtD[px * 16 + 3 + a * 4 + 1] + (double)box_b[a * 4 + 1];
                double rg2 = houtD[px * 16 + 3 + a * 4 + 2] + (double)box_b[a * 4 + 2];
                double rg3 = houtD[px * 16 + 3 + a * 4 + 3] + (double)box_b[a * 4 + 3];
                double ratio = (a == 0) ? 0.5 : ((a == 1) ? 1.0 : 2.0);
                double hr = sqrt(ratio), wr = 1.0 / hr;
                double wsd = wr * (double)SZ, hsd = hr * (double)SZ;
                double sx = (double)(gx * STRIDE), sy = (double)(gy * STRIDE);
                float ax0 = (float)(sx - 0.5 * wsd);
                float ay0 = (float)(sy - 0.5 * hsd);
                float ax1 = (float)(sx + 0.5 * wsd);
                float ay1 = (float)(sy + 0.5 * hsd);
                double wa = (double)ax1 - (double)ax0, ha = (double)ay1 - (double)ay0;
                double cxa = (double)ax0 + 0.5 * wa, cya = (double)ay0 + 0.5 * ha;
                double dwv = fmin(rg2, 4.135166556742356);
                double dhv = fmin(rg3, 4.135166556742356);
                double cx = rg0 * wa + cxa, cy = rg1 * ha + cya;
                double w = exp(dwv) * wa, h = exp(dhv) * ha;
                double x0 = cx - 0.5 * w, y0 = cy - 0.5 * h;
                double x1 = cx + 0.5 * w, y1 = cy + 0.5 * h;
                x0 = fmin(fmax(x0, 0.0), 1216.0);
                y0 = fmin(fmax(y0, 0.0), 800.0);
                x1 = fmin(fmax(x1, 0.0), 1216.0);
                y1 = fmin(fmax(y1, 0.0), 800.0);
                int gidx = LOFF + (gy * W + gx) * 3 + a;
                scoresA[(size_t)b * ATOTAL + gidx] = (float)score;
                float4 bx = make_float4((float)x0, (float)y0, (float)x1, (float)y1);
                *(float4*)&boxesA[((size_t)b * ATOTAL + gidx) * 4] = bx;
            }
        }
    }
}

// ---------------- per-(batch,level) top-k via 3-pass radix threshold ----------------
__global__ __launch_bounds__(256) void topk_kernel(
    const float* __restrict__ scoresA, const float* __restrict__ boxesA,
    float* __restrict__ selScore, float* __restrict__ selBox,
    int* __restrict__ selValid, int* __restrict__ selAnchor)
{
    const int lvl = blockIdx.x, b = blockIdx.y;
    const int n = dCount[lvl], loff = dLoff[lvl], seg = dSeg[lvl], k = dSegK[lvl];
    const float* sc = scoresA + (size_t)b * ATOTAL + loff;
    const int tid = threadIdx.x;

    float* oS = selScore + b * KSEL;
    float* oB = selBox + (size_t)b * KSEL * 4;
    int* oV = selValid + b * KSEL;
    int* oA = selAnchor + b * KSEL;

    auto emit = [&](int slot, int i) {
        int g = loff + i;
        float s = sc[i];
        float4 bx = *(const float4*)&boxesA[((size_t)b * ATOTAL + g) * 4];
        oS[seg + slot] = s;
        *(float4*)&oB[(size_t)(seg + slot) * 4] = bx;
        oV[seg + slot] = ((bx.z - bx.x) >= 1e-3f && (bx.w - bx.y) >= 1e-3f) ? 1 : 0;
        oA[seg + slot] = g;
    };

    if (n <= k) {
        for (int i = tid; i < n; i += 256) emit(i, i);
        return;
    }

    __shared__ uint hist[2048];
    __shared__ uint sh_bin, sh_krem;
    __shared__ uint cntG, cntE;
    __shared__ int stash[64];

    uint krem = (uint)k;
    uint prefix = 0;
    for (int pass = 0; pass < 3; ++pass) {
        for (int e = tid; e < 2048; e += 256) hist[e] = 0;
        __syncthreads();
        for (int i = tid; i < n; i += 256) {
            uint key = fkey(sc[i]);
            uint bin; bool sel;
            if (pass == 0)      { sel = true;                      bin = key >> 21; }
            else if (pass == 1) { sel = ((key >> 21) == prefix);   bin = (key >> 10) & 0x7FFu; }
            else                { sel = ((key >> 10) == prefix);   bin = key & 0x3FFu; }
            if (sel) atomicAdd(&hist[bin], 1u);
        }
        __syncthreads();
        if (tid == 0) {
            int nb = (pass == 2) ? 1024 : 2048;
            uint c = 0;
            for (int x = nb - 1; x >= 0; --x) {
                uint h = hist[x];
                if (c + h >= krem) { sh_bin = (uint)x; sh_krem = krem - c; break; }
                c += h;
            }
        }
        __syncthreads();
        uint bin = sh_bin; krem = sh_krem;
        if (pass == 0)      prefix = bin;
        else if (pass == 1) prefix = (prefix << 11) | bin;
        else                prefix = (prefix << 10) | bin;
        __syncthreads();
    }
    const uint T = prefix;
    const uint need_eq = krem;
    if (tid == 0) { cntG = 0; cntE = 0; }
    __syncthreads();
    for (int i = tid; i < n; i += 256) {
        uint key = fkey(sc[i]);
        if (key > T) {
            uint pos = atomicAdd(&cntG, 1u);
            emit((int)pos, i);
        } else if (key == T) {
            uint e = atomicAdd(&cntE, 1u);
            if (e < 64) stash[e] = i;
        }
    }
    __syncthreads();
    if (tid == 0) {
        uint ne = cntE < 64u ? cntE : 64u;
        uint base = cntG;   // == k - need_eq
        for (uint t2 = 0; t2 < need_eq; ++t2) {
            int best = -1, bj = -1;
            for (uint j2 = 0; j2 < ne; ++j2) {
                int v = stash[j2];
                if (v >= 0 && (best < 0 || v < best)) { best = v; bj = j2; }
            }
            if (bj >= 0) { stash[bj] = -1; emit((int)(base + t2), best); }
            else emit((int)(base + t2), 0);   // pathological fallback, never expected
        }
    }
}

// ---------------- per-batch descending sort (score, then anchor-idx asc) ----------------
__global__ __launch_bounds__(1024) void sort_kernel(
    const float* __restrict__ selScore, const float* __restrict__ selBox,
    const int* __restrict__ selValid, const int* __restrict__ selAnchor,
    int* __restrict__ sortedSlot, float* __restrict__ sortedBoxOff,
    ull* __restrict__ validMask)
{
    const int b = blockIdx.x, tid = threadIdx.x;
    __shared__ ull  skey[8192];
    __shared__ uint spay[8192];
    __shared__ ull  svm[NW];

    for (int i = tid; i < 8192; i += 1024) {
        ull kk2; uint pp;
        if (i < KSEL) {
            float s = selScore[b * KSEL + i];
            int v = selValid[b * KSEL + i];
            uint k32 = v ? fkey(s) : 0x007FFFFFu;   // invalid => key(-inf)
            uint a32 = 0xFFFFFFFFu - (uint)selAnchor[b * KSEL + i];
            kk2 = ((ull)k32 << 32) | a32; pp = (uint)i;
        } else { kk2 = 0ull; pp = 0xFFFFFFFFu; }
        skey[i] = kk2; spay[i] = pp;
    }
    __syncthreads();
    for (uint kk = 2; kk <= 8192; kk <<= 1) {
        for (uint j = kk >> 1; j > 0; j >>= 1) {
            for (int i = tid; i < 8192; i += 1024) {
                uint ixj = (uint)i ^ j;
                if (ixj > (uint)i) {
                    bool up = ((((uint)i) & kk) == 0);
                    ull a = skey[i], c = skey[ixj];
                    bool sw = up ? (a < c) : (a > c);   // flipped comparators -> descending
                    if (sw) {
                        skey[i] = c; skey[ixj] = a;
                        uint tp = spay[i]; spay[i] = spay[ixj]; spay[ixj] = tp;
                    }
                }
            }
            __syncthreads();
        }
    }
    for (int i = tid; i < NW; i += 1024) svm[i] = 0ull;
    __syncthreads();
    for (int i = tid; i < KSEL; i += 1024) {
        uint slot = spay[i];
        sortedSlot[b * KSEL + i] = (int)slot;
        int v = selValid[b * KSEL + slot];
        if (v) atomicOr(&svm[i >> 6], 1ull << (i & 63));
        int lvl = (int)slot / 1000;
        float off = 1217.0f * (float)lvl;
        float4 bx = *(const float4*)&selBox[((size_t)b * KSEL + slot) * 4];
        bx.x += off; bx.y += off; bx.z += off; bx.w += off;
        *(float4*)&sortedBoxOff[((size_t)b * KSEL + i) * 4] = bx;
    }
    __syncthreads();
    for (int i = tid; i < NW; i += 1024) validMask[b * NW + i] = svm[i];
}

// ---------------- NMS pairwise suppression bitmask ----------------
__global__ __launch_bounds__(64) void nms_mask(const float* __restrict__ sortedBoxOff,
                                               ull* __restrict__ mat)
{
    const int jb = blockIdx.x, ib = blockIdx.y, b = blockIdx.z;
    const int tid = threadIdx.x;
    __shared__ float4 bj[64];
    __shared__ float  aj[64];
    const int j0 = jb * 64;
    const int jn = (KSEL - j0) < 64 ? (KSEL - j0) : 64;
    if (tid < jn) {
        float4 v = *(const float4*)&sortedBoxOff[((size_t)b * KSEL + j0 + tid) * 4];
        bj[tid] = v; aj[tid] = (v.z - v.x) * (v.w - v.y);
    }
    __syncthreads();
    const int i = ib * 64 + tid;
    if (i >= KSEL) return;
    float4 bi = *(const float4*)&sortedBoxOff[((size_t)b * KSEL + i) * 4];
    float ai = (bi.z - bi.x) * (bi.w - bi.y);
    ull m = 0ull;
    for (int jj = 0; jj < jn; ++jj) {
        int j = j0 + jj;
        if (j <= i) continue;
        float4 bb = bj[jj];
        float ltx = fmaxf(bi.x, bb.x), lty = fmaxf(bi.y, bb.y);
        float rbx = fminf(bi.z, bb.z), rby = fminf(bi.w, bb.w);
        float wx = fmaxf(rbx - ltx, 0.f), wy = fmaxf(rby - lty, 0.f);
        float inter = wx * wy;
        float iou = inter / (ai + aj[jj] - inter + 1e-9f);
        if (iou > 0.7f) m |= (1ull << jj);
    }
    mat[((size_t)b * KSEL + i) * NW + jb] = m;
}

// ---------------- greedy scan (1 wave per batch, register-resident bitset) ----------------
__global__ __launch_bounds__(64) void nms_scan(const ull* __restrict__ mat,
                                               const ull* __restrict__ validMask,
                                               int* __restrict__ keptPos,
                                               int* __restrict__ nkOut)
{
    const int b = blockIdx.x, lane = threadIdx.x;
    ull v0 = validMask[b * NW + lane];
    ull v1 = (lane < NW - 64) ? validMask[b * NW + 64 + lane] : 0ull;
    ull s0 = 0ull, s1 = 0ull;
    int nk = 0;
    const ull* mb = mat + (size_t)b * KSEL * NW;
    const int NG = (KSEL + 7) / 8;
    for (int g = 0; g < NG; ++g) {
        ull rA[8], rB[8];
#pragma unroll
        for (int d = 0; d < 8; ++d) {
            int i = g * 8 + d;
            if (i < KSEL) {
                rA[d] = mb[(size_t)i * NW + lane];
                rB[d] = (lane < NW - 64) ? mb[(size_t)i * NW + 64 + lane] : 0ull;
            } else { rA[d] = 0ull; rB[d] = 0ull; }
        }
#pragma unroll
        for (int d = 0; d < 8; ++d) {
            int i = g * 8 + d;
            if (i >= KSEL) break;
            int wi = i >> 6;
            ull a0 = v0 & ~s0, a1 = v1 & ~s1;
            ull aw = (wi < 64) ? __shfl(a0, wi, 64) : __shfl(a1, wi - 64, 64);
            if ((aw >> (i & 63)) & 1ull) {
                s0 |= rA[d]; s1 |= rB[d];
                if (lane == 0) keptPos[b * POST_NMS + nk] = i;
                ++nk;
                if (nk == POST_NMS) { if (lane == 0) nkOut[b] = nk; return; }
            }
        }
    }
    if (lane == 0) nkOut[b] = nk;
}

// ---------------- final output ----------------
__global__ __launch_bounds__(256) void out_kernel(
    const int* __restrict__ keptPos, const int* __restrict__ nkOut,
    const int* __restrict__ sortedSlot,
    const float* __restrict__ selBox, const float* __restrict__ selScore,
    float* __restrict__ out)
{
    int t = blockIdx.x * 256 + threadIdx.x;
    if (t >= BATCH * POST_NMS) return;
    int b = t / POST_NMS, row = t - b * POST_NMS;
    float4 bx = make_float4(0.f, 0.f, 0.f, 0.f);
    float sc = -1e9f;
    if (row < nkOut[b]) {
        int i = keptPos[b * POST_NMS + row];
        int slot = sortedSlot[b * KSEL + i];
        bx = *(const float4*)&selBox[((size_t)b * KSEL + slot) * 4];
        sc = selScore[b * KSEL + slot];
    }
    *(float4*)&out[(size_t)t * 4] = bx;
    out[BATCH * POST_NMS * 4 + t] = sc;
}

// ---------------- host launch ----------------
extern "C" void kernel_launch(void* const* d_in, const int* in_sizes, int n_in,
                              void* d_out, int out_size, void* d_ws, size_t ws_size,
                              hipStream_t stream)
{
    (void)in_sizes; (void)n_in; (void)out_size; (void)ws_size;
    const float* feat[5] = {(const float*)d_in[0], (const float*)d_in[1],
                            (const float*)d_in[2], (const float*)d_in[3],
                            (const float*)d_in[4]};
    const float* conv_w = (const float*)d_in[5];
    const float* conv_b = (const float*)d_in[6];
    const float* cls_w  = (const float*)d_in[7];
    const float* cls_b  = (const float*)d_in[8];
    const float* box_w  = (const float*)d_in[9];
    const float* box_b  = (const float*)d_in[10];
    float* out = (float*)d_out;

    char* ws = (char*)d_ws;
    size_t off = 0;
    auto carve = [&](size_t bytes) -> void* {
        void* p = (void*)(ws + off);
        off += (bytes + 255) & ~(size_t)255;
        return p;
    };
    float* wT2         = (float*)carve((size_t)2 * 2304 * 128 * 4);
    float* scoresA     = (float*)carve((size_t)BATCH * ATOTAL * 4);
    float* boxesA      = (float*)carve((size_t)BATCH * ATOTAL * 16);
    float* selScore    = (float*)carve((size_t)BATCH * KSEL * 4);
    float* selBox      = (float*)carve((size_t)BATCH * KSEL * 16);
    int*   selValid    = (int*)  carve((size_t)BATCH * KSEL * 4);
    int*   selAnchor   = (int*)  carve((size_t)BATCH * KSEL * 4);
    int*   sortedSlot  = (int*)  carve((size_t)BATCH * KSEL * 4);
    float* sortedBoxOff= (float*)carve((size_t)BATCH * KSEL * 16);
    ull*   validMask   = (ull*)  carve((size_t)BATCH * NW * 8);
    ull*   mat         = (ull*)  carve((size_t)BATCH * KSEL * NW * 8);
    int*   keptPos     = (int*)  carve((size_t)BATCH * POST_NMS * 4);
    int*   nkOut       = (int*)  carve(64);

    wt_kernel<<<2304, 256, 0, stream>>>(conv_w, wT2);

    {
        constexpr int t0 = ((cH[0]+7)/8) * ((cW[0]+15)/16);
        conv_fused<0><<<dim3(t0, BATCH), 256, 0, stream>>>(feat[0], wT2, conv_b, cls_w, cls_b, box_w, box_b, scoresA, boxesA);
    }
    {
        constexpr int t1 = ((cH[1]+7)/8) * ((cW[1]+15)/16);
        conv_fused<1><<<dim3(t1, BATCH), 256, 0, stream>>>(feat[1], wT2, conv_b, cls_w, cls_b, box_w, box_b, scoresA, boxesA);
    }
    {
        constexpr int t2 = ((cH[2]+7)/8) * ((cW[2]+15)/16);
        conv_fused<2><<<dim3(t2, BATCH), 256, 0, stream>>>(feat[2], wT2, conv_b, cls_w, cls_b, box_w, box_b, scoresA, boxesA);
    }
    {
        constexpr int t3 = ((cH[3]+7)/8) * ((cW[3]+15)/16);
        conv_fused<3><<<dim3(t3, BATCH), 256, 0, stream>>>(feat[3], wT2, conv_b, cls_w, cls_b, box_w, box_b, scoresA, boxesA);
    }
    {
        constexpr int t4 = ((cH[4]+7)/8) * ((cW[4]+15)/16);
        conv_fused<4><<<dim3(t4, BATCH), 256, 0, stream>>>(feat[4], wT2, conv_b, cls_w, cls_b, box_w, box_b, scoresA, boxesA);
    }

    topk_kernel<<<dim3(5, BATCH), 256, 0, stream>>>(scoresA, boxesA, selScore, selBox, selValid, selAnchor);
    sort_kernel<<<dim3(BATCH), 1024, 0, stream>>>(selScore, selBox, selValid, selAnchor, sortedSlot, sortedBoxOff, validMask);
    nms_mask<<<dim3(NW, NW, BATCH), 64, 0, stream>>>(sortedBoxOff, mat);
    nms_scan<<<dim3(BATCH), 64, 0, stream>>>(mat, validMask, keptPos, nkOut);
    out_kernel<<<dim3((BATCH * POST_NMS + 255) / 256), 256, 0, stream>>>(keptPos, nkOut, sortedSlot, selBox, selScore, out);
}

// Round 5
// 5886.893 us; speedup vs baseline: 6.3110x; 1.6922x over previous
//
#include <hip/hip_runtime.h>
#include <stdint.h>
#include <math.h>

typedef unsigned int uint;
typedef unsigned long long ull;

#define BATCH 2
#define ATOTAL 242991
#define KSEL 4741
#define NW 75
#define POST_NMS 1000

// level constants (host + compile-time device use)
constexpr int cH[5]       = {200,100,50,25,13};
constexpr int cW[5]       = {304,152,76,38,19};
constexpr int cStrideL[5] = {4,8,16,32,64};
constexpr int cSizeL[5]   = {32,64,128,256,512};
constexpr int cLoff[5]    = {0,182400,228000,239400,242250};
constexpr int cCount[5]   = {182400,45600,11400,2850,741};
constexpr int cSeg[5]     = {0,1000,2000,3000,4000};
constexpr int cSegK[5]    = {1000,1000,1000,1000,741};

// runtime-indexed device copies
__device__ __constant__ int dLoff[5]  = {0,182400,228000,239400,242250};
__device__ __constant__ int dCount[5] = {182400,45600,11400,2850,741};
__device__ __constant__ int dSeg[5]   = {0,1000,2000,3000,4000};
__device__ __constant__ int dSegK[5]  = {1000,1000,1000,1000,741};

__device__ __forceinline__ uint fkey(float f) {
    uint u = __float_as_uint(f);
    return (u & 0x80000000u) ? ~u : (u | 0x80000000u);
}

// ---------------- weight relayout: conv_w [O=256][K=2304] -> wT2 [ocg2][K][128] ----------------
__global__ __launch_bounds__(256) void wt_kernel(const float* __restrict__ conv_w,
                                                 float* __restrict__ wT2) {
    int t = blockIdx.x * 256 + threadIdx.x;
    if (t < 2304 * 256) {
        int ocp = t / 2304;           // 0..255
        int k   = t - ocp * 2304;     // lane-consecutive -> coalesced read
        int ocg = ocp >> 7, ocl = ocp & 127;
        wT2[((size_t)ocg * 2304 + k) * 128 + ocl] = conv_w[(size_t)ocp * 2304 + k];
    }
}

// ---------------- fused conv3x3+relu + 1x1 heads (f64) + decode (f64) + clip ----------------
// tile: 8 rows x 16 cols = 128 px. 256 threads: og=tid>>4 (16 oc-groups of 8),
// ty=(tid>>2)&3 (2 rows each), tx=tid&3 (4 cols each). K-chunk = 4 ic, reg-prefetched.
// Register-pressure discipline (round-4 lesson): ic/dy loops are `#pragma unroll 1`
// so the scheduler cannot hoist 36 k-steps of weight ds_reads (VGPR 256 + 0.9 GB
// scratch spill per dispatch). Accumulation order per acc element is k-ascending
// regardless of unrolling -> bit-identical results.
template <int LVL>
__global__ __launch_bounds__(256) void conv_fused(
    const float* __restrict__ feat, const float* __restrict__ wT2,
    const float* __restrict__ conv_b,
    const float* __restrict__ cls_w, const float* __restrict__ cls_b,
    const float* __restrict__ box_w, const float* __restrict__ box_b,
    float* __restrict__ scoresA, float* __restrict__ boxesA)
{
    constexpr int H = cH[LVL], W = cW[LVL];
    constexpr int STRIDE = cStrideL[LVL], SZ = cSizeL[LVL], LOFF = cLoff[LVL];
    constexpr int TILESX = (W + 15) / 16;

    const int tile = blockIdx.x;
    const int b    = blockIdx.y;
    const int ty0  = (tile / TILESX) * 8;
    const int tx0  = (tile % TILESX) * 16;
    const int tid  = threadIdx.x;

    __shared__ float hwS[256 * 16];                 // [oc][16 heads] 16 KiB
    __shared__ __align__(16) char uni[32768];       // union region
    float*  inS   = (float*)uni;                    // [4ic][10][20]  (3200 B)
    float*  wS    = (float*)(uni + 3200);           // [36k][128oc]   (18432 B)
    float*  tS    = (float*)uni;                    // [128px][64oc]  (32768 B, swizzled)
    double* houtD = (double*)uni;                   // [128px][16]    (16384 B)

    // stage head weights once
    for (int e = tid; e < 256 * 16; e += 256) {
        int oc = e >> 4, h = e & 15;
        float v = 0.f;
        if (h < 3)        v = cls_w[h * 256 + oc];
        else if (h < 15)  v = box_w[(h - 3) * 256 + oc];
        hwS[e] = v;
    }

    const int og  = tid >> 4;        // 0..15 oc-group (8 oc)
    const int ty  = (tid >> 2) & 3;  // 0..3 (2 rows each)
    const int tx  = tid & 3;         // 0..3 (4 cols each)
    const int ty2 = ty * 2;
    const int tx4 = tx * 4;
    const int og8 = og * 8;

    const float* fb = feat + (size_t)b * 256 * H * W;

    // precompute input staging coords (constant across chunks)
    int  ioff[3]; int idst[3]; bool ival[3];
#pragma unroll
    for (int j = 0; j < 3; ++j) {
        int e = tid + j * 256;
        ival[j] = false; ioff[j] = 0; idst[j] = -1;
        if (e < 720) {
            int ic = e / 180, rem = e - ic * 180;
            int row = rem / 18, col = rem - row * 18;
            int gy = ty0 + row - 1, gx = tx0 + col - 1;
            idst[j] = (ic * 10 + row) * 20 + col;
            if (gy >= 0 && gy < H && gx >= 0 && gx < W) {
                ival[j] = true; ioff[j] = (ic * H + gy) * W + gx;
            }
        }
    }

    double hacc[8] = {0,0,0,0,0,0,0,0};   // per-thread f64 head accumulators

    float4 wreg[5];
    float  ireg[3];

    for (int ocg = 0; ocg < 2; ++ocg) {
        const float* wTg = wT2 + (size_t)ocg * 2304 * 128;

        float acc[2][4][8];
#pragma unroll
        for (int rr = 0; rr < 2; ++rr)
#pragma unroll
            for (int cc = 0; cc < 4; ++cc)
#pragma unroll
                for (int oo = 0; oo < 8; ++oo) acc[rr][cc][oo] = 0.f;

        // ---- K loop: 64 chunks of 4 ic (36 k) ----
        // prologue: load chunk 0
        {
            const float* wb = wTg;
#pragma unroll
            for (int j = 0; j < 4; ++j) wreg[j] = *(const float4*)(wb + (size_t)(tid + j*256) * 4);
            wreg[4] = (tid < 128) ? *(const float4*)(wb + (size_t)(1024 + tid) * 4)
                                  : make_float4(0.f,0.f,0.f,0.f);
#pragma unroll
            for (int j = 0; j < 3; ++j) ireg[j] = ival[j] ? fb[ioff[j]] : 0.f;
        }
        __syncthreads();   // previous phase's LDS reads (tS/houtD) complete
        {
#pragma unroll
            for (int j = 0; j < 4; ++j) *(float4*)(wS + (tid + j*256)*4) = wreg[j];
            if (tid < 128) *(float4*)(wS + (1024 + tid)*4) = wreg[4];
#pragma unroll
            for (int j = 0; j < 3; ++j) if (idst[j] >= 0) inS[idst[j]] = ireg[j];
        }
        __syncthreads();   // chunk 0 ready

        for (int c = 0; c < 64; ++c) {
            // prefetch chunk c+1 into registers (latency hides under compute)
            if (c + 1 < 64) {
                const float* wb = wTg + (size_t)(c + 1) * 36 * 128;
                const float* fc = fb + (size_t)(c + 1) * 4 * H * W;
#pragma unroll
                for (int j = 0; j < 4; ++j) wreg[j] = *(const float4*)(wb + (size_t)(tid + j*256) * 4);
                if (tid < 128) wreg[4] = *(const float4*)(wb + (size_t)(1024 + tid) * 4);
#pragma unroll
                for (int j = 0; j < 3; ++j) ireg[j] = ival[j] ? fc[ioff[j]] : 0.f;
            }
            // compute current chunk — ic/dy serial (register-pressure cap), dx/cc/oo unrolled
#pragma unroll 1
            for (int ic = 0; ic < 4; ++ic) {
#pragma unroll 1
                for (int dy = 0; dy < 3; ++dy) {
                    const float* ip0 = &inS[((ic * 10) + ty2 + dy) * 20 + tx4];
                    float4 a0 = *(const float4*)ip0;
                    float2 b0 = *(const float2*)(ip0 + 4);
                    float4 a1 = *(const float4*)(ip0 + 20);
                    float2 b1 = *(const float2*)(ip0 + 24);
                    float i0[6] = {a0.x, a0.y, a0.z, a0.w, b0.x, b0.y};
                    float i1[6] = {a1.x, a1.y, a1.z, a1.w, b1.x, b1.y};
                    const int kb = (ic * 9 + dy * 3) * 128 + og8;
#pragma unroll
                    for (int dx = 0; dx < 3; ++dx) {
                        float4 w0 = *(const float4*)&wS[kb + dx * 128];
                        float4 w1 = *(const float4*)&wS[kb + dx * 128 + 4];
                        float wv[8] = {w0.x,w0.y,w0.z,w0.w,w1.x,w1.y,w1.z,w1.w};
#pragma unroll
                        for (int cc = 0; cc < 4; ++cc) {
                            float v0 = i0[cc + dx];
                            float v1 = i1[cc + dx];
#pragma unroll
                            for (int oo = 0; oo < 8; ++oo) {
                                acc[0][cc][oo] = fmaf(v0, wv[oo], acc[0][cc][oo]);
                                acc[1][cc][oo] = fmaf(v1, wv[oo], acc[1][cc][oo]);
                            }
                        }
                    }
                }
            }
            __syncthreads();   // all LDS reads of this chunk done
            if (c + 1 < 64) {
#pragma unroll
                for (int j = 0; j < 4; ++j) *(float4*)(wS + (tid + j*256)*4) = wreg[j];
                if (tid < 128) *(float4*)(wS + (1024 + tid)*4) = wreg[4];
#pragma unroll
                for (int j = 0; j < 3; ++j) if (idst[j] >= 0) inS[idst[j]] = ireg[j];
                __syncthreads();   // next chunk ready
            }
        }

        // ---- head contraction, 2 substeps of 64 oc (oc ascending), f64 ----
        float4 cb0 = *(const float4*)&conv_b[ocg * 128 + og8];
        float4 cb1 = *(const float4*)&conv_b[ocg * 128 + og8 + 4];
        float cbv[8] = {cb0.x,cb0.y,cb0.z,cb0.w,cb1.x,cb1.y,cb1.z,cb1.w};

        for (int s = 0; s < 2; ++s) {
            // writers: og>>3 == s  (oc_local s*64 .. s*64+63)
            if ((og >> 3) == s) {
                const int g0 = (og & 7) * 2;
#pragma unroll
                for (int rr = 0; rr < 2; ++rr)
#pragma unroll
                    for (int cc = 0; cc < 4; ++cc) {
                        int px = (ty2 + rr) * 16 + tx4 + cc;
                        int sw = px & 15;
                        float4 t0, t1;
                        t0.x = fmaxf(acc[rr][cc][0] + cbv[0], 0.f);
                        t0.y = fmaxf(acc[rr][cc][1] + cbv[1], 0.f);
                        t0.z = fmaxf(acc[rr][cc][2] + cbv[2], 0.f);
                        t0.w = fmaxf(acc[rr][cc][3] + cbv[3], 0.f);
                        t1.x = fmaxf(acc[rr][cc][4] + cbv[4], 0.f);
                        t1.y = fmaxf(acc[rr][cc][5] + cbv[5], 0.f);
                        t1.z = fmaxf(acc[rr][cc][6] + cbv[6], 0.f);
                        t1.w = fmaxf(acc[rr][cc][7] + cbv[7], 0.f);
                        *(float4*)&tS[px * 64 + ((g0    ) ^ sw) * 4] = t0;
                        *(float4*)&tS[px * 64 + ((g0 + 1) ^ sw) * 4] = t1;
                    }
            }
            __syncthreads();
            // accumulate: px = tid&127, head-half = tid>>7
            {
                const int px = tid & 127;
                const int hh = tid >> 7;
                const int sw = px & 15;
                const int ocb = ocg * 128 + s * 64;
#pragma unroll 1
                for (int j4 = 0; j4 < 16; ++j4) {
                    float4 t4 = *(const float4*)&tS[px * 64 + (j4 ^ sw) * 4];
                    float tv[4] = {t4.x, t4.y, t4.z, t4.w};
#pragma unroll
                    for (int jj = 0; jj < 4; ++jj) {
                        const float* hb = &hwS[(ocb + j4 * 4 + jj) * 16 + hh * 8];
                        float4 h0 = *(const float4*)hb;
                        float4 h1 = *(const float4*)(hb + 4);
                        double tv_d = (double)tv[jj];
                        hacc[0] += tv_d * (double)h0.x;
                        hacc[1] += tv_d * (double)h0.y;
                        hacc[2] += tv_d * (double)h0.z;
                        hacc[3] += tv_d * (double)h0.w;
                        hacc[4] += tv_d * (double)h1.x;
                        hacc[5] += tv_d * (double)h1.y;
                        hacc[6] += tv_d * (double)h1.z;
                        hacc[7] += tv_d * (double)h1.w;
                    }
                }
            }
            __syncthreads();
        }
    }

    // ---- write head outputs to LDS (f64) ----
    {
        const int px = tid & 127;
        const int hh = tid >> 7;
#pragma unroll
        for (int j = 0; j < 8; ++j) houtD[px * 16 + hh * 8 + j] = hacc[j];
    }
    __syncthreads();

    // ---- decode + clip in f64, store f32 ----
    if (tid < 128) {
        const int px = tid;
        const int gy = ty0 + (px >> 4);
        const int gx = tx0 + (px & 15);
        if (gy < H && gx < W) {
#pragma unroll 1
            for (int a = 0; a < 3; ++a) {
                double score = houtD[px * 16 + a] + (double)cls_b[a];
                double rg0 = houtD[px * 16 + 3 + a * 4 + 0] + (double)box_b[a * 4 + 0];
                double rg1 = houtD[px * 16 + 3 + a * 4 + 1] + (double)box_b[a * 4 + 1];
                double rg2 = houtD[px * 16 + 3 + a * 4 + 2] + (double)box_b[a * 4 + 2];
                double rg3 = houtD[px * 16 + 3 + a * 4 + 3] + (double)box_b[a * 4 + 3];
                double ratio = (a == 0) ? 0.5 : ((a == 1) ? 1.0 : 2.0);
                double hr = sqrt(ratio), wr = 1.0 / hr;
                double wsd = wr * (double)SZ, hsd = hr * (double)SZ;
                double sx = (double)(gx * STRIDE), sy = (double)(gy * STRIDE);
                float ax0 = (float)(sx - 0.5 * wsd);
                float ay0 = (float)(sy - 0.5 * hsd);
                float ax1 = (float)(sx + 0.5 * wsd);
                float ay1 = (float)(sy + 0.5 * hsd);
                double wa = (double)ax1 - (double)ax0, ha = (double)ay1 - (double)ay0;
                double cxa = (double)ax0 + 0.5 * wa, cya = (double)ay0 + 0.5 * ha;
                double dwv = fmin(rg2, 4.135166556742356);
                double dhv = fmin(rg3, 4.135166556742356);
                double cx = rg0 * wa + cxa, cy = rg1 * ha + cya;
                double w = exp(dwv) * wa, h = exp(dhv) * ha;
                double x0 = cx - 0.5 * w, y0 = cy - 0.5 * h;
                double x1 = cx + 0.5 * w, y1 = cy + 0.5 * h;
                x0 = fmin(fmax(x0, 0.0), 1216.0);
                y0 = fmin(fmax(y0, 0.0), 800.0);
                x1 = fmin(fmax(x1, 0.0), 1216.0);
                y1 = fmin(fmax(y1, 0.0), 800.0);
                int gidx = LOFF + (gy * W + gx) * 3 + a;
                scoresA[(size_t)b * ATOTAL + gidx] = (float)score;
                float4 bx = make_float4((float)x0, (float)y0, (float)x1, (float)y1);
                *(float4*)&boxesA[((size_t)b * ATOTAL + gidx) * 4] = bx;
            }
        }
    }
}

// ---------------- per-(batch,level) top-k via 3-pass radix threshold ----------------
__global__ __launch_bounds__(256) void topk_kernel(
    const float* __restrict__ scoresA, const float* __restrict__ boxesA,
    float* __restrict__ selScore, float* __restrict__ selBox,
    int* __restrict__ selValid, int* __restrict__ selAnchor)
{
    const int lvl = blockIdx.x, b = blockIdx.y;
    const int n = dCount[lvl], loff = dLoff[lvl], seg = dSeg[lvl], k = dSegK[lvl];
    const float* sc = scoresA + (size_t)b * ATOTAL + loff;
    const int tid = threadIdx.x;

    float* oS = selScore + b * KSEL;
    float* oB = selBox + (size_t)b * KSEL * 4;
    int* oV = selValid + b * KSEL;
    int* oA = selAnchor + b * KSEL;

    auto emit = [&](int slot, int i) {
        int g = loff + i;
        float s = sc[i];
        float4 bx = *(const float4*)&boxesA[((size_t)b * ATOTAL + g) * 4];
        oS[seg + slot] = s;
        *(float4*)&oB[(size_t)(seg + slot) * 4] = bx;
        oV[seg + slot] = ((bx.z - bx.x) >= 1e-3f && (bx.w - bx.y) >= 1e-3f) ? 1 : 0;
        oA[seg + slot] = g;
    };

    if (n <= k) {
        for (int i = tid; i < n; i += 256) emit(i, i);
        return;
    }

    __shared__ uint hist[2048];
    __shared__ uint sh_bin, sh_krem;
    __shared__ uint cntG, cntE;
    __shared__ int stash[64];

    uint krem = (uint)k;
    uint prefix = 0;
    for (int pass = 0; pass < 3; ++pass) {
        for (int e = tid; e < 2048; e += 256) hist[e] = 0;
        __syncthreads();
        for (int i = tid; i < n; i += 256) {
            uint key = fkey(sc[i]);
            uint bin; bool sel;
            if (pass == 0)      { sel = true;                      bin = key >> 21; }
            else if (pass == 1) { sel = ((key >> 21) == prefix);   bin = (key >> 10) & 0x7FFu; }
            else                { sel = ((key >> 10) == prefix);   bin = key & 0x3FFu; }
            if (sel) atomicAdd(&hist[bin], 1u);
        }
        __syncthreads();
        if (tid == 0) {
            int nb = (pass == 2) ? 1024 : 2048;
            uint c = 0;
            for (int x = nb - 1; x >= 0; --x) {
                uint h = hist[x];
                if (c + h >= krem) { sh_bin = (uint)x; sh_krem = krem - c; break; }
                c += h;
            }
        }
        __syncthreads();
        uint bin = sh_bin; krem = sh_krem;
        if (pass == 0)      prefix = bin;
        else if (pass == 1) prefix = (prefix << 11) | bin;
        else                prefix = (prefix << 10) | bin;
        __syncthreads();
    }
    const uint T = prefix;
    const uint need_eq = krem;
    if (tid == 0) { cntG = 0; cntE = 0; }
    __syncthreads();
    for (int i = tid; i < n; i += 256) {
        uint key = fkey(sc[i]);
        if (key > T) {
            uint pos = atomicAdd(&cntG, 1u);
            emit((int)pos, i);
        } else if (key == T) {
            uint e = atomicAdd(&cntE, 1u);
            if (e < 64) stash[e] = i;
        }
    }
    __syncthreads();
    if (tid == 0) {
        uint ne = cntE < 64u ? cntE : 64u;
        uint base = cntG;   // == k - need_eq
        for (uint t2 = 0; t2 < need_eq; ++t2) {
            int best = -1, bj = -1;
            for (uint j2 = 0; j2 < ne; ++j2) {
                int v = stash[j2];
                if (v >= 0 && (best < 0 || v < best)) { best = v; bj = j2; }
            }
            if (bj >= 0) { stash[bj] = -1; emit((int)(base + t2), best); }
            else emit((int)(base + t2), 0);   // pathological fallback, never expected
        }
    }
}

// ---------------- per-batch descending sort (score, then anchor-idx asc) ----------------
__global__ __launch_bounds__(1024) void sort_kernel(
    const float* __restrict__ selScore, const float* __restrict__ selBox,
    const int* __restrict__ selValid, const int* __restrict__ selAnchor,
    int* __restrict__ sortedSlot, float* __restrict__ sortedBoxOff,
    ull* __restrict__ validMask)
{
    const int b = blockIdx.x, tid = threadIdx.x;
    __shared__ ull  skey[8192];
    __shared__ uint spay[8192];
    __shared__ ull  svm[NW];

    for (int i = tid; i < 8192; i += 1024) {
        ull kk2; uint pp;
        if (i < KSEL) {
            float s = selScore[b * KSEL + i];
            int v = selValid[b * KSEL + i];
            uint k32 = v ? fkey(s) : 0x007FFFFFu;   // invalid => key(-inf)
            uint a32 = 0xFFFFFFFFu - (uint)selAnchor[b * KSEL + i];
            kk2 = ((ull)k32 << 32) | a32; pp = (uint)i;
        } else { kk2 = 0ull; pp = 0xFFFFFFFFu; }
        skey[i] = kk2; spay[i] = pp;
    }
    __syncthreads();
    for (uint kk = 2; kk <= 8192; kk <<= 1) {
        for (uint j = kk >> 1; j > 0; j >>= 1) {
            for (int i = tid; i < 8192; i += 1024) {
                uint ixj = (uint)i ^ j;
                if (ixj > (uint)i) {
                    bool up = ((((uint)i) & kk) == 0);
                    ull a = skey[i], c = skey[ixj];
                    bool sw = up ? (a < c) : (a > c);   // flipped comparators -> descending
                    if (sw) {
                        skey[i] = c; skey[ixj] = a;
                        uint tp = spay[i]; spay[i] = spay[ixj]; spay[ixj] = tp;
                    }
                }
            }
            __syncthreads();
        }
    }
    for (int i = tid; i < NW; i += 1024) svm[i] = 0ull;
    __syncthreads();
    for (int i = tid; i < KSEL; i += 1024) {
        uint slot = spay[i];
        sortedSlot[b * KSEL + i] = (int)slot;
        int v = selValid[b * KSEL + slot];
        if (v) atomicOr(&svm[i >> 6], 1ull << (i & 63));
        int lvl = (int)slot / 1000;
        float off = 1217.0f * (float)lvl;
        float4 bx = *(const float4*)&selBox[((size_t)b * KSEL + slot) * 4];
        bx.x += off; bx.y += off; bx.z += off; bx.w += off;
        *(float4*)&sortedBoxOff[((size_t)b * KSEL + i) * 4] = bx;
    }
    __syncthreads();
    for (int i = tid; i < NW; i += 1024) validMask[b * NW + i] = svm[i];
}

// ---------------- NMS pairwise suppression bitmask ----------------
__global__ __launch_bounds__(64) void nms_mask(const float* __restrict__ sortedBoxOff,
                                               ull* __restrict__ mat)
{
    const int jb = blockIdx.x, ib = blockIdx.y, b = blockIdx.z;
    const int tid = threadIdx.x;
    __shared__ float4 bj[64];
    __shared__ float  aj[64];
    const int j0 = jb * 64;
    const int jn = (KSEL - j0) < 64 ? (KSEL - j0) : 64;
    if (tid < jn) {
        float4 v = *(const float4*)&sortedBoxOff[((size_t)b * KSEL + j0 + tid) * 4];
        bj[tid] = v; aj[tid] = (v.z - v.x) * (v.w - v.y);
    }
    __syncthreads();
    const int i = ib * 64 + tid;
    if (i >= KSEL) return;
    float4 bi = *(const float4*)&sortedBoxOff[((size_t)b * KSEL + i) * 4];
    float ai = (bi.z - bi.x) * (bi.w - bi.y);
    ull m = 0ull;
    for (int jj = 0; jj < jn; ++jj) {
        int j = j0 + jj;
        if (j <= i) continue;
        float4 bb = bj[jj];
        float ltx = fmaxf(bi.x, bb.x), lty = fmaxf(bi.y, bb.y);
        float rbx = fminf(bi.z, bb.z), rby = fminf(bi.w, bb.w);
        float wx = fmaxf(rbx - ltx, 0.f), wy = fmaxf(rby - lty, 0.f);
        float inter = wx * wy;
        float iou = inter / (ai + aj[jj] - inter + 1e-9f);
        if (iou > 0.7f) m |= (1ull << jj);
    }
    mat[((size_t)b * KSEL + i) * NW + jb] = m;
}

// ---------------- greedy scan (1 wave per batch, register-resident bitset) ----------------
__global__ __launch_bounds__(64) void nms_scan(const ull* __restrict__ mat,
                                               const ull* __restrict__ validMask,
                                               int* __restrict__ keptPos,
                                               int* __restrict__ nkOut)
{
    const int b = blockIdx.x, lane = threadIdx.x;
    ull v0 = validMask[b * NW + lane];
    ull v1 = (lane < NW - 64) ? validMask[b * NW + 64 + lane] : 0ull;
    ull s0 = 0ull, s1 = 0ull;
    int nk = 0;
    const ull* mb = mat + (size_t)b * KSEL * NW;
    const int NG = (KSEL + 7) / 8;
    for (int g = 0; g < NG; ++g) {
        ull rA[8], rB[8];
#pragma unroll
        for (int d = 0; d < 8; ++d) {
            int i = g * 8 + d;
            if (i < KSEL) {
                rA[d] = mb[(size_t)i * NW + lane];
                rB[d] = (lane < NW - 64) ? mb[(size_t)i * NW + 64 + lane] : 0ull;
            } else { rA[d] = 0ull; rB[d] = 0ull; }
        }
#pragma unroll
        for (int d = 0; d < 8; ++d) {
            int i = g * 8 + d;
            if (i >= KSEL) break;
            int wi = i >> 6;
            ull a0 = v0 & ~s0, a1 = v1 & ~s1;
            ull aw = (wi < 64) ? __shfl(a0, wi, 64) : __shfl(a1, wi - 64, 64);
            if ((aw >> (i & 63)) & 1ull) {
                s0 |= rA[d]; s1 |= rB[d];
                if (lane == 0) keptPos[b * POST_NMS + nk] = i;
                ++nk;
                if (nk == POST_NMS) { if (lane == 0) nkOut[b] = nk; return; }
            }
        }
    }
    if (lane == 0) nkOut[b] = nk;
}

// ---------------- final output ----------------
__global__ __launch_bounds__(256) void out_kernel(
    const int* __restrict__ keptPos, const int* __restrict__ nkOut,
    const int* __restrict__ sortedSlot,
    const float* __restrict__ selBox, const float* __restrict__ selScore,
    float* __restrict__ out)
{
    int t = blockIdx.x * 256 + threadIdx.x;
    if (t >= BATCH * POST_NMS) return;
    int b = t / POST_NMS, row = t - b * POST_NMS;
    float4 bx = make_float4(0.f, 0.f, 0.f, 0.f);
    float sc = -1e9f;
    if (row < nkOut[b]) {
        int i = keptPos[b * POST_NMS + row];
        int slot = sortedSlot[b * KSEL + i];
        bx = *(const float4*)&selBox[((size_t)b * KSEL + slot) * 4];
        sc = selScore[b * KSEL + slot];
    }
    *(float4*)&out[(size_t)t * 4] = bx;
    out[BATCH * POST_NMS * 4 + t] = sc;
}

// ---------------- host launch ----------------
extern "C" void kernel_launch(void* const* d_in, const int* in_sizes, int n_in,
                              void* d_out, int out_size, void* d_ws, size_t ws_size,
                              hipStream_t stream)
{
    (void)in_sizes; (void)n_in; (void)out_size; (void)ws_size;
    const float* feat[5] = {(const float*)d_in[0], (const float*)d_in[1],
                            (const float*)d_in[2], (const float*)d_in[3],
                            (const float*)d_in[4]};
    const float* conv_w = (const float*)d_in[5];
    const float* conv_b = (const float*)d_in[6];
    const float* cls_w  = (const float*)d_in[7];
    const float* cls_b  = (const float*)d_in[8];
    const float* box_w  = (const float*)d_in[9];
    const float* box_b  = (const float*)d_in[10];
    float* out = (float*)d_out;

    char* ws = (char*)d_ws;
    size_t off = 0;
    auto carve = [&](size_t bytes) -> void* {
        void* p = (void*)(ws + off);
        off += (bytes + 255) & ~(size_t)255;
        return p;
    };
    float* wT2         = (float*)carve((size_t)2 * 2304 * 128 * 4);
    float* scoresA     = (float*)carve((size_t)BATCH * ATOTAL * 4);
    float* boxesA      = (float*)carve((size_t)BATCH * ATOTAL * 16);
    float* selScore    = (float*)carve((size_t)BATCH * KSEL * 4);
    float* selBox      = (float*)carve((size_t)BATCH * KSEL * 16);
    int*   selValid    = (int*)  carve((size_t)BATCH * KSEL * 4);
    int*   selAnchor   = (int*)  carve((size_t)BATCH * KSEL * 4);
    int*   sortedSlot  = (int*)  carve((size_t)BATCH * KSEL * 4);
    float* sortedBoxOff= (float*)carve((size_t)BATCH * KSEL * 16);
    ull*   validMask   = (ull*)  carve((size_t)BATCH * NW * 8);
    ull*   mat         = (ull*)  carve((size_t)BATCH * KSEL * NW * 8);
    int*   keptPos     = (int*)  carve((size_t)BATCH * POST_NMS * 4);
    int*   nkOut       = (int*)  carve(64);

    wt_kernel<<<2304, 256, 0, stream>>>(conv_w, wT2);

    {
        constexpr int t0 = ((cH[0]+7)/8) * ((cW[0]+15)/16);
        conv_fused<0><<<dim3(t0, BATCH), 256, 0, stream>>>(feat[0], wT2, conv_b, cls_w, cls_b, box_w, box_b, scoresA, boxesA);
    }
    {
        constexpr int t1 = ((cH[1]+7)/8) * ((cW[1]+15)/16);
        conv_fused<1><<<dim3(t1, BATCH), 256, 0, stream>>>(feat[1], wT2, conv_b, cls_w, cls_b, box_w, box_b, scoresA, boxesA);
    }
    {
        constexpr int t2 = ((cH[2]+7)/8) * ((cW[2]+15)/16);
        conv_fused<2><<<dim3(t2, BATCH), 256, 0, stream>>>(feat[2], wT2, conv_b, cls_w, cls_b, box_w, box_b, scoresA, boxesA);
    }
    {
        constexpr int t3 = ((cH[3]+7)/8) * ((cW[3]+15)/16);
        conv_fused<3><<<dim3(t3, BATCH), 256, 0, stream>>>(feat[3], wT2, conv_b, cls_w, cls_b, box_w, box_b, scoresA, boxesA);
    }
    {
        constexpr int t4 = ((cH[4]+7)/8) * ((cW[4]+15)/16);
        conv_fused<4><<<dim3(t4, BATCH), 256, 0, stream>>>(feat[4], wT2, conv_b, cls_w, cls_b, box_w, box_b, scoresA, boxesA);
    }

    topk_kernel<<<dim3(5, BATCH), 256, 0, stream>>>(scoresA, boxesA, selScore, selBox, selValid, selAnchor);
    sort_kernel<<<dim3(BATCH), 1024, 0, stream>>>(selScore, selBox, selValid, selAnchor, sortedSlot, sortedBoxOff, validMask);
    nms_mask<<<dim3(NW, NW, BATCH), 64, 0, stream>>>(sortedBoxOff, mat);
    nms_scan<<<dim3(BATCH), 64, 0, stream>>>(mat, validMask, keptPos, nkOut);
    out_kernel<<<dim3((BATCH * POST_NMS + 255) / 256), 256, 0, stream>>>(keptPos, nkOut, sortedSlot, selBox, selScore, out);
}

// Round 6
// 3996.801 us; speedup vs baseline: 9.2956x; 1.4729x over previous
//
#include <hip/hip_runtime.h>
#include <stdint.h>
#include <math.h>

typedef unsigned int uint;
typedef unsigned long long ull;

#define BATCH 2
#define ATOTAL 242991
#define KSEL 4741
#define NW 75
#define POST_NMS 1000

// level constants (host use)
constexpr int cH[5]       = {200,100,50,25,13};
constexpr int cW[5]       = {304,152,76,38,19};

// runtime-indexed device copies
__device__ __constant__ int dLoff[5]  = {0,182400,228000,239400,242250};
__device__ __constant__ int dCount[5] = {182400,45600,11400,2850,741};
__device__ __constant__ int dSeg[5]   = {0,1000,2000,3000,4000};
__device__ __constant__ int dSegK[5]  = {1000,1000,1000,1000,741};
__device__ __constant__ int dHc[5]     = {200,100,50,25,13};
__device__ __constant__ int dWc[5]     = {304,152,76,38,19};
__device__ __constant__ int dTilesX[5] = {19,10,5,3,2};
__device__ __constant__ int dCumT[6]   = {0,475,605,640,652,656};   // tiles per level: 475,130,35,12,4
__device__ __constant__ int dStrideC[5]= {4,8,16,32,64};
__device__ __constant__ int dSizeC[5]  = {32,64,128,256,512};

__device__ __forceinline__ uint fkey(float f) {
    uint u = __float_as_uint(f);
    return (u & 0x80000000u) ? ~u : (u | 0x80000000u);
}

// ---------------- weight relayout: conv_w [O=256][K=2304] -> wT2 [ocg2][K][128] ----------------
__global__ __launch_bounds__(256) void wt_kernel(const float* __restrict__ conv_w,
                                                 float* __restrict__ wT2) {
    int t = blockIdx.x * 256 + threadIdx.x;
    if (t < 2304 * 256) {
        int ocp = t / 2304;           // 0..255
        int k   = t - ocp * 2304;     // lane-consecutive -> coalesced read
        int ocg = ocp >> 7, ocl = ocp & 127;
        wT2[((size_t)ocg * 2304 + k) * 128 + ocl] = conv_w[(size_t)ocp * 2304 + k];
    }
}

// ---------------- fused conv3x3+relu + 1x1 heads (f64) + decode (f64) + clip ----------------
// ALL levels + batches in one dispatch (grid = (656, 2)): runtime level lookup.
// tile: 8 rows x 16 cols = 128 px. 256 threads: og=tid>>4 (16 oc-groups of 8),
// ty=(tid>>2)&3 (2 rows each), tx=tid&3 (4 cols each). K-chunk = 4 ic, reg-prefetched.
// LDS budget: 36,864 B (no standing head-weight buffer; hw2 staged per substep)
// -> 4 blocks/CU for latency hiding. ic/dy loops stay `#pragma unroll 1` (VGPR cap).
__global__ __launch_bounds__(256) void conv_fused_all(
    const float* __restrict__ f0, const float* __restrict__ f1,
    const float* __restrict__ f2, const float* __restrict__ f3,
    const float* __restrict__ f4, const float* __restrict__ wT2,
    const float* __restrict__ conv_b,
    const float* __restrict__ cls_w, const float* __restrict__ cls_b,
    const float* __restrict__ box_w, const float* __restrict__ box_b,
    float* __restrict__ scoresA, float* __restrict__ boxesA)
{
    const int bidx = blockIdx.x;
    const int b    = blockIdx.y;
    const int tid  = threadIdx.x;

    int lvl = 0;
#pragma unroll
    for (int l = 1; l < 5; ++l) if (bidx >= dCumT[l]) lvl = l;
    const int tile   = bidx - dCumT[lvl];
    const int H      = dHc[lvl], W = dWc[lvl];
    const int TILESX = dTilesX[lvl];
    const int ty0    = (tile / TILESX) * 8;
    const int tx0    = (tile % TILESX) * 16;
    const int HW     = H * W;
    const int HW4    = 4 * HW;
    const float* feat = (lvl == 0) ? f0 : (lvl == 1) ? f1 : (lvl == 2) ? f2 : (lvl == 3) ? f3 : f4;

    __shared__ __align__(16) char uni[36864];       // union region
    float*  inS   = (float*)uni;                    // [4ic][10][20]  (3200 B)
    float*  wS    = (float*)(uni + 3200);           // [36k][128oc]   (18432 B)
    float*  tS    = (float*)uni;                    // [128px][64oc]  (32768 B, swizzled)
    double* houtD = (double*)uni;                   // [128px][16]    (16384 B)
    float*  hw2   = (float*)(uni + 32768);          // [64oc][16]     (4096 B, staged/substep)

    const int og  = tid >> 4;        // 0..15 oc-group (8 oc)
    const int ty  = (tid >> 2) & 3;  // 0..3 (2 rows each)
    const int tx  = tid & 3;         // 0..3 (4 cols each)
    const int ty2 = ty * 2;
    const int tx4 = tx * 4;
    const int og8 = og * 8;

    const float* fb = feat + (size_t)b * 256 * HW;

    // precompute input staging coords (constant across chunks)
    int  ioff[3]; int idst[3]; bool ival[3];
#pragma unroll
    for (int j = 0; j < 3; ++j) {
        int e = tid + j * 256;
        ival[j] = false; ioff[j] = 0; idst[j] = -1;
        if (e < 720) {
            int ic = e / 180, rem = e - ic * 180;
            int row = rem / 18, col = rem - row * 18;
            int gy = ty0 + row - 1, gx = tx0 + col - 1;
            idst[j] = (ic * 10 + row) * 20 + col;
            if (gy >= 0 && gy < H && gx >= 0 && gx < W) {
                ival[j] = true; ioff[j] = (ic * H + gy) * W + gx;
            }
        }
    }

    double hacc[8] = {0,0,0,0,0,0,0,0};   // per-thread f64 head accumulators

    float4 wreg[5];
    float  ireg[3];

    for (int ocg = 0; ocg < 2; ++ocg) {
        const float* wTg = wT2 + (size_t)ocg * 2304 * 128;

        float acc[2][4][8];
#pragma unroll
        for (int rr = 0; rr < 2; ++rr)
#pragma unroll
            for (int cc = 0; cc < 4; ++cc)
#pragma unroll
                for (int oo = 0; oo < 8; ++oo) acc[rr][cc][oo] = 0.f;

        // ---- K loop: 64 chunks of 4 ic (36 k) ----
        // prologue: load chunk 0
        {
            const float* wb = wTg;
#pragma unroll
            for (int j = 0; j < 4; ++j) wreg[j] = *(const float4*)(wb + (size_t)(tid + j*256) * 4);
            wreg[4] = (tid < 128) ? *(const float4*)(wb + (size_t)(1024 + tid) * 4)
                                  : make_float4(0.f,0.f,0.f,0.f);
#pragma unroll
            for (int j = 0; j < 3; ++j) ireg[j] = ival[j] ? fb[ioff[j]] : 0.f;
        }
        __syncthreads();   // previous phase's LDS reads (tS/houtD) complete
        {
#pragma unroll
            for (int j = 0; j < 4; ++j) *(float4*)(wS + (tid + j*256)*4) = wreg[j];
            if (tid < 128) *(float4*)(wS + (1024 + tid)*4) = wreg[4];
#pragma unroll
            for (int j = 0; j < 3; ++j) if (idst[j] >= 0) inS[idst[j]] = ireg[j];
        }
        __syncthreads();   // chunk 0 ready

        for (int c = 0; c < 64; ++c) {
            // prefetch chunk c+1 into registers (latency hides under compute)
            if (c + 1 < 64) {
                const float* wb = wTg + (size_t)(c + 1) * 36 * 128;
                const float* fc = fb + (size_t)(c + 1) * HW4;
#pragma unroll
                for (int j = 0; j < 4; ++j) wreg[j] = *(const float4*)(wb + (size_t)(tid + j*256) * 4);
                if (tid < 128) wreg[4] = *(const float4*)(wb + (size_t)(1024 + tid) * 4);
#pragma unroll
                for (int j = 0; j < 3; ++j) ireg[j] = ival[j] ? fc[ioff[j]] : 0.f;
            }
            // compute current chunk — ic/dy serial (register-pressure cap), dx/cc/oo unrolled
#pragma unroll 1
            for (int ic = 0; ic < 4; ++ic) {
#pragma unroll 1
                for (int dy = 0; dy < 3; ++dy) {
                    const float* ip0 = &inS[((ic * 10) + ty2 + dy) * 20 + tx4];
                    float4 a0 = *(const float4*)ip0;
                    float2 b0 = *(const float2*)(ip0 + 4);
                    float4 a1 = *(const float4*)(ip0 + 20);
                    float2 b1 = *(const float2*)(ip0 + 24);
                    float i0[6] = {a0.x, a0.y, a0.z, a0.w, b0.x, b0.y};
                    float i1[6] = {a1.x, a1.y, a1.z, a1.w, b1.x, b1.y};
                    const int kb = (ic * 9 + dy * 3) * 128 + og8;
#pragma unroll
                    for (int dx = 0; dx < 3; ++dx) {
                        float4 w0 = *(const float4*)&wS[kb + dx * 128];
                        float4 w1 = *(const float4*)&wS[kb + dx * 128 + 4];
                        float wv[8] = {w0.x,w0.y,w0.z,w0.w,w1.x,w1.y,w1.z,w1.w};
#pragma unroll
                        for (int cc = 0; cc < 4; ++cc) {
                            float v0 = i0[cc + dx];
                            float v1 = i1[cc + dx];
#pragma unroll
                            for (int oo = 0; oo < 8; ++oo) {
                                acc[0][cc][oo] = fmaf(v0, wv[oo], acc[0][cc][oo]);
                                acc[1][cc][oo] = fmaf(v1, wv[oo], acc[1][cc][oo]);
                            }
                        }
                    }
                }
            }
            __syncthreads();   // all LDS reads of this chunk done
            if (c + 1 < 64) {
#pragma unroll
                for (int j = 0; j < 4; ++j) *(float4*)(wS + (tid + j*256)*4) = wreg[j];
                if (tid < 128) *(float4*)(wS + (1024 + tid)*4) = wreg[4];
#pragma unroll
                for (int j = 0; j < 3; ++j) if (idst[j] >= 0) inS[idst[j]] = ireg[j];
                __syncthreads();   // next chunk ready
            }
        }

        // ---- head contraction, 2 substeps of 64 oc (oc ascending), f64 ----
        float4 cb0 = *(const float4*)&conv_b[ocg * 128 + og8];
        float4 cb1 = *(const float4*)&conv_b[ocg * 128 + og8 + 4];
        float cbv[8] = {cb0.x,cb0.y,cb0.z,cb0.w,cb1.x,cb1.y,cb1.z,cb1.w};

        for (int s = 0; s < 2; ++s) {
            // writers: og>>3 == s  (oc_local s*64 .. s*64+63)
            if ((og >> 3) == s) {
                const int g0 = (og & 7) * 2;
#pragma unroll
                for (int rr = 0; rr < 2; ++rr)
#pragma unroll
                    for (int cc = 0; cc < 4; ++cc) {
                        int px = (ty2 + rr) * 16 + tx4 + cc;
                        int sw = px & 15;
                        float4 t0, t1;
                        t0.x = fmaxf(acc[rr][cc][0] + cbv[0], 0.f);
                        t0.y = fmaxf(acc[rr][cc][1] + cbv[1], 0.f);
                        t0.z = fmaxf(acc[rr][cc][2] + cbv[2], 0.f);
                        t0.w = fmaxf(acc[rr][cc][3] + cbv[3], 0.f);
                        t1.x = fmaxf(acc[rr][cc][4] + cbv[4], 0.f);
                        t1.y = fmaxf(acc[rr][cc][5] + cbv[5], 0.f);
                        t1.z = fmaxf(acc[rr][cc][6] + cbv[6], 0.f);
                        t1.w = fmaxf(acc[rr][cc][7] + cbv[7], 0.f);
                        *(float4*)&tS[px * 64 + ((g0    ) ^ sw) * 4] = t0;
                        *(float4*)&tS[px * 64 + ((g0 + 1) ^ sw) * 4] = t1;
                    }
            }
            // stage head weights for this 64-oc substep: hw2[oc2][16]
            {
                const int oc2 = tid >> 2;                 // 0..63
                const int h0  = (tid & 3) * 4;            // 0,4,8,12
                const int oc  = ocg * 128 + s * 64 + oc2;
                float vv[4];
#pragma unroll
                for (int q = 0; q < 4; ++q) {
                    int h = h0 + q;
                    vv[q] = (h < 3) ? cls_w[h * 256 + oc]
                          : (h < 15) ? box_w[(h - 3) * 256 + oc] : 0.f;
                }
                *(float4*)&hw2[oc2 * 16 + h0] = make_float4(vv[0], vv[1], vv[2], vv[3]);
            }
            __syncthreads();
            // accumulate: px = tid&127, head-half = tid>>7
            {
                const int px = tid & 127;
                const int hh = tid >> 7;
                const int sw = px & 15;
#pragma unroll 1
                for (int j4 = 0; j4 < 16; ++j4) {
                    float4 t4 = *(const float4*)&tS[px * 64 + (j4 ^ sw) * 4];
                    float tv[4] = {t4.x, t4.y, t4.z, t4.w};
#pragma unroll
                    for (int jj = 0; jj < 4; ++jj) {
                        const float* hb = &hw2[(j4 * 4 + jj) * 16 + hh * 8];
                        float4 h0 = *(const float4*)hb;
                        float4 h1 = *(const float4*)(hb + 4);
                        double tv_d = (double)tv[jj];
                        hacc[0] += tv_d * (double)h0.x;
                        hacc[1] += tv_d * (double)h0.y;
                        hacc[2] += tv_d * (double)h0.z;
                        hacc[3] += tv_d * (double)h0.w;
                        hacc[4] += tv_d * (double)h1.x;
                        hacc[5] += tv_d * (double)h1.y;
                        hacc[6] += tv_d * (double)h1.z;
                        hacc[7] += tv_d * (double)h1.w;
                    }
                }
            }
            __syncthreads();
        }
    }

    // ---- write head outputs to LDS (f64) ----  (s-loop trailing barrier protects tS alias)
    {
        const int px = tid & 127;
        const int hh = tid >> 7;
#pragma unroll
        for (int j = 0; j < 8; ++j) houtD[px * 16 + hh * 8 + j] = hacc[j];
    }
    __syncthreads();

    // ---- decode + clip in f64, store f32 ----
    if (tid < 128) {
        const int px = tid;
        const int gy = ty0 + (px >> 4);
        const int gx = tx0 + (px & 15);
        if (gy < H && gx < W) {
            const int STRIDE = dStrideC[lvl];
            const int SZ     = dSizeC[lvl];
            const int LOFF   = dLoff[lvl];
#pragma unroll 1
            for (int a = 0; a < 3; ++a) {
                double score = houtD[px * 16 + a] + (double)cls_b[a];
                double rg0 = houtD[px * 16 + 3 + a * 4 + 0] + (double)box_b[a * 4 + 0];
                double rg1 = houtD[px * 16 + 3 + a * 4 + 1] + (double)box_b[a * 4 + 1];
                double rg2 = houtD[px * 16 + 3 + a * 4 + 2] + (double)box_b[a * 4 + 2];
                double rg3 = houtD[px * 16 + 3 + a * 4 + 3] + (double)box_b[a * 4 + 3];
                double ratio = (a == 0) ? 0.5 : ((a == 1) ? 1.0 : 2.0);
                double hr = sqrt(ratio), wr = 1.0 / hr;
                double wsd = wr * (double)SZ, hsd = hr * (double)SZ;
                double sx = (double)(gx * STRIDE), sy = (double)(gy * STRIDE);
                float ax0 = (float)(sx - 0.5 * wsd);
                float ay0 = (float)(sy - 0.5 * hsd);
                float ax1 = (float)(sx + 0.5 * wsd);
                float ay1 = (float)(sy + 0.5 * hsd);
                double wa = (double)ax1 - (double)ax0, ha = (double)ay1 - (double)ay0;
                double cxa = (double)ax0 + 0.5 * wa, cya = (double)ay0 + 0.5 * ha;
                double dwv = fmin(rg2, 4.135166556742356);
                double dhv = fmin(rg3, 4.135166556742356);
                double cx = rg0 * wa + cxa, cy = rg1 * ha + cya;
                double w = exp(dwv) * wa, h = exp(dhv) * ha;
                double x0 = cx - 0.5 * w, y0 = cy - 0.5 * h;
                double x1 = cx + 0.5 * w, y1 = cy + 0.5 * h;
                x0 = fmin(fmax(x0, 0.0), 1216.0);
                y0 = fmin(fmax(y0, 0.0), 800.0);
                x1 = fmin(fmax(x1, 0.0), 1216.0);
                y1 = fmin(fmax(y1, 0.0), 800.0);
                int gidx = LOFF + (gy * W + gx) * 3 + a;
                scoresA[(size_t)b * ATOTAL + gidx] = (float)score;
                float4 bx = make_float4((float)x0, (float)y0, (float)x1, (float)y1);
                *(float4*)&boxesA[((size_t)b * ATOTAL + gidx) * 4] = bx;
            }
        }
    }
}

// ---------------- per-(batch,level) top-k via 3-pass radix threshold ----------------
__global__ __launch_bounds__(256) void topk_kernel(
    const float* __restrict__ scoresA, const float* __restrict__ boxesA,
    float* __restrict__ selScore, float* __restrict__ selBox,
    int* __restrict__ selValid, int* __restrict__ selAnchor)
{
    const int lvl = blockIdx.x, b = blockIdx.y;
    const int n = dCount[lvl], loff = dLoff[lvl], seg = dSeg[lvl], k = dSegK[lvl];
    const float* sc = scoresA + (size_t)b * ATOTAL + loff;
    const int tid = threadIdx.x;

    float* oS = selScore + b * KSEL;
    float* oB = selBox + (size_t)b * KSEL * 4;
    int* oV = selValid + b * KSEL;
    int* oA = selAnchor + b * KSEL;

    auto emit = [&](int slot, int i) {
        int g = loff + i;
        float s = sc[i];
        float4 bx = *(const float4*)&boxesA[((size_t)b * ATOTAL + g) * 4];
        oS[seg + slot] = s;
        *(float4*)&oB[(size_t)(seg + slot) * 4] = bx;
        oV[seg + slot] = ((bx.z - bx.x) >= 1e-3f && (bx.w - bx.y) >= 1e-3f) ? 1 : 0;
        oA[seg + slot] = g;
    };

    if (n <= k) {
        for (int i = tid; i < n; i += 256) emit(i, i);
        return;
    }

    __shared__ uint hist[2048];
    __shared__ uint sh_bin, sh_krem;
    __shared__ uint cntG, cntE;
    __shared__ int stash[64];

    uint krem = (uint)k;
    uint prefix = 0;
    for (int pass = 0; pass < 3; ++pass) {
        for (int e = tid; e < 2048; e += 256) hist[e] = 0;
        __syncthreads();
        for (int i = tid; i < n; i += 256) {
            uint key = fkey(sc[i]);
            uint bin; bool sel;
            if (pass == 0)      { sel = true;                      bin = key >> 21; }
            else if (pass == 1) { sel = ((key >> 21) == prefix);   bin = (key >> 10) & 0x7FFu; }
            else                { sel = ((key >> 10) == prefix);   bin = key & 0x3FFu; }
            if (sel) atomicAdd(&hist[bin], 1u);
        }
        __syncthreads();
        if (tid == 0) {
            int nb = (pass == 2) ? 1024 : 2048;
            uint c = 0;
            for (int x = nb - 1; x >= 0; --x) {
                uint h = hist[x];
                if (c + h >= krem) { sh_bin = (uint)x; sh_krem = krem - c; break; }
                c += h;
            }
        }
        __syncthreads();
        uint bin = sh_bin; krem = sh_krem;
        if (pass == 0)      prefix = bin;
        else if (pass == 1) prefix = (prefix << 11) | bin;
        else                prefix = (prefix << 10) | bin;
        __syncthreads();
    }
    const uint T = prefix;
    const uint need_eq = krem;
    if (tid == 0) { cntG = 0; cntE = 0; }
    __syncthreads();
    for (int i = tid; i < n; i += 256) {
        uint key = fkey(sc[i]);
        if (key > T) {
            uint pos = atomicAdd(&cntG, 1u);
            emit((int)pos, i);
        } else if (key == T) {
            uint e = atomicAdd(&cntE, 1u);
            if (e < 64) stash[e] = i;
        }
    }
    __syncthreads();
    if (tid == 0) {
        uint ne = cntE < 64u ? cntE : 64u;
        uint base = cntG;   // == k - need_eq
        for (uint t2 = 0; t2 < need_eq; ++t2) {
            int best = -1, bj = -1;
            for (uint j2 = 0; j2 < ne; ++j2) {
                int v = stash[j2];
                if (v >= 0 && (best < 0 || v < best)) { best = v; bj = j2; }
            }
            if (bj >= 0) { stash[bj] = -1; emit((int)(base + t2), best); }
            else emit((int)(base + t2), 0);   // pathological fallback, never expected
        }
    }
}

// ---------------- per-batch descending sort (score, then anchor-idx asc) ----------------
__global__ __launch_bounds__(1024) void sort_kernel(
    const float* __restrict__ selScore, const float* __restrict__ selBox,
    const int* __restrict__ selValid, const int* __restrict__ selAnchor,
    int* __restrict__ sortedSlot, float* __restrict__ sortedBoxOff,
    ull* __restrict__ validMask)
{
    const int b = blockIdx.x, tid = threadIdx.x;
    __shared__ ull  skey[8192];
    __shared__ uint spay[8192];
    __shared__ ull  svm[NW];

    for (int i = tid; i < 8192; i += 1024) {
        ull kk2; uint pp;
        if (i < KSEL) {
            float s = selScore[b * KSEL + i];
            int v = selValid[b * KSEL + i];
            uint k32 = v ? fkey(s) : 0x007FFFFFu;   // invalid => key(-inf)
            uint a32 = 0xFFFFFFFFu - (uint)selAnchor[b * KSEL + i];
            kk2 = ((ull)k32 << 32) | a32; pp = (uint)i;
        } else { kk2 = 0ull; pp = 0xFFFFFFFFu; }
        skey[i] = kk2; spay[i] = pp;
    }
    __syncthreads();
    for (uint kk = 2; kk <= 8192; kk <<= 1) {
        for (uint j = kk >> 1; j > 0; j >>= 1) {
            for (int i = tid; i < 8192; i += 1024) {
                uint ixj = (uint)i ^ j;
                if (ixj > (uint)i) {
                    bool up = ((((uint)i) & kk) == 0);
                    ull a = skey[i], c = skey[ixj];
                    bool sw = up ? (a < c) : (a > c);   // flipped comparators -> descending
                    if (sw) {
                        skey[i] = c; skey[ixj] = a;
                        uint tp = spay[i]; spay[i] = spay[ixj]; spay[ixj] = tp;
                    }
                }
            }
            __syncthreads();
        }
    }
    for (int i = tid; i < NW; i += 1024) svm[i] = 0ull;
    __syncthreads();
    for (int i = tid; i < KSEL; i += 1024) {
        uint slot = spay[i];
        sortedSlot[b * KSEL + i] = (int)slot;
        int v = selValid[b * KSEL + slot];
        if (v) atomicOr(&svm[i >> 6], 1ull << (i & 63));
        int lvl = (int)slot / 1000;
        float off = 1217.0f * (float)lvl;
        float4 bx = *(const float4*)&selBox[((size_t)b * KSEL + slot) * 4];
        bx.x += off; bx.y += off; bx.z += off; bx.w += off;
        *(float4*)&sortedBoxOff[((size_t)b * KSEL + i) * 4] = bx;
    }
    __syncthreads();
    for (int i = tid; i < NW; i += 1024) validMask[b * NW + i] = svm[i];
}

// ---------------- NMS pairwise suppression bitmask ----------------
__global__ __launch_bounds__(64) void nms_mask(const float* __restrict__ sortedBoxOff,
                                               ull* __restrict__ mat)
{
    const int jb = blockIdx.x, ib = blockIdx.y, b = blockIdx.z;
    const int tid = threadIdx.x;
    __shared__ float4 bj[64];
    __shared__ float  aj[64];
    const int j0 = jb * 64;
    const int jn = (KSEL - j0) < 64 ? (KSEL - j0) : 64;
    if (tid < jn) {
        float4 v = *(const float4*)&sortedBoxOff[((size_t)b * KSEL + j0 + tid) * 4];
        bj[tid] = v; aj[tid] = (v.z - v.x) * (v.w - v.y);
    }
    __syncthreads();
    const int i = ib * 64 + tid;
    if (i >= KSEL) return;
    float4 bi = *(const float4*)&sortedBoxOff[((size_t)b * KSEL + i) * 4];
    float ai = (bi.z - bi.x) * (bi.w - bi.y);
    ull m = 0ull;
    for (int jj = 0; jj < jn; ++jj) {
        int j = j0 + jj;
        if (j <= i) continue;
        float4 bb = bj[jj];
        float ltx = fmaxf(bi.x, bb.x), lty = fmaxf(bi.y, bb.y);
        float rbx = fminf(bi.z, bb.z), rby = fminf(bi.w, bb.w);
        float wx = fmaxf(rbx - ltx, 0.f), wy = fmaxf(rby - lty, 0.f);
        float inter = wx * wy;
        float iou = inter / (ai + aj[jj] - inter + 1e-9f);
        if (iou > 0.7f) m |= (1ull << jj);
    }
    mat[((size_t)b * KSEL + i) * NW + jb] = m;
}

// ---------------- greedy scan (1 wave per batch, register-resident bitset) ----------------
__global__ __launch_bounds__(64) void nms_scan(const ull* __restrict__ mat,
                                               const ull* __restrict__ validMask,
                                               int* __restrict__ keptPos,
                                               int* __restrict__ nkOut)
{
    const int b = blockIdx.x, lane = threadIdx.x;
    ull v0 = validMask[b * NW + lane];
    ull v1 = (lane < NW - 64) ? validMask[b * NW + 64 + lane] : 0ull;
    ull s0 = 0ull, s1 = 0ull;
    int nk = 0;
    const ull* mb = mat + (size_t)b * KSEL * NW;
    const int NG = (KSEL + 7) / 8;
    for (int g = 0; g < NG; ++g) {
        ull rA[8], rB[8];
#pragma unroll
        for (int d = 0; d < 8; ++d) {
            int i = g * 8 + d;
            if (i < KSEL) {
                rA[d] = mb[(size_t)i * NW + lane];
                rB[d] = (lane < NW - 64) ? mb[(size_t)i * NW + 64 + lane] : 0ull;
            } else { rA[d] = 0ull; rB[d] = 0ull; }
        }
#pragma unroll
        for (int d = 0; d < 8; ++d) {
            int i = g * 8 + d;
            if (i >= KSEL) break;
            int wi = i >> 6;
            ull a0 = v0 & ~s0, a1 = v1 & ~s1;
            ull aw = (wi < 64) ? __shfl(a0, wi, 64) : __shfl(a1, wi - 64, 64);
            if ((aw >> (i & 63)) & 1ull) {
                s0 |= rA[d]; s1 |= rB[d];
                if (lane == 0) keptPos[b * POST_NMS + nk] = i;
                ++nk;
                if (nk == POST_NMS) { if (lane == 0) nkOut[b] = nk; return; }
            }
        }
    }
    if (lane == 0) nkOut[b] = nk;
}

// ---------------- final output ----------------
__global__ __launch_bounds__(256) void out_kernel(
    const int* __restrict__ keptPos, const int* __restrict__ nkOut,
    const int* __restrict__ sortedSlot,
    const float* __restrict__ selBox, const float* __restrict__ selScore,
    float* __restrict__ out)
{
    int t = blockIdx.x * 256 + threadIdx.x;
    if (t >= BATCH * POST_NMS) return;
    int b = t / POST_NMS, row = t - b * POST_NMS;
    float4 bx = make_float4(0.f, 0.f, 0.f, 0.f);
    float sc = -1e9f;
    if (row < nkOut[b]) {
        int i = keptPos[b * POST_NMS + row];
        int slot = sortedSlot[b * KSEL + i];
        bx = *(const float4*)&selBox[((size_t)b * KSEL + slot) * 4];
        sc = selScore[b * KSEL + slot];
    }
    *(float4*)&out[(size_t)t * 4] = bx;
    out[BATCH * POST_NMS * 4 + t] = sc;
}

// ---------------- host launch ----------------
extern "C" void kernel_launch(void* const* d_in, const int* in_sizes, int n_in,
                              void* d_out, int out_size, void* d_ws, size_t ws_size,
                              hipStream_t stream)
{
    (void)in_sizes; (void)n_in; (void)out_size; (void)ws_size;
    const float* feat[5] = {(const float*)d_in[0], (const float*)d_in[1],
                            (const float*)d_in[2], (const float*)d_in[3],
                            (const float*)d_in[4]};
    const float* conv_w = (const float*)d_in[5];
    const float* conv_b = (const float*)d_in[6];
    const float* cls_w  = (const float*)d_in[7];
    const float* cls_b  = (const float*)d_in[8];
    const float* box_w  = (const float*)d_in[9];
    const float* box_b  = (const float*)d_in[10];
    float* out = (float*)d_out;

    char* ws = (char*)d_ws;
    size_t off = 0;
    auto carve = [&](size_t bytes) -> void* {
        void* p = (void*)(ws + off);
        off += (bytes + 255) & ~(size_t)255;
        return p;
    };
    float* wT2         = (float*)carve((size_t)2 * 2304 * 128 * 4);
    float* scoresA     = (float*)carve((size_t)BATCH * ATOTAL * 4);
    float* boxesA      = (float*)carve((size_t)BATCH * ATOTAL * 16);
    float* selScore    = (float*)carve((size_t)BATCH * KSEL * 4);
    float* selBox      = (float*)carve((size_t)BATCH * KSEL * 16);
    int*   selValid    = (int*)  carve((size_t)BATCH * KSEL * 4);
    int*   selAnchor   = (int*)  carve((size_t)BATCH * KSEL * 4);
    int*   sortedSlot  = (int*)  carve((size_t)BATCH * KSEL * 4);
    float* sortedBoxOff= (float*)carve((size_t)BATCH * KSEL * 16);
    ull*   validMask   = (ull*)  carve((size_t)BATCH * NW * 8);
    ull*   mat         = (ull*)  carve((size_t)BATCH * KSEL * NW * 8);
    int*   keptPos     = (int*)  carve((size_t)BATCH * POST_NMS * 4);
    int*   nkOut       = (int*)  carve(64);

    wt_kernel<<<2304, 256, 0, stream>>>(conv_w, wT2);

    // one dispatch: all 5 levels x 2 batches (656 tiles x 2)
    conv_fused_all<<<dim3(656, BATCH), 256, 0, stream>>>(
        feat[0], feat[1], feat[2], feat[3], feat[4], wT2, conv_b,
        cls_w, cls_b, box_w, box_b, scoresA, boxesA);

    topk_kernel<<<dim3(5, BATCH), 256, 0, stream>>>(scoresA, boxesA, selScore, selBox, selValid, selAnchor);
    sort_kernel<<<dim3(BATCH), 1024, 0, stream>>>(selScore, selBox, selValid, selAnchor, sortedSlot, sortedBoxOff, validMask);
    nms_mask<<<dim3(NW, NW, BATCH), 64, 0, stream>>>(sortedBoxOff, mat);
    nms_scan<<<dim3(BATCH), 64, 0, stream>>>(mat, validMask, keptPos, nkOut);
    out_kernel<<<dim3((BATCH * POST_NMS + 255) / 256), 256, 0, stream>>>(keptPos, nkOut, sortedSlot, selBox, selScore, out);
}

// Round 7
// 3268.924 us; speedup vs baseline: 11.3654x; 1.2227x over previous
//
#include <hip/hip_runtime.h>
#include <stdint.h>
#include <math.h>

typedef unsigned int uint;
typedef unsigned short ushort;
typedef unsigned long long ull;
typedef __attribute__((ext_vector_type(8))) short bf16x8;
typedef __attribute__((ext_vector_type(4))) float f32x4;

#define BATCH 2
#define ATOTAL 242991
#define KSEL 4741
#define NW 75
#define POST_NMS 1000
#define WB_ELEMS (72*2*3*8*64*8)   // 1,769,472 u16 = 3.5 MB

// runtime-indexed device copies
__device__ __constant__ int dLoff[5]  = {0,182400,228000,239400,242250};
__device__ __constant__ int dCount[5] = {182400,45600,11400,2850,741};
__device__ __constant__ int dSeg[5]   = {0,1000,2000,3000,4000};
__device__ __constant__ int dSegK[5]  = {1000,1000,1000,1000,741};
__device__ __constant__ int dHc[5]     = {200,100,50,25,13};
__device__ __constant__ int dWc[5]     = {304,152,76,38,19};
__device__ __constant__ int dTilesX[5] = {19,10,5,3,2};
__device__ __constant__ int dCumT[6]   = {0,475,605,640,652,656};
__device__ __constant__ int dStrideC[5]= {4,8,16,32,64};
__device__ __constant__ int dSizeC[5]  = {32,64,128,256,512};

__device__ __forceinline__ uint fkey(float f) {
    uint u = __float_as_uint(f);
    return (u & 0x80000000u) ? ~u : (u | 0x80000000u);
}
__device__ __forceinline__ ushort bfrne(float x) {
    uint u = __float_as_uint(x);
    uint r = (u + 0x7FFFu + ((u >> 16) & 1u)) >> 16;
    return (ushort)r;
}
__device__ __forceinline__ float bf2f(ushort h) {
    return __uint_as_float(((uint)h) << 16);
}

// ---------------- weight gen: conv_w [O=256][IC=256][3][3] -> wB fragment-ordered bf16x3 ----
// layout: [step72=(icblk*9+dydx)][ocg2][pl3][nt8][lane64][e8] u16
__global__ __launch_bounds__(256) void wt_kernel(const float* __restrict__ conv_w,
                                                 ushort* __restrict__ wB) {
    int t = blockIdx.x * 256 + threadIdx.x;
    if (t >= WB_ELEMS) return;
    int e    = t & 7;
    int lane = (t >> 3) & 63;
    int nt   = (t >> 9) & 7;
    int r12  = t >> 12;
    int pl   = r12 % 3;
    int r2   = r12 / 3;
    int ocg  = r2 & 1;
    int step = r2 >> 1;            // 0..71
    int icblk = step / 9, dydx = step - icblk * 9;
    int oc = ocg * 128 + nt * 16 + (lane & 15);
    int ic = icblk * 32 + ((lane >> 4) << 3) + e;
    float v = conv_w[(size_t)oc * 2304 + ic * 9 + dydx];
    ushort h = bfrne(v);
    float vm = v - bf2f(h);
    ushort m = bfrne(vm);
    ushort l = bfrne(vm - bf2f(m));
    wB[t] = (pl == 0) ? h : ((pl == 1) ? m : l);
}

// ---------------- MFMA conv3x3 (bf16x3 split, 6 products) + relu + f64 heads + f64 decode ----
// grid (656, 2). tile 8 rows x 16 cols = 128 px. 4 waves: wave=(wm,wn), each 4mt x 4nt.
// mfma_f32_16x16x32_bf16: A lane l: A[i=l&15][k=8*(l>>4)+e]; B lane l: B[k][j=l&15];
// D lane l reg r: D[i=4*(l>>4)+r][j=l&15].  (layouts per cdna4 guide m89/m91)
__global__ __launch_bounds__(256) void conv_mfma_all(
    const float* __restrict__ f0, const float* __restrict__ f1,
    const float* __restrict__ f2, const float* __restrict__ f3,
    const float* __restrict__ f4, const ushort* __restrict__ wB,
    const float* __restrict__ conv_b,
    const float* __restrict__ cls_w, const float* __restrict__ cls_b,
    const float* __restrict__ box_w, const float* __restrict__ box_b,
    float* __restrict__ scoresA, float* __restrict__ boxesA)
{
    const int bidx = blockIdx.x;
    const int b    = blockIdx.y;
    const int tid  = threadIdx.x;

    int lvl = 0;
#pragma unroll
    for (int l = 1; l < 5; ++l) if (bidx >= dCumT[l]) lvl = l;
    const int tile   = bidx - dCumT[lvl];
    const int H      = dHc[lvl], W = dWc[lvl];
    const int TILESX = dTilesX[lvl];
    const int ty0    = (tile / TILESX) * 8;
    const int tx0    = (tile % TILESX) * 16;
    const int HW     = H * W;
    const float* feat = (lvl == 0) ? f0 : (lvl == 1) ? f1 : (lvl == 2) ? f2 : (lvl == 3) ? f3 : f4;
    const float* fb = feat + (size_t)b * 256 * HW;

    __shared__ __align__(16) char uni[59136];
    ushort* halo = (ushort*)uni;                 // [3pl][5760] u16 = 34560 B
    ushort* ldsB = (ushort*)(uni + 34560);       // [3pl][8nt][64lane][8e] = 24576 B
    float*  tS   = (float*)uni;                  // 32768 B (aliases halo, conv done)
    float*  hw2  = (float*)(uni + 32768);        // 4096 B
    double* houtD= (double*)uni;                 // 16384 B (aliases tS, slabs done)

    const int lane = tid & 63, wave = tid >> 6;
    const int wm = wave >> 1, wn = wave & 1;
    const int g = lane >> 4, col = lane & 15;
    const int laneA = g * 1440 + col * 8;        // u16 idx, lane-constant part

    double hacc[8] = {0,0,0,0,0,0,0,0};

#pragma unroll 1
    for (int ocg = 0; ocg < 2; ++ocg) {
        f32x4 acc[4][4];
#pragma unroll
        for (int mi = 0; mi < 4; ++mi)
#pragma unroll
            for (int ni = 0; ni < 4; ++ni)
                acc[mi][ni] = (f32x4){0.f, 0.f, 0.f, 0.f};

#pragma unroll 1
        for (int icblk = 0; icblk < 8; ++icblk) {
            __syncthreads();   // prior A/B-frag reads done before halo overwrite
            // ---- stage halo: 32 ic x 10 rows x 18 cols, 3 bf16 planes ----
#pragma unroll 1
            for (int j = 0; j < 23; ++j) {
                int e = tid + j * 256;
                if (e < 5760) {
                    int ic = e / 180; int rem = e - ic * 180;
                    int hrow = rem / 18; int hcol = rem - hrow * 18;
                    int gy = ty0 + hrow - 1, gx = tx0 + hcol - 1;
                    float v = 0.f;
                    if (gy >= 0 && gy < H && gx >= 0 && gx < W)
                        v = fb[(size_t)(icblk * 32 + ic) * HW + gy * W + gx];
                    ushort h = bfrne(v);
                    float vm = v - bf2f(h);
                    ushort m = bfrne(vm);
                    ushort l = bfrne(vm - bf2f(m));
                    int li = (((ic >> 3) * 10 + hrow) * 18 + hcol) * 8 + (ic & 7);
                    halo[li] = h; halo[5760 + li] = m; halo[11520 + li] = l;
                }
            }
#pragma unroll 1
            for (int dydx = 0; dydx < 9; ++dydx) {
                const int dy = dydx / 3, dx = dydx - dy * 3;
                __syncthreads();   // prior compute's ldsB reads done (also publishes halo)
                // ---- stage B: 24576 B linear copy (fragment-ordered) ----
                {
                    const uint4* gq = (const uint4*)(wB + ((size_t)(icblk * 9 + dydx) * 2 + ocg) * 12288);
                    uint4* lq = (uint4*)ldsB;
                    uint4 v0 = gq[tid];        uint4 v1 = gq[tid + 256];
                    uint4 v2 = gq[tid + 512];  uint4 v3 = gq[tid + 768];
                    uint4 v4 = gq[tid + 1024]; uint4 v5 = gq[tid + 1280];
                    lq[tid] = v0;        lq[tid + 256] = v1;
                    lq[tid + 512] = v2;  lq[tid + 768] = v3;
                    lq[tid + 1024] = v4; lq[tid + 1280] = v5;
                }
                __syncthreads();   // B visible
                // ---- A fragments (3 planes x 4 m-tiles) ----
                bf16x8 A[3][4];
                const int abase = laneA + dx * 8 + (4 * wm + dy) * 144;
#pragma unroll
                for (int pl = 0; pl < 3; ++pl)
#pragma unroll
                    for (int mi = 0; mi < 4; ++mi)
                        A[pl][mi] = *(const bf16x8*)(halo + pl * 5760 + abase + mi * 144);
                // ---- MFMAs: per nt read B 3 planes, 6 products x 4 mi ----
#pragma unroll
                for (int ni = 0; ni < 4; ++ni) {
                    const int nt = 4 * wn + ni;
                    bf16x8 Bh = *(const bf16x8*)(ldsB + ((0 * 8 + nt) * 64 + lane) * 8);
                    bf16x8 Bm = *(const bf16x8*)(ldsB + ((1 * 8 + nt) * 64 + lane) * 8);
                    bf16x8 Bl = *(const bf16x8*)(ldsB + ((2 * 8 + nt) * 64 + lane) * 8);
#pragma unroll
                    for (int mi = 0; mi < 4; ++mi) {
                        f32x4 c = acc[mi][ni];
                        c = __builtin_amdgcn_mfma_f32_16x16x32_bf16(A[0][mi], Bh, c, 0, 0, 0);
                        c = __builtin_amdgcn_mfma_f32_16x16x32_bf16(A[0][mi], Bm, c, 0, 0, 0);
                        c = __builtin_amdgcn_mfma_f32_16x16x32_bf16(A[1][mi], Bh, c, 0, 0, 0);
                        c = __builtin_amdgcn_mfma_f32_16x16x32_bf16(A[0][mi], Bl, c, 0, 0, 0);
                        c = __builtin_amdgcn_mfma_f32_16x16x32_bf16(A[1][mi], Bm, c, 0, 0, 0);
                        c = __builtin_amdgcn_mfma_f32_16x16x32_bf16(A[2][mi], Bh, c, 0, 0, 0);
                        acc[mi][ni] = c;
                    }
                }
            }
        }
        __syncthreads();   // all halo/ldsB reads done -> tS may overwrite
        // ---- writeout + f64 head contraction, 2 slabs of 64 oc (oc ascending) ----
        float cb[4];
#pragma unroll
        for (int ni = 0; ni < 4; ++ni)
            cb[ni] = conv_b[ocg * 128 + (4 * wn + ni) * 16 + col];

#pragma unroll 1
        for (int s2 = 0; s2 < 2; ++s2) {
            if (wn == s2) {
#pragma unroll
                for (int mi = 0; mi < 4; ++mi) {
#pragma unroll
                    for (int r = 0; r < 4; ++r) {
                        int px = (4 * wm + mi) * 16 + 4 * g + r;
                        int sw = px & 15;
#pragma unroll
                        for (int ni = 0; ni < 4; ++ni) {
                            int slot = (ni * 4 + (col >> 2)) ^ sw;
                            tS[px * 64 + slot * 4 + (col & 3)] =
                                fmaxf(acc[mi][ni][r] + cb[ni], 0.f);
                        }
                    }
                }
            }
            // stage head weights for this 64-oc slab
            {
                const int oc2 = tid >> 2;
                const int h0  = (tid & 3) * 4;
                const int oc  = ocg * 128 + s2 * 64 + oc2;
                float vv[4];
#pragma unroll
                for (int q = 0; q < 4; ++q) {
                    int h = h0 + q;
                    vv[q] = (h < 3) ? cls_w[h * 256 + oc]
                          : (h < 15) ? box_w[(h - 3) * 256 + oc] : 0.f;
                }
                *(float4*)&hw2[oc2 * 16 + h0] = make_float4(vv[0], vv[1], vv[2], vv[3]);
            }
            __syncthreads();
            // accumulate: px = tid&127, head-half = tid>>7 (oc ascending within slab)
            {
                const int px = tid & 127;
                const int hh = tid >> 7;
                const int sw = px & 15;
#pragma unroll 1
                for (int j4 = 0; j4 < 16; ++j4) {
                    float4 t4 = *(const float4*)&tS[px * 64 + (j4 ^ sw) * 4];
                    float tv[4] = {t4.x, t4.y, t4.z, t4.w};
#pragma unroll
                    for (int jj = 0; jj < 4; ++jj) {
                        const float* hb = &hw2[(j4 * 4 + jj) * 16 + hh * 8];
                        float4 h0 = *(const float4*)hb;
                        float4 h1 = *(const float4*)(hb + 4);
                        double tv_d = (double)tv[jj];
                        hacc[0] += tv_d * (double)h0.x;
                        hacc[1] += tv_d * (double)h0.y;
                        hacc[2] += tv_d * (double)h0.z;
                        hacc[3] += tv_d * (double)h0.w;
                        hacc[4] += tv_d * (double)h1.x;
                        hacc[5] += tv_d * (double)h1.y;
                        hacc[6] += tv_d * (double)h1.z;
                        hacc[7] += tv_d * (double)h1.w;
                    }
                }
            }
            __syncthreads();   // slab reads done before next slab overwrites tS
        }
    }

    // ---- write head outputs to LDS (f64) ----
    {
        const int px = tid & 127;
        const int hh = tid >> 7;
#pragma unroll
        for (int j = 0; j < 8; ++j) houtD[px * 16 + hh * 8 + j] = hacc[j];
    }
    __syncthreads();

    // ---- decode + clip in f64, store f32 (unchanged from passing config) ----
    if (tid < 128) {
        const int px = tid;
        const int gy = ty0 + (px >> 4);
        const int gx = tx0 + (px & 15);
        if (gy < H && gx < W) {
            const int STRIDE = dStrideC[lvl];
            const int SZ     = dSizeC[lvl];
            const int LOFF   = dLoff[lvl];
#pragma unroll 1
            for (int a = 0; a < 3; ++a) {
                double score = houtD[px * 16 + a] + (double)cls_b[a];
                double rg0 = houtD[px * 16 + 3 + a * 4 + 0] + (double)box_b[a * 4 + 0];
                double rg1 = houtD[px * 16 + 3 + a * 4 + 1] + (double)box_b[a * 4 + 1];
                double rg2 = houtD[px * 16 + 3 + a * 4 + 2] + (double)box_b[a * 4 + 2];
                double rg3 = houtD[px * 16 + 3 + a * 4 + 3] + (double)box_b[a * 4 + 3];
                double ratio = (a == 0) ? 0.5 : ((a == 1) ? 1.0 : 2.0);
                double hr = sqrt(ratio), wr = 1.0 / hr;
                double wsd = wr * (double)SZ, hsd = hr * (double)SZ;
                double sx = (double)(gx * STRIDE), sy = (double)(gy * STRIDE);
                float ax0 = (float)(sx - 0.5 * wsd);
                float ay0 = (float)(sy - 0.5 * hsd);
                float ax1 = (float)(sx + 0.5 * wsd);
                float ay1 = (float)(sy + 0.5 * hsd);
                double wa = (double)ax1 - (double)ax0, ha = (double)ay1 - (double)ay0;
                double cxa = (double)ax0 + 0.5 * wa, cya = (double)ay0 + 0.5 * ha;
                double dwv = fmin(rg2, 4.135166556742356);
                double dhv = fmin(rg3, 4.135166556742356);
                double cx = rg0 * wa + cxa, cy = rg1 * ha + cya;
                double w = exp(dwv) * wa, h = exp(dhv) * ha;
                double x0 = cx - 0.5 * w, y0 = cy - 0.5 * h;
                double x1 = cx + 0.5 * w, y1 = cy + 0.5 * h;
                x0 = fmin(fmax(x0, 0.0), 1216.0);
                y0 = fmin(fmax(y0, 0.0), 800.0);
                x1 = fmin(fmax(x1, 0.0), 1216.0);
                y1 = fmin(fmax(y1, 0.0), 800.0);
                int gidx = LOFF + (gy * W + gx) * 3 + a;
                scoresA[(size_t)b * ATOTAL + gidx] = (float)score;
                float4 bx = make_float4((float)x0, (float)y0, (float)x1, (float)y1);
                *(float4*)&boxesA[((size_t)b * ATOTAL + gidx) * 4] = bx;
            }
        }
    }
}

// ---------------- per-(batch,level) top-k via 3-pass radix threshold ----------------
__global__ __launch_bounds__(256) void topk_kernel(
    const float* __restrict__ scoresA, const float* __restrict__ boxesA,
    float* __restrict__ selScore, float* __restrict__ selBox,
    int* __restrict__ selValid, int* __restrict__ selAnchor)
{
    const int lvl = blockIdx.x, b = blockIdx.y;
    const int n = dCount[lvl], loff = dLoff[lvl], seg = dSeg[lvl], k = dSegK[lvl];
    const float* sc = scoresA + (size_t)b * ATOTAL + loff;
    const int tid = threadIdx.x;

    float* oS = selScore + b * KSEL;
    float* oB = selBox + (size_t)b * KSEL * 4;
    int* oV = selValid + b * KSEL;
    int* oA = selAnchor + b * KSEL;

    auto emit = [&](int slot, int i) {
        int g = loff + i;
        float s = sc[i];
        float4 bx = *(const float4*)&boxesA[((size_t)b * ATOTAL + g) * 4];
        oS[seg + slot] = s;
        *(float4*)&oB[(size_t)(seg + slot) * 4] = bx;
        oV[seg + slot] = ((bx.z - bx.x) >= 1e-3f && (bx.w - bx.y) >= 1e-3f) ? 1 : 0;
        oA[seg + slot] = g;
    };

    if (n <= k) {
        for (int i = tid; i < n; i += 256) emit(i, i);
        return;
    }

    __shared__ uint hist[2048];
    __shared__ uint sh_bin, sh_krem;
    __shared__ uint cntG, cntE;
    __shared__ int stash[64];

    uint krem = (uint)k;
    uint prefix = 0;
    for (int pass = 0; pass < 3; ++pass) {
        for (int e = tid; e < 2048; e += 256) hist[e] = 0;
        __syncthreads();
        for (int i = tid; i < n; i += 256) {
            uint key = fkey(sc[i]);
            uint bin; bool sel;
            if (pass == 0)      { sel = true;                      bin = key >> 21; }
            else if (pass == 1) { sel = ((key >> 21) == prefix);   bin = (key >> 10) & 0x7FFu; }
            else                { sel = ((key >> 10) == prefix);   bin = key & 0x3FFu; }
            if (sel) atomicAdd(&hist[bin], 1u);
        }
        __syncthreads();
        if (tid == 0) {
            int nb = (pass == 2) ? 1024 : 2048;
            uint c = 0;
            for (int x = nb - 1; x >= 0; --x) {
                uint h = hist[x];
                if (c + h >= krem) { sh_bin = (uint)x; sh_krem = krem - c; break; }
                c += h;
            }
        }
        __syncthreads();
        uint bin = sh_bin; krem = sh_krem;
        if (pass == 0)      prefix = bin;
        else if (pass == 1) prefix = (prefix << 11) | bin;
        else                prefix = (prefix << 10) | bin;
        __syncthreads();
    }
    const uint T = prefix;
    const uint need_eq = krem;
    if (tid == 0) { cntG = 0; cntE = 0; }
    __syncthreads();
    for (int i = tid; i < n; i += 256) {
        uint key = fkey(sc[i]);
        if (key > T) {
            uint pos = atomicAdd(&cntG, 1u);
            emit((int)pos, i);
        } else if (key == T) {
            uint e = atomicAdd(&cntE, 1u);
            if (e < 64) stash[e] = i;
        }
    }
    __syncthreads();
    if (tid == 0) {
        uint ne = cntE < 64u ? cntE : 64u;
        uint base = cntG;   // == k - need_eq
        for (uint t2 = 0; t2 < need_eq; ++t2) {
            int best = -1, bj = -1;
            for (uint j2 = 0; j2 < ne; ++j2) {
                int v = stash[j2];
                if (v >= 0 && (best < 0 || v < best)) { best = v; bj = j2; }
            }
            if (bj >= 0) { stash[bj] = -1; emit((int)(base + t2), best); }
            else emit((int)(base + t2), 0);
        }
    }
}

// ---------------- per-batch descending sort (score, then anchor-idx asc) ----------------
__global__ __launch_bounds__(1024) void sort_kernel(
    const float* __restrict__ selScore, const float* __restrict__ selBox,
    const int* __restrict__ selValid, const int* __restrict__ selAnchor,
    int* __restrict__ sortedSlot, float* __restrict__ sortedBoxOff,
    ull* __restrict__ validMask)
{
    const int b = blockIdx.x, tid = threadIdx.x;
    __shared__ ull  skey[8192];
    __shared__ uint spay[8192];
    __shared__ ull  svm[NW];

    for (int i = tid; i < 8192; i += 1024) {
        ull kk2; uint pp;
        if (i < KSEL) {
            float s = selScore[b * KSEL + i];
            int v = selValid[b * KSEL + i];
            uint k32 = v ? fkey(s) : 0x007FFFFFu;
            uint a32 = 0xFFFFFFFFu - (uint)selAnchor[b * KSEL + i];
            kk2 = ((ull)k32 << 32) | a32; pp = (uint)i;
        } else { kk2 = 0ull; pp = 0xFFFFFFFFu; }
        skey[i] = kk2; spay[i] = pp;
    }
    __syncthreads();
    for (uint kk = 2; kk <= 8192; kk <<= 1) {
        for (uint j = kk >> 1; j > 0; j >>= 1) {
            for (int i = tid; i < 8192; i += 1024) {
                uint ixj = (uint)i ^ j;
                if (ixj > (uint)i) {
                    bool up = ((((uint)i) & kk) == 0);
                    ull a = skey[i], c = skey[ixj];
                    bool sw = up ? (a < c) : (a > c);
                    if (sw) {
                        skey[i] = c; skey[ixj] = a;
                        uint tp = spay[i]; spay[i] = spay[ixj]; spay[ixj] = tp;
                    }
                }
            }
            __syncthreads();
        }
    }
    for (int i = tid; i < NW; i += 1024) svm[i] = 0ull;
    __syncthreads();
    for (int i = tid; i < KSEL; i += 1024) {
        uint slot = spay[i];
        sortedSlot[b * KSEL + i] = (int)slot;
        int v = selValid[b * KSEL + slot];
        if (v) atomicOr(&svm[i >> 6], 1ull << (i & 63));
        int lvl = (int)slot / 1000;
        float off = 1217.0f * (float)lvl;
        float4 bx = *(const float4*)&selBox[((size_t)b * KSEL + slot) * 4];
        bx.x += off; bx.y += off; bx.z += off; bx.w += off;
        *(float4*)&sortedBoxOff[((size_t)b * KSEL + i) * 4] = bx;
    }
    __syncthreads();
    for (int i = tid; i < NW; i += 1024) validMask[b * NW + i] = svm[i];
}

// ---------------- NMS pairwise suppression bitmask ----------------
__global__ __launch_bounds__(64) void nms_mask(const float* __restrict__ sortedBoxOff,
                                               ull* __restrict__ mat)
{
    const int jb = blockIdx.x, ib = blockIdx.y, b = blockIdx.z;
    const int tid = threadIdx.x;
    __shared__ float4 bj[64];
    __shared__ float  aj[64];
    const int j0 = jb * 64;
    const int jn = (KSEL - j0) < 64 ? (KSEL - j0) : 64;
    if (tid < jn) {
        float4 v = *(const float4*)&sortedBoxOff[((size_t)b * KSEL + j0 + tid) * 4];
        bj[tid] = v; aj[tid] = (v.z - v.x) * (v.w - v.y);
    }
    __syncthreads();
    const int i = ib * 64 + tid;
    if (i >= KSEL) return;
    float4 bi = *(const float4*)&sortedBoxOff[((size_t)b * KSEL + i) * 4];
    float ai = (bi.z - bi.x) * (bi.w - bi.y);
    ull m = 0ull;
    for (int jj = 0; jj < jn; ++jj) {
        int j = j0 + jj;
        if (j <= i) continue;
        float4 bb = bj[jj];
        float ltx = fmaxf(bi.x, bb.x), lty = fmaxf(bi.y, bb.y);
        float rbx = fminf(bi.z, bb.z), rby = fminf(bi.w, bb.w);
        float wx = fmaxf(rbx - ltx, 0.f), wy = fmaxf(rby - lty, 0.f);
        float inter = wx * wy;
        float iou = inter / (ai + aj[jj] - inter + 1e-9f);
        if (iou > 0.7f) m |= (1ull << jj);
    }
    mat[((size_t)b * KSEL + i) * NW + jb] = m;
}

// ---------------- greedy scan (1 wave per batch, register-resident bitset) ----------------
__global__ __launch_bounds__(64) void nms_scan(const ull* __restrict__ mat,
                                               const ull* __restrict__ validMask,
                                               int* __restrict__ keptPos,
                                               int* __restrict__ nkOut)
{
    const int b = blockIdx.x, lane = threadIdx.x;
    ull v0 = validMask[b * NW + lane];
    ull v1 = (lane < NW - 64) ? validMask[b * NW + 64 + lane] : 0ull;
    ull s0 = 0ull, s1 = 0ull;
    int nk = 0;
    const ull* mb = mat + (size_t)b * KSEL * NW;
    const int NG = (KSEL + 7) / 8;
    for (int g = 0; g < NG; ++g) {
        ull rA[8], rB[8];
#pragma unroll
        for (int d = 0; d < 8; ++d) {
            int i = g * 8 + d;
            if (i < KSEL) {
                rA[d] = mb[(size_t)i * NW + lane];
                rB[d] = (lane < NW - 64) ? mb[(size_t)i * NW + 64 + lane] : 0ull;
            } else { rA[d] = 0ull; rB[d] = 0ull; }
        }
#pragma unroll
        for (int d = 0; d < 8; ++d) {
            int i = g * 8 + d;
            if (i >= KSEL) break;
            int wi = i >> 6;
            ull a0 = v0 & ~s0, a1 = v1 & ~s1;
            ull aw = (wi < 64) ? __shfl(a0, wi, 64) : __shfl(a1, wi - 64, 64);
            if ((aw >> (i & 63)) & 1ull) {
                s0 |= rA[d]; s1 |= rB[d];
                if (lane == 0) keptPos[b * POST_NMS + nk] = i;
                ++nk;
                if (nk == POST_NMS) { if (lane == 0) nkOut[b] = nk; return; }
            }
        }
    }
    if (lane == 0) nkOut[b] = nk;
}

// ---------------- final output ----------------
__global__ __launch_bounds__(256) void out_kernel(
    const int* __restrict__ keptPos, const int* __restrict__ nkOut,
    const int* __restrict__ sortedSlot,
    const float* __restrict__ selBox, const float* __restrict__ selScore,
    float* __restrict__ out)
{
    int t = blockIdx.x * 256 + threadIdx.x;
    if (t >= BATCH * POST_NMS) return;
    int b = t / POST_NMS, row = t - b * POST_NMS;
    float4 bx = make_float4(0.f, 0.f, 0.f, 0.f);
    float sc = -1e9f;
    if (row < nkOut[b]) {
        int i = keptPos[b * POST_NMS + row];
        int slot = sortedSlot[b * KSEL + i];
        bx = *(const float4*)&selBox[((size_t)b * KSEL + slot) * 4];
        sc = selScore[b * KSEL + slot];
    }
    *(float4*)&out[(size_t)t * 4] = bx;
    out[BATCH * POST_NMS * 4 + t] = sc;
}

// ---------------- host launch ----------------
extern "C" void kernel_launch(void* const* d_in, const int* in_sizes, int n_in,
                              void* d_out, int out_size, void* d_ws, size_t ws_size,
                              hipStream_t stream)
{
    (void)in_sizes; (void)n_in; (void)out_size; (void)ws_size;
    const float* feat[5] = {(const float*)d_in[0], (const float*)d_in[1],
                            (const float*)d_in[2], (const float*)d_in[3],
                            (const float*)d_in[4]};
    const float* conv_w = (const float*)d_in[5];
    const float* conv_b = (const float*)d_in[6];
    const float* cls_w  = (const float*)d_in[7];
    const float* cls_b  = (const float*)d_in[8];
    const float* box_w  = (const float*)d_in[9];
    const float* box_b  = (const float*)d_in[10];
    float* out = (float*)d_out;

    char* ws = (char*)d_ws;
    size_t off = 0;
    auto carve = [&](size_t bytes) -> void* {
        void* p = (void*)(ws + off);
        off += (bytes + 255) & ~(size_t)255;
        return p;
    };
    ushort* wB         = (ushort*)carve((size_t)WB_ELEMS * 2);
    float* scoresA     = (float*)carve((size_t)BATCH * ATOTAL * 4);
    float* boxesA      = (float*)carve((size_t)BATCH * ATOTAL * 16);
    float* selScore    = (float*)carve((size_t)BATCH * KSEL * 4);
    float* selBox      = (float*)carve((size_t)BATCH * KSEL * 16);
    int*   selValid    = (int*)  carve((size_t)BATCH * KSEL * 4);
    int*   selAnchor   = (int*)  carve((size_t)BATCH * KSEL * 4);
    int*   sortedSlot  = (int*)  carve((size_t)BATCH * KSEL * 4);
    float* sortedBoxOff= (float*)carve((size_t)BATCH * KSEL * 16);
    ull*   validMask   = (ull*)  carve((size_t)BATCH * NW * 8);
    ull*   mat         = (ull*)  carve((size_t)BATCH * KSEL * NW * 8);
    int*   keptPos     = (int*)  carve((size_t)BATCH * POST_NMS * 4);
    int*   nkOut       = (int*)  carve(64);

    wt_kernel<<<(WB_ELEMS + 255) / 256, 256, 0, stream>>>(conv_w, wB);

    conv_mfma_all<<<dim3(656, BATCH), 256, 0, stream>>>(
        feat[0], feat[1], feat[2], feat[3], feat[4], wB, conv_b,
        cls_w, cls_b, box_w, box_b, scoresA, boxesA);

    topk_kernel<<<dim3(5, BATCH), 256, 0, stream>>>(scoresA, boxesA, selScore, selBox, selValid, selAnchor);
    sort_kernel<<<dim3(BATCH), 1024, 0, stream>>>(selScore, selBox, selValid, selAnchor, sortedSlot, sortedBoxOff, validMask);
    nms_mask<<<dim3(NW, NW, BATCH), 64, 0, stream>>>(sortedBoxOff, mat);
    nms_scan<<<dim3(BATCH), 64, 0, stream>>>(mat, validMask, keptPos, nkOut);
    out_kernel<<<dim3((BATCH * POST_NMS + 255) / 256), 256, 0, stream>>>(keptPos, nkOut, sortedSlot, selBox, selScore, out);
}

// Round 8
// 3216.936 us; speedup vs baseline: 11.5490x; 1.0162x over previous
//
#include <hip/hip_runtime.h>
#include <stdint.h>
#include <math.h>

typedef unsigned int uint;
typedef unsigned short ushort;
typedef unsigned long long ull;
typedef __attribute__((ext_vector_type(8))) short bf16x8;
typedef __attribute__((ext_vector_type(4))) float f32x4;

#define BATCH 2
#define ATOTAL 242991
#define KSEL 4741
#define NW 75
#define POST_NMS 1000
#define WB_ELEMS (72*2*3*8*64*8)   // 1,769,472 u16 = 3.5 MB

// runtime-indexed device copies
__device__ __constant__ int dLoff[5]  = {0,182400,228000,239400,242250};
__device__ __constant__ int dCount[5] = {182400,45600,11400,2850,741};
__device__ __constant__ int dSeg[5]   = {0,1000,2000,3000,4000};
__device__ __constant__ int dSegK[5]  = {1000,1000,1000,1000,741};
__device__ __constant__ int dHc[5]     = {200,100,50,25,13};
__device__ __constant__ int dWc[5]     = {304,152,76,38,19};
__device__ __constant__ int dTilesX[5] = {19,10,5,3,2};
__device__ __constant__ int dCumT[6]   = {0,475,605,640,652,656};
__device__ __constant__ int dStrideC[5]= {4,8,16,32,64};
__device__ __constant__ int dSizeC[5]  = {32,64,128,256,512};

__device__ __forceinline__ uint fkey(float f) {
    uint u = __float_as_uint(f);
    return (u & 0x80000000u) ? ~u : (u | 0x80000000u);
}
__device__ __forceinline__ ushort bfrne(float x) {
    uint u = __float_as_uint(x);
    uint r = (u + 0x7FFFu + ((u >> 16) & 1u)) >> 16;
    return (ushort)r;
}
__device__ __forceinline__ float bf2f(ushort h) {
    return __uint_as_float(((uint)h) << 16);
}

// ---------------- weight gen: conv_w [O=256][IC=256][3][3] -> wB fragment-ordered bf16x3 ----
// layout: [step72=(icblk*9+dydx)][ocg2][pl3][nt8][lane64][e8] u16
__global__ __launch_bounds__(256) void wt_kernel(const float* __restrict__ conv_w,
                                                 ushort* __restrict__ wB) {
    int t = blockIdx.x * 256 + threadIdx.x;
    if (t >= WB_ELEMS) return;
    int e    = t & 7;
    int lane = (t >> 3) & 63;
    int nt   = (t >> 9) & 7;
    int r12  = t >> 12;
    int pl   = r12 % 3;
    int r2   = r12 / 3;
    int ocg  = r2 & 1;
    int step = r2 >> 1;            // 0..71
    int icblk = step / 9, dydx = step - icblk * 9;
    int oc = ocg * 128 + nt * 16 + (lane & 15);
    int ic = icblk * 32 + ((lane >> 4) << 3) + e;
    float v = conv_w[(size_t)oc * 2304 + ic * 9 + dydx];
    ushort h = bfrne(v);
    float vm = v - bf2f(h);
    ushort m = bfrne(vm);
    ushort l = bfrne(vm - bf2f(m));
    wB[t] = (pl == 0) ? h : ((pl == 1) ? m : l);
}

// ---------------- MFMA conv3x3 (bf16x3 split, 6 products) + relu + f64 heads + f64 decode ----
// grid (656, 2). tile 8 rows x 16 cols = 128 px. 4 waves: wave=(wm,wn), each 4mt x 4nt.
// Round-8 change (T14): B-slab for step s+1 is global->reg prefetched DURING step s's
// MFMA phase; the barrier/ds_write at step s+1 finds vmcnt already satisfied. Removes
// ~300-900cy of exposed L2/L3 latency per step (144 steps). MFMA order bit-identical.
__global__ __launch_bounds__(256) void conv_mfma_all(
    const float* __restrict__ f0, const float* __restrict__ f1,
    const float* __restrict__ f2, const float* __restrict__ f3,
    const float* __restrict__ f4, const ushort* __restrict__ wB,
    const float* __restrict__ conv_b,
    const float* __restrict__ cls_w, const float* __restrict__ cls_b,
    const float* __restrict__ box_w, const float* __restrict__ box_b,
    float* __restrict__ scoresA, float* __restrict__ boxesA)
{
    const int bidx = blockIdx.x;
    const int b    = blockIdx.y;
    const int tid  = threadIdx.x;

    int lvl = 0;
#pragma unroll
    for (int l = 1; l < 5; ++l) if (bidx >= dCumT[l]) lvl = l;
    const int tile   = bidx - dCumT[lvl];
    const int H      = dHc[lvl], W = dWc[lvl];
    const int TILESX = dTilesX[lvl];
    const int ty0    = (tile / TILESX) * 8;
    const int tx0    = (tile % TILESX) * 16;
    const int HW     = H * W;
    const float* feat = (lvl == 0) ? f0 : (lvl == 1) ? f1 : (lvl == 2) ? f2 : (lvl == 3) ? f3 : f4;
    const float* fb = feat + (size_t)b * 256 * HW;

    __shared__ __align__(16) char uni[59136];
    ushort* halo = (ushort*)uni;                 // [3pl][5760] u16 = 34560 B
    ushort* ldsB = (ushort*)(uni + 34560);       // [3pl][8nt][64lane][8e] = 24576 B
    float*  tS   = (float*)uni;                  // 32768 B (aliases halo, conv done)
    float*  hw2  = (float*)(uni + 32768);        // 4096 B (aliases ldsB head, conv done)
    double* houtD= (double*)uni;                 // 16384 B (aliases tS, slabs done)

    const int lane = tid & 63, wave = tid >> 6;
    const int wm = wave >> 1, wn = wave & 1;
    const int g = lane >> 4, col = lane & 15;
    const int laneA = g * 1440 + col * 8;        // u16 idx, lane-constant part

    double hacc[8] = {0,0,0,0,0,0,0,0};

    // B prefetch registers (6 x uint4 = 24 KB/block slab)
    uint4 Br0, Br1, Br2, Br3, Br4, Br5;
    // prologue: issue loads for (ocg=0, step=0)
    {
        const uint4* gq = (const uint4*)wB;
        Br0 = gq[tid];        Br1 = gq[tid + 256];
        Br2 = gq[tid + 512];  Br3 = gq[tid + 768];
        Br4 = gq[tid + 1024]; Br5 = gq[tid + 1280];
    }

#pragma unroll 1
    for (int ocg = 0; ocg < 2; ++ocg) {
        f32x4 acc[4][4];
#pragma unroll
        for (int mi = 0; mi < 4; ++mi)
#pragma unroll
            for (int ni = 0; ni < 4; ++ni)
                acc[mi][ni] = (f32x4){0.f, 0.f, 0.f, 0.f};

#pragma unroll 1
        for (int s = 0; s < 72; ++s) {
            const int icblk = s / 9;
            const int dydx  = s - icblk * 9;
            const int dy = dydx / 3, dx = dydx - dy * 3;

            __syncthreads();   // prior step's halo/ldsB reads (and epilogue reads) done
            // ---- stage halo at icblk start (32 ic x 10 x 18, 3 bf16 planes) ----
            if (dydx == 0) {
#pragma unroll 1
                for (int j = 0; j < 23; ++j) {
                    int e = tid + j * 256;
                    if (e < 5760) {
                        int ic = e / 180; int rem = e - ic * 180;
                        int hrow = rem / 18; int hcol = rem - hrow * 18;
                        int gy = ty0 + hrow - 1, gx = tx0 + hcol - 1;
                        float v = 0.f;
                        if (gy >= 0 && gy < H && gx >= 0 && gx < W)
                            v = fb[(size_t)(icblk * 32 + ic) * HW + gy * W + gx];
                        ushort h = bfrne(v);
                        float vm = v - bf2f(h);
                        ushort m = bfrne(vm);
                        ushort l = bfrne(vm - bf2f(m));
                        int li = (((ic >> 3) * 10 + hrow) * 18 + hcol) * 8 + (ic & 7);
                        halo[li] = h; halo[5760 + li] = m; halo[11520 + li] = l;
                    }
                }
            }
            // ---- write prefetched B slab to LDS (vmcnt auto-waited; data long arrived) ----
            {
                uint4* lq = (uint4*)ldsB;
                lq[tid] = Br0;        lq[tid + 256] = Br1;
                lq[tid + 512] = Br2;  lq[tid + 768] = Br3;
                lq[tid + 1024] = Br4; lq[tid + 1280] = Br5;
            }
            __syncthreads();   // halo + B visible
            // ---- issue next step's B loads (hidden under MFMA phase below) ----
            {
                int gstep = ocg * 72 + s + 1;   // global step index 1..144
                if (gstep < 144) {
                    int s2 = gstep % 72, og2 = gstep / 72;
                    const uint4* gq = (const uint4*)(wB + ((size_t)(s2 * 2 + og2)) * 12288);
                    Br0 = gq[tid];        Br1 = gq[tid + 256];
                    Br2 = gq[tid + 512];  Br3 = gq[tid + 768];
                    Br4 = gq[tid + 1024]; Br5 = gq[tid + 1280];
                }
            }
            // ---- A fragments (3 planes x 4 m-tiles) ----
            bf16x8 A[3][4];
            const int abase = laneA + dx * 8 + (4 * wm + dy) * 144;
#pragma unroll
            for (int pl = 0; pl < 3; ++pl)
#pragma unroll
                for (int mi = 0; mi < 4; ++mi)
                    A[pl][mi] = *(const bf16x8*)(halo + pl * 5760 + abase + mi * 144);
            // ---- MFMAs: per nt read B 3 planes, 6 products x 4 mi ----
#pragma unroll
            for (int ni = 0; ni < 4; ++ni) {
                const int nt = 4 * wn + ni;
                bf16x8 Bh = *(const bf16x8*)(ldsB + ((0 * 8 + nt) * 64 + lane) * 8);
                bf16x8 Bm = *(const bf16x8*)(ldsB + ((1 * 8 + nt) * 64 + lane) * 8);
                bf16x8 Bl = *(const bf16x8*)(ldsB + ((2 * 8 + nt) * 64 + lane) * 8);
#pragma unroll
                for (int mi = 0; mi < 4; ++mi) {
                    f32x4 c = acc[mi][ni];
                    c = __builtin_amdgcn_mfma_f32_16x16x32_bf16(A[0][mi], Bh, c, 0, 0, 0);
                    c = __builtin_amdgcn_mfma_f32_16x16x32_bf16(A[0][mi], Bm, c, 0, 0, 0);
                    c = __builtin_amdgcn_mfma_f32_16x16x32_bf16(A[1][mi], Bh, c, 0, 0, 0);
                    c = __builtin_amdgcn_mfma_f32_16x16x32_bf16(A[0][mi], Bl, c, 0, 0, 0);
                    c = __builtin_amdgcn_mfma_f32_16x16x32_bf16(A[1][mi], Bm, c, 0, 0, 0);
                    c = __builtin_amdgcn_mfma_f32_16x16x32_bf16(A[2][mi], Bh, c, 0, 0, 0);
                    acc[mi][ni] = c;
                }
            }
        }
        __syncthreads();   // all halo/ldsB reads done -> tS may overwrite
        // ---- writeout + f64 head contraction, 2 slabs of 64 oc (oc ascending) ----
        float cb[4];
#pragma unroll
        for (int ni = 0; ni < 4; ++ni)
            cb[ni] = conv_b[ocg * 128 + (4 * wn + ni) * 16 + col];

#pragma unroll 1
        for (int s2 = 0; s2 < 2; ++s2) {
            if (wn == s2) {
#pragma unroll
                for (int mi = 0; mi < 4; ++mi) {
#pragma unroll
                    for (int r = 0; r < 4; ++r) {
                        int px = (4 * wm + mi) * 16 + 4 * g + r;
                        int sw = px & 15;
#pragma unroll
                        for (int ni = 0; ni < 4; ++ni) {
                            int slot = (ni * 4 + (col >> 2)) ^ sw;
                            tS[px * 64 + slot * 4 + (col & 3)] =
                                fmaxf(acc[mi][ni][r] + cb[ni], 0.f);
                        }
                    }
                }
            }
            // stage head weights for this 64-oc slab
            {
                const int oc2 = tid >> 2;
                const int h0  = (tid & 3) * 4;
                const int oc  = ocg * 128 + s2 * 64 + oc2;
                float vv[4];
#pragma unroll
                for (int q = 0; q < 4; ++q) {
                    int h = h0 + q;
                    vv[q] = (h < 3) ? cls_w[h * 256 + oc]
                          : (h < 15) ? box_w[(h - 3) * 256 + oc] : 0.f;
                }
                *(float4*)&hw2[oc2 * 16 + h0] = make_float4(vv[0], vv[1], vv[2], vv[3]);
            }
            __syncthreads();
            // accumulate: px = tid&127, head-half = tid>>7 (oc ascending within slab)
            {
                const int px = tid & 127;
                const int hh = tid >> 7;
                const int sw = px & 15;
#pragma unroll 1
                for (int j4 = 0; j4 < 16; ++j4) {
                    float4 t4 = *(const float4*)&tS[px * 64 + (j4 ^ sw) * 4];
                    float tv[4] = {t4.x, t4.y, t4.z, t4.w};
#pragma unroll
                    for (int jj = 0; jj < 4; ++jj) {
                        const float* hb = &hw2[(j4 * 4 + jj) * 16 + hh * 8];
                        float4 h0 = *(const float4*)hb;
                        float4 h1 = *(const float4*)(hb + 4);
                        double tv_d = (double)tv[jj];
                        hacc[0] += tv_d * (double)h0.x;
                        hacc[1] += tv_d * (double)h0.y;
                        hacc[2] += tv_d * (double)h0.z;
                        hacc[3] += tv_d * (double)h0.w;
                        hacc[4] += tv_d * (double)h1.x;
                        hacc[5] += tv_d * (double)h1.y;
                        hacc[6] += tv_d * (double)h1.z;
                        hacc[7] += tv_d * (double)h1.w;
                    }
                }
            }
            __syncthreads();   // slab reads done before next slab overwrites tS
        }
    }

    // ---- write head outputs to LDS (f64) ----
    {
        const int px = tid & 127;
        const int hh = tid >> 7;
#pragma unroll
        for (int j = 0; j < 8; ++j) houtD[px * 16 + hh * 8 + j] = hacc[j];
    }
    __syncthreads();

    // ---- decode + clip in f64, store f32 (unchanged from passing config) ----
    if (tid < 128) {
        const int px = tid;
        const int gy = ty0 + (px >> 4);
        const int gx = tx0 + (px & 15);
        if (gy < H && gx < W) {
            const int STRIDE = dStrideC[lvl];
            const int SZ     = dSizeC[lvl];
            const int LOFF   = dLoff[lvl];
#pragma unroll 1
            for (int a = 0; a < 3; ++a) {
                double score = houtD[px * 16 + a] + (double)cls_b[a];
                double rg0 = houtD[px * 16 + 3 + a * 4 + 0] + (double)box_b[a * 4 + 0];
                double rg1 = houtD[px * 16 + 3 + a * 4 + 1] + (double)box_b[a * 4 + 1];
                double rg2 = houtD[px * 16 + 3 + a * 4 + 2] + (double)box_b[a * 4 + 2];
                double rg3 = houtD[px * 16 + 3 + a * 4 + 3] + (double)box_b[a * 4 + 3];
                double ratio = (a == 0) ? 0.5 : ((a == 1) ? 1.0 : 2.0);
                double hr = sqrt(ratio), wr = 1.0 / hr;
                double wsd = wr * (double)SZ, hsd = hr * (double)SZ;
                double sx = (double)(gx * STRIDE), sy = (double)(gy * STRIDE);
                float ax0 = (float)(sx - 0.5 * wsd);
                float ay0 = (float)(sy - 0.5 * hsd);
                float ax1 = (float)(sx + 0.5 * wsd);
                float ay1 = (float)(sy + 0.5 * hsd);
                double wa = (double)ax1 - (double)ax0, ha = (double)ay1 - (double)ay0;
                double cxa = (double)ax0 + 0.5 * wa, cya = (double)ay0 + 0.5 * ha;
                double dwv = fmin(rg2, 4.135166556742356);
                double dhv = fmin(rg3, 4.135166556742356);
                double cx = rg0 * wa + cxa, cy = rg1 * ha + cya;
                double w = exp(dwv) * wa, h = exp(dhv) * ha;
                double x0 = cx - 0.5 * w, y0 = cy - 0.5 * h;
                double x1 = cx + 0.5 * w, y1 = cy + 0.5 * h;
                x0 = fmin(fmax(x0, 0.0), 1216.0);
                y0 = fmin(fmax(y0, 0.0), 800.0);
                x1 = fmin(fmax(x1, 0.0), 1216.0);
                y1 = fmin(fmax(y1, 0.0), 800.0);
                int gidx = LOFF + (gy * W + gx) * 3 + a;
                scoresA[(size_t)b * ATOTAL + gidx] = (float)score;
                float4 bx = make_float4((float)x0, (float)y0, (float)x1, (float)y1);
                *(float4*)&boxesA[((size_t)b * ATOTAL + gidx) * 4] = bx;
            }
        }
    }
}

// ---------------- per-(batch,level) top-k via 3-pass radix threshold ----------------
__global__ __launch_bounds__(256) void topk_kernel(
    const float* __restrict__ scoresA, const float* __restrict__ boxesA,
    float* __restrict__ selScore, float* __restrict__ selBox,
    int* __restrict__ selValid, int* __restrict__ selAnchor)
{
    const int lvl = blockIdx.x, b = blockIdx.y;
    const int n = dCount[lvl], loff = dLoff[lvl], seg = dSeg[lvl], k = dSegK[lvl];
    const float* sc = scoresA + (size_t)b * ATOTAL + loff;
    const int tid = threadIdx.x;

    float* oS = selScore + b * KSEL;
    float* oB = selBox + (size_t)b * KSEL * 4;
    int* oV = selValid + b * KSEL;
    int* oA = selAnchor + b * KSEL;

    auto emit = [&](int slot, int i) {
        int g = loff + i;
        float s = sc[i];
        float4 bx = *(const float4*)&boxesA[((size_t)b * ATOTAL + g) * 4];
        oS[seg + slot] = s;
        *(float4*)&oB[(size_t)(seg + slot) * 4] = bx;
        oV[seg + slot] = ((bx.z - bx.x) >= 1e-3f && (bx.w - bx.y) >= 1e-3f) ? 1 : 0;
        oA[seg + slot] = g;
    };

    if (n <= k) {
        for (int i = tid; i < n; i += 256) emit(i, i);
        return;
    }

    __shared__ uint hist[2048];
    __shared__ uint sh_bin, sh_krem;
    __shared__ uint cntG, cntE;
    __shared__ int stash[64];

    uint krem = (uint)k;
    uint prefix = 0;
    for (int pass = 0; pass < 3; ++pass) {
        for (int e = tid; e < 2048; e += 256) hist[e] = 0;
        __syncthreads();
        for (int i = tid; i < n; i += 256) {
            uint key = fkey(sc[i]);
            uint bin; bool sel;
            if (pass == 0)      { sel = true;                      bin = key >> 21; }
            else if (pass == 1) { sel = ((key >> 21) == prefix);   bin = (key >> 10) & 0x7FFu; }
            else                { sel = ((key >> 10) == prefix);   bin = key & 0x3FFu; }
            if (sel) atomicAdd(&hist[bin], 1u);
        }
        __syncthreads();
        if (tid == 0) {
            int nb = (pass == 2) ? 1024 : 2048;
            uint c = 0;
            for (int x = nb - 1; x >= 0; --x) {
                uint h = hist[x];
                if (c + h >= krem) { sh_bin = (uint)x; sh_krem = krem - c; break; }
                c += h;
            }
        }
        __syncthreads();
        uint bin = sh_bin; krem = sh_krem;
        if (pass == 0)      prefix = bin;
        else if (pass == 1) prefix = (prefix << 11) | bin;
        else                prefix = (prefix << 10) | bin;
        __syncthreads();
    }
    const uint T = prefix;
    const uint need_eq = krem;
    if (tid == 0) { cntG = 0; cntE = 0; }
    __syncthreads();
    for (int i = tid; i < n; i += 256) {
        uint key = fkey(sc[i]);
        if (key > T) {
            uint pos = atomicAdd(&cntG, 1u);
            emit((int)pos, i);
        } else if (key == T) {
            uint e = atomicAdd(&cntE, 1u);
            if (e < 64) stash[e] = i;
        }
    }
    __syncthreads();
    if (tid == 0) {
        uint ne = cntE < 64u ? cntE : 64u;
        uint base = cntG;   // == k - need_eq
        for (uint t2 = 0; t2 < need_eq; ++t2) {
            int best = -1, bj = -1;
            for (uint j2 = 0; j2 < ne; ++j2) {
                int v = stash[j2];
                if (v >= 0 && (best < 0 || v < best)) { best = v; bj = j2; }
            }
            if (bj >= 0) { stash[bj] = -1; emit((int)(base + t2), best); }
            else emit((int)(base + t2), 0);
        }
    }
}

// ---------------- per-batch descending sort (score, then anchor-idx asc) ----------------
__global__ __launch_bounds__(1024) void sort_kernel(
    const float* __restrict__ selScore, const float* __restrict__ selBox,
    const int* __restrict__ selValid, const int* __restrict__ selAnchor,
    int* __restrict__ sortedSlot, float* __restrict__ sortedBoxOff,
    ull* __restrict__ validMask)
{
    const int b = blockIdx.x, tid = threadIdx.x;
    __shared__ ull  skey[8192];
    __shared__ uint spay[8192];
    __shared__ ull  svm[NW];

    for (int i = tid; i < 8192; i += 1024) {
        ull kk2; uint pp;
        if (i < KSEL) {
            float s = selScore[b * KSEL + i];
            int v = selValid[b * KSEL + i];
            uint k32 = v ? fkey(s) : 0x007FFFFFu;
            uint a32 = 0xFFFFFFFFu - (uint)selAnchor[b * KSEL + i];
            kk2 = ((ull)k32 << 32) | a32; pp = (uint)i;
        } else { kk2 = 0ull; pp = 0xFFFFFFFFu; }
        skey[i] = kk2; spay[i] = pp;
    }
    __syncthreads();
    for (uint kk = 2; kk <= 8192; kk <<= 1) {
        for (uint j = kk >> 1; j > 0; j >>= 1) {
            for (int i = tid; i < 8192; i += 1024) {
                uint ixj = (uint)i ^ j;
                if (ixj > (uint)i) {
                    bool up = ((((uint)i) & kk) == 0);
                    ull a = skey[i], c = skey[ixj];
                    bool sw = up ? (a < c) : (a > c);
                    if (sw) {
                        skey[i] = c; skey[ixj] = a;
                        uint tp = spay[i]; spay[i] = spay[ixj]; spay[ixj] = tp;
                    }
                }
            }
            __syncthreads();
        }
    }
    for (int i = tid; i < NW; i += 1024) svm[i] = 0ull;
    __syncthreads();
    for (int i = tid; i < KSEL; i += 1024) {
        uint slot = spay[i];
        sortedSlot[b * KSEL + i] = (int)slot;
        int v = selValid[b * KSEL + slot];
        if (v) atomicOr(&svm[i >> 6], 1ull << (i & 63));
        int lvl = (int)slot / 1000;
        float off = 1217.0f * (float)lvl;
        float4 bx = *(const float4*)&selBox[((size_t)b * KSEL + slot) * 4];
        bx.x += off; bx.y += off; bx.z += off; bx.w += off;
        *(float4*)&sortedBoxOff[((size_t)b * KSEL + i) * 4] = bx;
    }
    __syncthreads();
    for (int i = tid; i < NW; i += 1024) validMask[b * NW + i] = svm[i];
}

// ---------------- NMS pairwise suppression bitmask ----------------
__global__ __launch_bounds__(64) void nms_mask(const float* __restrict__ sortedBoxOff,
                                               ull* __restrict__ mat)
{
    const int jb = blockIdx.x, ib = blockIdx.y, b = blockIdx.z;
    const int tid = threadIdx.x;
    __shared__ float4 bj[64];
    __shared__ float  aj[64];
    const int j0 = jb * 64;
    const int jn = (KSEL - j0) < 64 ? (KSEL - j0) : 64;
    if (tid < jn) {
        float4 v = *(const float4*)&sortedBoxOff[((size_t)b * KSEL + j0 + tid) * 4];
        bj[tid] = v; aj[tid] = (v.z - v.x) * (v.w - v.y);
    }
    __syncthreads();
    const int i = ib * 64 + tid;
    if (i >= KSEL) return;
    float4 bi = *(const float4*)&sortedBoxOff[((size_t)b * KSEL + i) * 4];
    float ai = (bi.z - bi.x) * (bi.w - bi.y);
    ull m = 0ull;
    for (int jj = 0; jj < jn; ++jj) {
        int j = j0 + jj;
        if (j <= i) continue;
        float4 bb = bj[jj];
        float ltx = fmaxf(bi.x, bb.x), lty = fmaxf(bi.y, bb.y);
        float rbx = fminf(bi.z, bb.z), rby = fminf(bi.w, bb.w);
        float wx = fmaxf(rbx - ltx, 0.f), wy = fmaxf(rby - lty, 0.f);
        float inter = wx * wy;
        float iou = inter / (ai + aj[jj] - inter + 1e-9f);
        if (iou > 0.7f) m |= (1ull << jj);
    }
    mat[((size_t)b * KSEL + i) * NW + jb] = m;
}

// ---------------- greedy scan (1 wave per batch, register-resident bitset) ----------------
__global__ __launch_bounds__(64) void nms_scan(const ull* __restrict__ mat,
                                               const ull* __restrict__ validMask,
                                               int* __restrict__ keptPos,
                                               int* __restrict__ nkOut)
{
    const int b = blockIdx.x, lane = threadIdx.x;
    ull v0 = validMask[b * NW + lane];
    ull v1 = (lane < NW - 64) ? validMask[b * NW + 64 + lane] : 0ull;
    ull s0 = 0ull, s1 = 0ull;
    int nk = 0;
    const ull* mb = mat + (size_t)b * KSEL * NW;
    const int NG = (KSEL + 7) / 8;
    for (int g = 0; g < NG; ++g) {
        ull rA[8], rB[8];
#pragma unroll
        for (int d = 0; d < 8; ++d) {
            int i = g * 8 + d;
            if (i < KSEL) {
                rA[d] = mb[(size_t)i * NW + lane];
                rB[d] = (lane < NW - 64) ? mb[(size_t)i * NW + 64 + lane] : 0ull;
            } else { rA[d] = 0ull; rB[d] = 0ull; }
        }
#pragma unroll
        for (int d = 0; d < 8; ++d) {
            int i = g * 8 + d;
            if (i >= KSEL) break;
            int wi = i >> 6;
            ull a0 = v0 & ~s0, a1 = v1 & ~s1;
            ull aw = (wi < 64) ? __shfl(a0, wi, 64) : __shfl(a1, wi - 64, 64);
            if ((aw >> (i & 63)) & 1ull) {
                s0 |= rA[d]; s1 |= rB[d];
                if (lane == 0) keptPos[b * POST_NMS + nk] = i;
                ++nk;
                if (nk == POST_NMS) { if (lane == 0) nkOut[b] = nk; return; }
            }
        }
    }
    if (lane == 0) nkOut[b] = nk;
}

// ---------------- final output ----------------
__global__ __launch_bounds__(256) void out_kernel(
    const int* __restrict__ keptPos, const int* __restrict__ nkOut,
    const int* __restrict__ sortedSlot,
    const float* __restrict__ selBox, const float* __restrict__ selScore,
    float* __restrict__ out)
{
    int t = blockIdx.x * 256 + threadIdx.x;
    if (t >= BATCH * POST_NMS) return;
    int b = t / POST_NMS, row = t - b * POST_NMS;
    float4 bx = make_float4(0.f, 0.f, 0.f, 0.f);
    float sc = -1e9f;
    if (row < nkOut[b]) {
        int i = keptPos[b * POST_NMS + row];
        int slot = sortedSlot[b * KSEL + i];
        bx = *(const float4*)&selBox[((size_t)b * KSEL + slot) * 4];
        sc = selScore[b * KSEL + slot];
    }
    *(float4*)&out[(size_t)t * 4] = bx;
    out[BATCH * POST_NMS * 4 + t] = sc;
}

// ---------------- host launch ----------------
extern "C" void kernel_launch(void* const* d_in, const int* in_sizes, int n_in,
                              void* d_out, int out_size, void* d_ws, size_t ws_size,
                              hipStream_t stream)
{
    (void)in_sizes; (void)n_in; (void)out_size; (void)ws_size;
    const float* feat[5] = {(const float*)d_in[0], (const float*)d_in[1],
                            (const float*)d_in[2], (const float*)d_in[3],
                            (const float*)d_in[4]};
    const float* conv_w = (const float*)d_in[5];
    const float* conv_b = (const float*)d_in[6];
    const float* cls_w  = (const float*)d_in[7];
    const float* cls_b  = (const float*)d_in[8];
    const float* box_w  = (const float*)d_in[9];
    const float* box_b  = (const float*)d_in[10];
    float* out = (float*)d_out;

    char* ws = (char*)d_ws;
    size_t off = 0;
    auto carve = [&](size_t bytes) -> void* {
        void* p = (void*)(ws + off);
        off += (bytes + 255) & ~(size_t)255;
        return p;
    };
    ushort* wB         = (ushort*)carve((size_t)WB_ELEMS * 2);
    float* scoresA     = (float*)carve((size_t)BATCH * ATOTAL * 4);
    float* boxesA      = (float*)carve((size_t)BATCH * ATOTAL * 16);
    float* selScore    = (float*)carve((size_t)BATCH * KSEL * 4);
    float* selBox      = (float*)carve((size_t)BATCH * KSEL * 16);
    int*   selValid    = (int*)  carve((size_t)BATCH * KSEL * 4);
    int*   selAnchor   = (int*)  carve((size_t)BATCH * KSEL * 4);
    int*   sortedSlot  = (int*)  carve((size_t)BATCH * KSEL * 4);
    float* sortedBoxOff= (float*)carve((size_t)BATCH * KSEL * 16);
    ull*   validMask   = (ull*)  carve((size_t)BATCH * NW * 8);
    ull*   mat         = (ull*)  carve((size_t)BATCH * KSEL * NW * 8);
    int*   keptPos     = (int*)  carve((size_t)BATCH * POST_NMS * 4);
    int*   nkOut       = (int*)  carve(64);

    wt_kernel<<<(WB_ELEMS + 255) / 256, 256, 0, stream>>>(conv_w, wB);

    conv_mfma_all<<<dim3(656, BATCH), 256, 0, stream>>>(
        feat[0], feat[1], feat[2], feat[3], feat[4], wB, conv_b,
        cls_w, cls_b, box_w, box_b, scoresA, boxesA);

    topk_kernel<<<dim3(5, BATCH), 256, 0, stream>>>(scoresA, boxesA, selScore, selBox, selValid, selAnchor);
    sort_kernel<<<dim3(BATCH), 1024, 0, stream>>>(selScore, selBox, selValid, selAnchor, sortedSlot, sortedBoxOff, validMask);
    nms_mask<<<dim3(NW, NW, BATCH), 64, 0, stream>>>(sortedBoxOff, mat);
    nms_scan<<<dim3(BATCH), 64, 0, stream>>>(mat, validMask, keptPos, nkOut);
    out_kernel<<<dim3((BATCH * POST_NMS + 255) / 256), 256, 0, stream>>>(keptPos, nkOut, sortedSlot, selBox, selScore, out);
}

// Round 9
// 2582.812 us; speedup vs baseline: 14.3845x; 1.2455x over previous
//
#include <hip/hip_runtime.h>
#include <stdint.h>
#include <math.h>

typedef unsigned int uint;
typedef unsigned short ushort;
typedef unsigned long long ull;
typedef __attribute__((ext_vector_type(8))) short bf16x8;
typedef __attribute__((ext_vector_type(4))) float f32x4;

#define BATCH 2
#define ATOTAL 242991
#define KSEL 4741
#define NW 75
#define POST_NMS 1000
#define WB_ELEMS (72*2*3*8*64*8)   // 1,769,472 u16 = 3.5 MB

// runtime-indexed device copies
__device__ __constant__ int dLoff[5]  = {0,182400,228000,239400,242250};
__device__ __constant__ int dCount[5] = {182400,45600,11400,2850,741};
__device__ __constant__ int dSeg[5]   = {0,1000,2000,3000,4000};
__device__ __constant__ int dSegK[5]  = {1000,1000,1000,1000,741};
__device__ __constant__ int dHc[5]     = {200,100,50,25,13};
__device__ __constant__ int dWc[5]     = {304,152,76,38,19};
__device__ __constant__ int dTilesX[5] = {19,10,5,3,2};
__device__ __constant__ int dCumT[6]   = {0,475,605,640,652,656};
__device__ __constant__ int dStrideC[5]= {4,8,16,32,64};
__device__ __constant__ int dSizeC[5]  = {32,64,128,256,512};

__device__ __forceinline__ uint fkey(float f) {
    uint u = __float_as_uint(f);
    return (u & 0x80000000u) ? ~u : (u | 0x80000000u);
}
__device__ __forceinline__ ushort bfrne(float x) {
    uint u = __float_as_uint(x);
    uint r = (u + 0x7FFFu + ((u >> 16) & 1u)) >> 16;
    return (ushort)r;
}
__device__ __forceinline__ float bf2f(ushort h) {
    return __uint_as_float(((uint)h) << 16);
}

// ---------------- weight gen: conv_w [O=256][IC=256][3][3] -> wB fragment-ordered bf16x3 ----
// layout: [step72=(icblk*9+dydx)][ocg2][pl3][nt8][lane64][e8] u16
__global__ __launch_bounds__(256) void wt_kernel(const float* __restrict__ conv_w,
                                                 ushort* __restrict__ wB) {
    int t = blockIdx.x * 256 + threadIdx.x;
    if (t >= WB_ELEMS) return;
    int e    = t & 7;
    int lane = (t >> 3) & 63;
    int nt   = (t >> 9) & 7;
    int r12  = t >> 12;
    int pl   = r12 % 3;
    int r2   = r12 / 3;
    int ocg  = r2 & 1;
    int step = r2 >> 1;            // 0..71
    int icblk = step / 9, dydx = step - icblk * 9;
    int oc = ocg * 128 + nt * 16 + (lane & 15);
    int ic = icblk * 32 + ((lane >> 4) << 3) + e;
    float v = conv_w[(size_t)oc * 2304 + ic * 9 + dydx];
    ushort h = bfrne(v);
    float vm = v - bf2f(h);
    ushort m = bfrne(vm);
    ushort l = bfrne(vm - bf2f(m));
    wB[t] = (pl == 0) ? h : ((pl == 1) ? m : l);
}

// ---------------- MFMA conv3x3 (bf16x3 split, 6 products) + relu + f64 heads + f64 decode ----
// grid (656, 2), 512 threads = 8 waves. tile 8 rows x 16 cols = 128 px.
// Round-9: 8 waves -> 2+ waves/SIMD TLP (round-8 showed 1 wave/SIMD exposed every stall);
// halo loads batch-issued (were 23 serial load-use iterations). Math order bit-identical.
// wave=(wm 0..3, wn 0..1): mt = 2*wm+mi (mi 0..1), nt = 4*wn+ni (ni 0..3).
__global__ __launch_bounds__(512) void conv_mfma_all(
    const float* __restrict__ f0, const float* __restrict__ f1,
    const float* __restrict__ f2, const float* __restrict__ f3,
    const float* __restrict__ f4, const ushort* __restrict__ wB,
    const float* __restrict__ conv_b,
    const float* __restrict__ cls_w, const float* __restrict__ cls_b,
    const float* __restrict__ box_w, const float* __restrict__ box_b,
    float* __restrict__ scoresA, float* __restrict__ boxesA)
{
    const int bidx = blockIdx.x;
    const int b    = blockIdx.y;
    const int tid  = threadIdx.x;

    int lvl = 0;
#pragma unroll
    for (int l = 1; l < 5; ++l) if (bidx >= dCumT[l]) lvl = l;
    const int tile   = bidx - dCumT[lvl];
    const int H      = dHc[lvl], W = dWc[lvl];
    const int TILESX = dTilesX[lvl];
    const int ty0    = (tile / TILESX) * 8;
    const int tx0    = (tile % TILESX) * 16;
    const int HW     = H * W;
    const float* feat = (lvl == 0) ? f0 : (lvl == 1) ? f1 : (lvl == 2) ? f2 : (lvl == 3) ? f3 : f4;
    const float* fb = feat + (size_t)b * 256 * HW;

    __shared__ __align__(16) char uni[59136];
    ushort* halo = (ushort*)uni;                 // [3pl][5760] u16 = 34560 B
    ushort* ldsB = (ushort*)(uni + 34560);       // [3pl][8nt][64lane][8e] = 24576 B
    float*  tS   = (float*)uni;                  // 32768 B (aliases halo, conv done)
    float*  hw2  = (float*)(uni + 32768);        // 4096 B (aliases ldsB head, conv done)
    double* houtD= (double*)uni;                 // 16384 B (aliases tS, slabs done)

    const int lane = tid & 63, wave = tid >> 6;
    const int wm = wave >> 1, wn = wave & 1;
    const int g = lane >> 4, col = lane & 15;
    const int laneA = g * 1440 + col * 8;        // u16 idx, lane-constant part

    // halo staging coords (icblk-invariant): 5760 elems / 512 threads = 12 slots
    int  hdst[12]; int hoff[12]; bool hval[12];
#pragma unroll
    for (int j = 0; j < 12; ++j) {
        int e = tid + j * 512;
        hdst[j] = -1; hoff[j] = 0; hval[j] = false;
        if (e < 5760) {
            int ic = e / 180, rem = e - ic * 180;
            int hrow = rem / 18, hcol = rem - hrow * 18;
            int gy = ty0 + hrow - 1, gx = tx0 + hcol - 1;
            hdst[j] = (((ic >> 3) * 10 + hrow) * 18 + hcol) * 8 + (ic & 7);
            if (gy >= 0 && gy < H && gx >= 0 && gx < W) {
                hval[j] = true; hoff[j] = ic * HW + gy * W + gx;
            }
        }
    }

    double hacc[4] = {0,0,0,0};   // per-thread f64 head accumulators (4 heads)

    // B prefetch registers (3 x uint4 per thread = 24 KB/block slab at 512 threads)
    uint4 Br0, Br1, Br2;
    {
        const uint4* gq = (const uint4*)wB;
        Br0 = gq[tid]; Br1 = gq[tid + 512]; Br2 = gq[tid + 1024];
    }

#pragma unroll 1
    for (int ocg = 0; ocg < 2; ++ocg) {
        f32x4 acc[2][4];
#pragma unroll
        for (int mi = 0; mi < 2; ++mi)
#pragma unroll
            for (int ni = 0; ni < 4; ++ni)
                acc[mi][ni] = (f32x4){0.f, 0.f, 0.f, 0.f};

#pragma unroll 1
        for (int s = 0; s < 72; ++s) {
            const int icblk = s / 9;
            const int dydx  = s - icblk * 9;
            const int dy = dydx / 3, dx = dydx - dy * 3;

            __syncthreads();   // prior step's halo/ldsB reads (and epilogue reads) done
            // ---- stage halo at icblk start: batch-issue 12 loads, then convert+write ----
            if (dydx == 0) {
                float hv[12];
                const float* fcb = fb + (size_t)icblk * 32 * HW;
#pragma unroll
                for (int j = 0; j < 12; ++j)
                    hv[j] = hval[j] ? fcb[hoff[j]] : 0.f;
#pragma unroll
                for (int j = 0; j < 12; ++j) {
                    if (hdst[j] >= 0) {
                        float v = hv[j];
                        ushort h = bfrne(v);
                        float vm = v - bf2f(h);
                        ushort m = bfrne(vm);
                        ushort l = bfrne(vm - bf2f(m));
                        int li = hdst[j];
                        halo[li] = h; halo[5760 + li] = m; halo[11520 + li] = l;
                    }
                }
            }
            // ---- write prefetched B slab to LDS ----
            {
                uint4* lq = (uint4*)ldsB;
                lq[tid] = Br0; lq[tid + 512] = Br1; lq[tid + 1024] = Br2;
            }
            __syncthreads();   // halo + B visible
            // ---- issue next step's B loads (hidden under MFMA phase) ----
            {
                int gstep = ocg * 72 + s + 1;
                if (gstep < 144) {
                    int s2 = gstep % 72, og2 = gstep / 72;
                    const uint4* gq = (const uint4*)(wB + ((size_t)(s2 * 2 + og2)) * 12288);
                    Br0 = gq[tid]; Br1 = gq[tid + 512]; Br2 = gq[tid + 1024];
                }
            }
            // ---- A fragments (3 planes x 2 m-tiles) ----
            bf16x8 A[3][2];
            const int abase = laneA + dx * 8 + (2 * wm + dy) * 144;
#pragma unroll
            for (int pl = 0; pl < 3; ++pl)
#pragma unroll
                for (int mi = 0; mi < 2; ++mi)
                    A[pl][mi] = *(const bf16x8*)(halo + pl * 5760 + abase + mi * 144);
            // ---- MFMAs: per nt read B 3 planes, 6 products x 2 mi ----
#pragma unroll
            for (int ni = 0; ni < 4; ++ni) {
                const int nt = 4 * wn + ni;
                bf16x8 Bh = *(const bf16x8*)(ldsB + ((0 * 8 + nt) * 64 + lane) * 8);
                bf16x8 Bm = *(const bf16x8*)(ldsB + ((1 * 8 + nt) * 64 + lane) * 8);
                bf16x8 Bl = *(const bf16x8*)(ldsB + ((2 * 8 + nt) * 64 + lane) * 8);
#pragma unroll
                for (int mi = 0; mi < 2; ++mi) {
                    f32x4 c = acc[mi][ni];
                    c = __builtin_amdgcn_mfma_f32_16x16x32_bf16(A[0][mi], Bh, c, 0, 0, 0);
                    c = __builtin_amdgcn_mfma_f32_16x16x32_bf16(A[0][mi], Bm, c, 0, 0, 0);
                    c = __builtin_amdgcn_mfma_f32_16x16x32_bf16(A[1][mi], Bh, c, 0, 0, 0);
                    c = __builtin_amdgcn_mfma_f32_16x16x32_bf16(A[0][mi], Bl, c, 0, 0, 0);
                    c = __builtin_amdgcn_mfma_f32_16x16x32_bf16(A[1][mi], Bm, c, 0, 0, 0);
                    c = __builtin_amdgcn_mfma_f32_16x16x32_bf16(A[2][mi], Bh, c, 0, 0, 0);
                    acc[mi][ni] = c;
                }
            }
        }
        __syncthreads();   // all halo/ldsB reads done -> tS may overwrite
        // ---- writeout + f64 head contraction, 2 slabs of 64 oc (oc ascending) ----
        float cb[4];
#pragma unroll
        for (int ni = 0; ni < 4; ++ni)
            cb[ni] = conv_b[ocg * 128 + (4 * wn + ni) * 16 + col];

#pragma unroll 1
        for (int s2 = 0; s2 < 2; ++s2) {
            if (wn == s2) {
#pragma unroll
                for (int mi = 0; mi < 2; ++mi) {
#pragma unroll
                    for (int r = 0; r < 4; ++r) {
                        int px = (2 * wm + mi) * 16 + 4 * g + r;
                        int sw = px & 15;
#pragma unroll
                        for (int ni = 0; ni < 4; ++ni) {
                            int slot = (ni * 4 + (col >> 2)) ^ sw;
                            tS[px * 64 + slot * 4 + (col & 3)] =
                                fmaxf(acc[mi][ni][r] + cb[ni], 0.f);
                        }
                    }
                }
            }
            // stage head weights for this 64-oc slab (threads 0..255)
            if (tid < 256) {
                const int oc2 = tid >> 2;
                const int h0  = (tid & 3) * 4;
                const int oc  = ocg * 128 + s2 * 64 + oc2;
                float vv[4];
#pragma unroll
                for (int q = 0; q < 4; ++q) {
                    int h = h0 + q;
                    vv[q] = (h < 3) ? cls_w[h * 256 + oc]
                          : (h < 15) ? box_w[(h - 3) * 256 + oc] : 0.f;
                }
                *(float4*)&hw2[oc2 * 16 + h0] = make_float4(vv[0], vv[1], vv[2], vv[3]);
            }
            __syncthreads();
            // accumulate: px = tid&127, head-quarter = tid>>7 (oc ascending within slab)
            {
                const int px = tid & 127;
                const int hh = tid >> 7;           // 0..3, heads hh*4..hh*4+3
                const int sw = px & 15;
#pragma unroll 1
                for (int j4 = 0; j4 < 16; ++j4) {
                    float4 t4 = *(const float4*)&tS[px * 64 + (j4 ^ sw) * 4];
                    float tv[4] = {t4.x, t4.y, t4.z, t4.w};
#pragma unroll
                    for (int jj = 0; jj < 4; ++jj) {
                        const float* hb = &hw2[(j4 * 4 + jj) * 16 + hh * 4];
                        float4 h0 = *(const float4*)hb;
                        double tv_d = (double)tv[jj];
                        hacc[0] += tv_d * (double)h0.x;
                        hacc[1] += tv_d * (double)h0.y;
                        hacc[2] += tv_d * (double)h0.z;
                        hacc[3] += tv_d * (double)h0.w;
                    }
                }
            }
            __syncthreads();   // slab reads done before next slab overwrites tS
        }
    }

    // ---- write head outputs to LDS (f64) ----
    {
        const int px = tid & 127;
        const int hh = tid >> 7;
#pragma unroll
        for (int j = 0; j < 4; ++j) houtD[px * 16 + hh * 4 + j] = hacc[j];
    }
    __syncthreads();

    // ---- decode + clip in f64, store f32 (unchanged from passing config) ----
    if (tid < 128) {
        const int px = tid;
        const int gy = ty0 + (px >> 4);
        const int gx = tx0 + (px & 15);
        if (gy < H && gx < W) {
            const int STRIDE = dStrideC[lvl];
            const int SZ     = dSizeC[lvl];
            const int LOFF   = dLoff[lvl];
#pragma unroll 1
            for (int a = 0; a < 3; ++a) {
                double score = houtD[px * 16 + a] + (double)cls_b[a];
                double rg0 = houtD[px * 16 + 3 + a * 4 + 0] + (double)box_b[a * 4 + 0];
                double rg1 = houtD[px * 16 + 3 + a * 4 + 1] + (double)box_b[a * 4 + 1];
                double rg2 = houtD[px * 16 + 3 + a * 4 + 2] + (double)box_b[a * 4 + 2];
                double rg3 = houtD[px * 16 + 3 + a * 4 + 3] + (double)box_b[a * 4 + 3];
                double ratio = (a == 0) ? 0.5 : ((a == 1) ? 1.0 : 2.0);
                double hr = sqrt(ratio), wr = 1.0 / hr;
                double wsd = wr * (double)SZ, hsd = hr * (double)SZ;
                double sx = (double)(gx * STRIDE), sy = (double)(gy * STRIDE);
                float ax0 = (float)(sx - 0.5 * wsd);
                float ay0 = (float)(sy - 0.5 * hsd);
                float ax1 = (float)(sx + 0.5 * wsd);
                float ay1 = (float)(sy + 0.5 * hsd);
                double wa = (double)ax1 - (double)ax0, ha = (double)ay1 - (double)ay0;
                double cxa = (double)ax0 + 0.5 * wa, cya = (double)ay0 + 0.5 * ha;
                double dwv = fmin(rg2, 4.135166556742356);
                double dhv = fmin(rg3, 4.135166556742356);
                double cx = rg0 * wa + cxa, cy = rg1 * ha + cya;
                double w = exp(dwv) * wa, h = exp(dhv) * ha;
                double x0 = cx - 0.5 * w, y0 = cy - 0.5 * h;
                double x1 = cx + 0.5 * w, y1 = cy + 0.5 * h;
                x0 = fmin(fmax(x0, 0.0), 1216.0);
                y0 = fmin(fmax(y0, 0.0), 800.0);
                x1 = fmin(fmax(x1, 0.0), 1216.0);
                y1 = fmin(fmax(y1, 0.0), 800.0);
                int gidx = LOFF + (gy * W + gx) * 3 + a;
                scoresA[(size_t)b * ATOTAL + gidx] = (float)score;
                float4 bx = make_float4((float)x0, (float)y0, (float)x1, (float)y1);
                *(float4*)&boxesA[((size_t)b * ATOTAL + gidx) * 4] = bx;
            }
        }
    }
}

// ---------------- per-(batch,level) top-k via 3-pass radix threshold ----------------
__global__ __launch_bounds__(256) void topk_kernel(
    const float* __restrict__ scoresA, const float* __restrict__ boxesA,
    float* __restrict__ selScore, float* __restrict__ selBox,
    int* __restrict__ selValid, int* __restrict__ selAnchor)
{
    const int lvl = blockIdx.x, b = blockIdx.y;
    const int n = dCount[lvl], loff = dLoff[lvl], seg = dSeg[lvl], k = dSegK[lvl];
    const float* sc = scoresA + (size_t)b * ATOTAL + loff;
    const int tid = threadIdx.x;

    float* oS = selScore + b * KSEL;
    float* oB = selBox + (size_t)b * KSEL * 4;
    int* oV = selValid + b * KSEL;
    int* oA = selAnchor + b * KSEL;

    auto emit = [&](int slot, int i) {
        int g = loff + i;
        float s = sc[i];
        float4 bx = *(const float4*)&boxesA[((size_t)b * ATOTAL + g) * 4];
        oS[seg + slot] = s;
        *(float4*)&oB[(size_t)(seg + slot) * 4] = bx;
        oV[seg + slot] = ((bx.z - bx.x) >= 1e-3f && (bx.w - bx.y) >= 1e-3f) ? 1 : 0;
        oA[seg + slot] = g;
    };

    if (n <= k) {
        for (int i = tid; i < n; i += 256) emit(i, i);
        return;
    }

    __shared__ uint hist[2048];
    __shared__ uint sh_bin, sh_krem;
    __shared__ uint cntG, cntE;
    __shared__ int stash[64];

    uint krem = (uint)k;
    uint prefix = 0;
    for (int pass = 0; pass < 3; ++pass) {
        for (int e = tid; e < 2048; e += 256) hist[e] = 0;
        __syncthreads();
        for (int i = tid; i < n; i += 256) {
            uint key = fkey(sc[i]);
            uint bin; bool sel;
            if (pass == 0)      { sel = true;                      bin = key >> 21; }
            else if (pass == 1) { sel = ((key >> 21) == prefix);   bin = (key >> 10) & 0x7FFu; }
            else                { sel = ((key >> 10) == prefix);   bin = key & 0x3FFu; }
            if (sel) atomicAdd(&hist[bin], 1u);
        }
        __syncthreads();
        if (tid == 0) {
            int nb = (pass == 2) ? 1024 : 2048;
            uint c = 0;
            for (int x = nb - 1; x >= 0; --x) {
                uint h = hist[x];
                if (c + h >= krem) { sh_bin = (uint)x; sh_krem = krem - c; break; }
                c += h;
            }
        }
        __syncthreads();
        uint bin = sh_bin; krem = sh_krem;
        if (pass == 0)      prefix = bin;
        else if (pass == 1) prefix = (prefix << 11) | bin;
        else                prefix = (prefix << 10) | bin;
        __syncthreads();
    }
    const uint T = prefix;
    const uint need_eq = krem;
    if (tid == 0) { cntG = 0; cntE = 0; }
    __syncthreads();
    for (int i = tid; i < n; i += 256) {
        uint key = fkey(sc[i]);
        if (key > T) {
            uint pos = atomicAdd(&cntG, 1u);
            emit((int)pos, i);
        } else if (key == T) {
            uint e = atomicAdd(&cntE, 1u);
            if (e < 64) stash[e] = i;
        }
    }
    __syncthreads();
    if (tid == 0) {
        uint ne = cntE < 64u ? cntE : 64u;
        uint base = cntG;   // == k - need_eq
        for (uint t2 = 0; t2 < need_eq; ++t2) {
            int best = -1, bj = -1;
            for (uint j2 = 0; j2 < ne; ++j2) {
                int v = stash[j2];
                if (v >= 0 && (best < 0 || v < best)) { best = v; bj = j2; }
            }
            if (bj >= 0) { stash[bj] = -1; emit((int)(base + t2), best); }
            else emit((int)(base + t2), 0);
        }
    }
}

// ---------------- per-batch descending sort (score, then anchor-idx asc) ----------------
__global__ __launch_bounds__(1024) void sort_kernel(
    const float* __restrict__ selScore, const float* __restrict__ selBox,
    const int* __restrict__ selValid, const int* __restrict__ selAnchor,
    int* __restrict__ sortedSlot, float* __restrict__ sortedBoxOff,
    ull* __restrict__ validMask)
{
    const int b = blockIdx.x, tid = threadIdx.x;
    __shared__ ull  skey[8192];
    __shared__ uint spay[8192];
    __shared__ ull  svm[NW];

    for (int i = tid; i < 8192; i += 1024) {
        ull kk2; uint pp;
        if (i < KSEL) {
            float s = selScore[b * KSEL + i];
            int v = selValid[b * KSEL + i];
            uint k32 = v ? fkey(s) : 0x007FFFFFu;
            uint a32 = 0xFFFFFFFFu - (uint)selAnchor[b * KSEL + i];
            kk2 = ((ull)k32 << 32) | a32; pp = (uint)i;
        } else { kk2 = 0ull; pp = 0xFFFFFFFFu; }
        skey[i] = kk2; spay[i] = pp;
    }
    __syncthreads();
    for (uint kk = 2; kk <= 8192; kk <<= 1) {
        for (uint j = kk >> 1; j > 0; j >>= 1) {
            for (int i = tid; i < 8192; i += 1024) {
                uint ixj = (uint)i ^ j;
                if (ixj > (uint)i) {
                    bool up = ((((uint)i) & kk) == 0);
                    ull a = skey[i], c = skey[ixj];
                    bool sw = up ? (a < c) : (a > c);
                    if (sw) {
                        skey[i] = c; skey[ixj] = a;
                        uint tp = spay[i]; spay[i] = spay[ixj]; spay[ixj] = tp;
                    }
                }
            }
            __syncthreads();
        }
    }
    for (int i = tid; i < NW; i += 1024) svm[i] = 0ull;
    __syncthreads();
    for (int i = tid; i < KSEL; i += 1024) {
        uint slot = spay[i];
        sortedSlot[b * KSEL + i] = (int)slot;
        int v = selValid[b * KSEL + slot];
        if (v) atomicOr(&svm[i >> 6], 1ull << (i & 63));
        int lvl = (int)slot / 1000;
        float off = 1217.0f * (float)lvl;
        float4 bx = *(const float4*)&selBox[((size_t)b * KSEL + slot) * 4];
        bx.x += off; bx.y += off; bx.z += off; bx.w += off;
        *(float4*)&sortedBoxOff[((size_t)b * KSEL + i) * 4] = bx;
    }
    __syncthreads();
    for (int i = tid; i < NW; i += 1024) validMask[b * NW + i] = svm[i];
}

// ---------------- NMS pairwise suppression bitmask ----------------
__global__ __launch_bounds__(64) void nms_mask(const float* __restrict__ sortedBoxOff,
                                               ull* __restrict__ mat)
{
    const int jb = blockIdx.x, ib = blockIdx.y, b = blockIdx.z;
    const int tid = threadIdx.x;
    __shared__ float4 bj[64];
    __shared__ float  aj[64];
    const int j0 = jb * 64;
    const int jn = (KSEL - j0) < 64 ? (KSEL - j0) : 64;
    if (tid < jn) {
        float4 v = *(const float4*)&sortedBoxOff[((size_t)b * KSEL + j0 + tid) * 4];
        bj[tid] = v; aj[tid] = (v.z - v.x) * (v.w - v.y);
    }
    __syncthreads();
    const int i = ib * 64 + tid;
    if (i >= KSEL) return;
    float4 bi = *(const float4*)&sortedBoxOff[((size_t)b * KSEL + i) * 4];
    float ai = (bi.z - bi.x) * (bi.w - bi.y);
    ull m = 0ull;
    for (int jj = 0; jj < jn; ++jj) {
        int j = j0 + jj;
        if (j <= i) continue;
        float4 bb = bj[jj];
        float ltx = fmaxf(bi.x, bb.x), lty = fmaxf(bi.y, bb.y);
        float rbx = fminf(bi.z, bb.z), rby = fminf(bi.w, bb.w);
        float wx = fmaxf(rbx - ltx, 0.f), wy = fmaxf(rby - lty, 0.f);
        float inter = wx * wy;
        float iou = inter / (ai + aj[jj] - inter + 1e-9f);
        if (iou > 0.7f) m |= (1ull << jj);
    }
    mat[((size_t)b * KSEL + i) * NW + jb] = m;
}

// ---------------- greedy scan (1 wave per batch, register-resident bitset) ----------------
__global__ __launch_bounds__(64) void nms_scan(const ull* __restrict__ mat,
                                               const ull* __restrict__ validMask,
                                               int* __restrict__ keptPos,
                                               int* __restrict__ nkOut)
{
    const int b = blockIdx.x, lane = threadIdx.x;
    ull v0 = validMask[b * NW + lane];
    ull v1 = (lane < NW - 64) ? validMask[b * NW + 64 + lane] : 0ull;
    ull s0 = 0ull, s1 = 0ull;
    int nk = 0;
    const ull* mb = mat + (size_t)b * KSEL * NW;
    const int NG = (KSEL + 7) / 8;
    for (int g = 0; g < NG; ++g) {
        ull rA[8], rB[8];
#pragma unroll
        for (int d = 0; d < 8; ++d) {
            int i = g * 8 + d;
            if (i < KSEL) {
                rA[d] = mb[(size_t)i * NW + lane];
                rB[d] = (lane < NW - 64) ? mb[(size_t)i * NW + 64 + lane] : 0ull;
            } else { rA[d] = 0ull; rB[d] = 0ull; }
        }
#pragma unroll
        for (int d = 0; d < 8; ++d) {
            int i = g * 8 + d;
            if (i >= KSEL) break;
            int wi = i >> 6;
            ull a0 = v0 & ~s0, a1 = v1 & ~s1;
            ull aw = (wi < 64) ? __shfl(a0, wi, 64) : __shfl(a1, wi - 64, 64);
            if ((aw >> (i & 63)) & 1ull) {
                s0 |= rA[d]; s1 |= rB[d];
                if (lane == 0) keptPos[b * POST_NMS + nk] = i;
                ++nk;
                if (nk == POST_NMS) { if (lane == 0) nkOut[b] = nk; return; }
            }
        }
    }
    if (lane == 0) nkOut[b] = nk;
}

// ---------------- final output ----------------
__global__ __launch_bounds__(256) void out_kernel(
    const int* __restrict__ keptPos, const int* __restrict__ nkOut,
    const int* __restrict__ sortedSlot,
    const float* __restrict__ selBox, const float* __restrict__ selScore,
    float* __restrict__ out)
{
    int t = blockIdx.x * 256 + threadIdx.x;
    if (t >= BATCH * POST_NMS) return;
    int b = t / POST_NMS, row = t - b * POST_NMS;
    float4 bx = make_float4(0.f, 0.f, 0.f, 0.f);
    float sc = -1e9f;
    if (row < nkOut[b]) {
        int i = keptPos[b * POST_NMS + row];
        int slot = sortedSlot[b * KSEL + i];
        bx = *(const float4*)&selBox[((size_t)b * KSEL + slot) * 4];
        sc = selScore[b * KSEL + slot];
    }
    *(float4*)&out[(size_t)t * 4] = bx;
    out[BATCH * POST_NMS * 4 + t] = sc;
}

// ---------------- host launch ----------------
extern "C" void kernel_launch(void* const* d_in, const int* in_sizes, int n_in,
                              void* d_out, int out_size, void* d_ws, size_t ws_size,
                              hipStream_t stream)
{
    (void)in_sizes; (void)n_in; (void)out_size; (void)ws_size;
    const float* feat[5] = {(const float*)d_in[0], (const float*)d_in[1],
                            (const float*)d_in[2], (const float*)d_in[3],
                            (const float*)d_in[4]};
    const float* conv_w = (const float*)d_in[5];
    const float* conv_b = (const float*)d_in[6];
    const float* cls_w  = (const float*)d_in[7];
    const float* cls_b  = (const float*)d_in[8];
    const float* box_w  = (const float*)d_in[9];
    const float* box_b  = (const float*)d_in[10];
    float* out = (float*)d_out;

    char* ws = (char*)d_ws;
    size_t off = 0;
    auto carve = [&](size_t bytes) -> void* {
        void* p = (void*)(ws + off);
        off += (bytes + 255) & ~(size_t)255;
        return p;
    };
    ushort* wB         = (ushort*)carve((size_t)WB_ELEMS * 2);
    float* scoresA     = (float*)carve((size_t)BATCH * ATOTAL * 4);
    float* boxesA      = (float*)carve((size_t)BATCH * ATOTAL * 16);
    float* selScore    = (float*)carve((size_t)BATCH * KSEL * 4);
    float* selBox      = (float*)carve((size_t)BATCH * KSEL * 16);
    int*   selValid    = (int*)  carve((size_t)BATCH * KSEL * 4);
    int*   selAnchor   = (int*)  carve((size_t)BATCH * KSEL * 4);
    int*   sortedSlot  = (int*)  carve((size_t)BATCH * KSEL * 4);
    float* sortedBoxOff= (float*)carve((size_t)BATCH * KSEL * 16);
    ull*   validMask   = (ull*)  carve((size_t)BATCH * NW * 8);
    ull*   mat         = (ull*)  carve((size_t)BATCH * KSEL * NW * 8);
    int*   keptPos     = (int*)  carve((size_t)BATCH * POST_NMS * 4);
    int*   nkOut       = (int*)  carve(64);

    wt_kernel<<<(WB_ELEMS + 255) / 256, 256, 0, stream>>>(conv_w, wB);

    conv_mfma_all<<<dim3(656, BATCH), 512, 0, stream>>>(
        feat[0], feat[1], feat[2], feat[3], feat[4], wB, conv_b,
        cls_w, cls_b, box_w, box_b, scoresA, boxesA);

    topk_kernel<<<dim3(5, BATCH), 256, 0, stream>>>(scoresA, boxesA, selScore, selBox, selValid, selAnchor);
    sort_kernel<<<dim3(BATCH), 1024, 0, stream>>>(selScore, selBox, selValid, selAnchor, sortedSlot, sortedBoxOff, validMask);
    nms_mask<<<dim3(NW, NW, BATCH), 64, 0, stream>>>(sortedBoxOff, mat);
    nms_scan<<<dim3(BATCH), 64, 0, stream>>>(mat, validMask, keptPos, nkOut);
    out_kernel<<<dim3((BATCH * POST_NMS + 255) / 256), 256, 0, stream>>>(keptPos, nkOut, sortedSlot, selBox, selScore, out);
}

// Round 10
// 1597.933 us; speedup vs baseline: 23.2503x; 1.6163x over previous
//
#include <hip/hip_runtime.h>
#include <hip/hip_fp16.h>
#include <stdint.h>
#include <math.h>

typedef unsigned int uint;
typedef unsigned short ushort;
typedef unsigned long long ull;
typedef __attribute__((ext_vector_type(8))) _Float16 f16x8;
typedef __attribute__((ext_vector_type(4))) float f32x4;

#define BATCH 2
#define ATOTAL 242991
#define KSEL 4741
#define NW 75
#define POST_NMS 1000
#define WB_ELEMS (72*2*2*8*64*8)   // 1,179,648 u16 = 2.25 MB (fp16 h + scaled-m planes)

// runtime-indexed device copies
__device__ __constant__ int dLoff[5]  = {0,182400,228000,239400,242250};
__device__ __constant__ int dCount[5] = {182400,45600,11400,2850,741};
__device__ __constant__ int dSeg[5]   = {0,1000,2000,3000,4000};
__device__ __constant__ int dSegK[5]  = {1000,1000,1000,1000,741};
__device__ __constant__ int dHc[5]     = {200,100,50,25,13};
__device__ __constant__ int dWc[5]     = {304,152,76,38,19};
__device__ __constant__ int dTilesX[5] = {19,10,5,3,2};
__device__ __constant__ int dCumT[6]   = {0,475,605,640,652,656};
__device__ __constant__ int dStrideC[5]= {4,8,16,32,64};
__device__ __constant__ int dSizeC[5]  = {32,64,128,256,512};

__device__ __forceinline__ uint fkey(float f) {
    uint u = __float_as_uint(f);
    return (u & 0x80000000u) ? ~u : (u | 0x80000000u);
}
__device__ __forceinline__ ushort h2u(__half h) {
    union { __half h; ushort u; } x; x.h = h; return x.u;
}

// ---------------- weight gen: conv_w -> wB fragment-ordered fp16 (h, m*1024) ----------------
// layout: [step72=(icblk*9+dydx)][ocg2][pl2][nt8][lane64][e8] u16
__global__ __launch_bounds__(256) void wt_kernel(const float* __restrict__ conv_w,
                                                 ushort* __restrict__ wB) {
    int t = blockIdx.x * 256 + threadIdx.x;
    if (t >= WB_ELEMS) return;
    int e    = t & 7;
    int lane = (t >> 3) & 63;
    int nt   = (t >> 9) & 7;
    int r12  = t >> 12;
    int pl   = r12 & 1;
    int r2   = r12 >> 1;
    int ocg  = r2 & 1;
    int step = r2 >> 1;            // 0..71
    int icblk = step / 9, dydx = step - icblk * 9;
    int oc = ocg * 128 + nt * 16 + (lane & 15);
    int ic = icblk * 32 + ((lane >> 4) << 3) + e;
    float v = conv_w[(size_t)oc * 2304 + ic * 9 + dydx];
    __half h = __float2half(v);
    float r = (v - __half2float(h)) * 1024.0f;   // scaled residual stays fp16-normal
    __half m = __float2half(r);
    wB[t] = (pl == 0) ? h2u(h) : h2u(m);
}

// ---------------- MFMA conv3x3 (fp16x2 scaled-m split, 3 products) + f64 heads/decode ----
// grid (656, 2), 512 threads = 8 waves. tile 8 rows x 16 cols = 128 px.
// c = accH + accM*2^-10; accH += Ah*Bh; accM += Ah*Bm' + Am'*Bh (m-planes stored x1024,
// so residuals are fp16-NORMAL -> immune to any MFMA denorm flush; t-err ~2e-8, 30x below
// the fp32 path that passed absmax 0.0). LDS ~39.4KB -> up to 4 blocks/CU.
__global__ __launch_bounds__(512) void conv_mfma_all(
    const float* __restrict__ f0, const float* __restrict__ f1,
    const float* __restrict__ f2, const float* __restrict__ f3,
    const float* __restrict__ f4, const ushort* __restrict__ wB,
    const float* __restrict__ conv_b,
    const float* __restrict__ cls_w, const float* __restrict__ cls_b,
    const float* __restrict__ box_w, const float* __restrict__ box_b,
    float* __restrict__ scoresA, float* __restrict__ boxesA)
{
    const int bidx = blockIdx.x;
    const int b    = blockIdx.y;
    const int tid  = threadIdx.x;

    int lvl = 0;
#pragma unroll
    for (int l = 1; l < 5; ++l) if (bidx >= dCumT[l]) lvl = l;
    const int tile   = bidx - dCumT[lvl];
    const int H      = dHc[lvl], W = dWc[lvl];
    const int TILESX = dTilesX[lvl];
    const int ty0    = (tile / TILESX) * 8;
    const int tx0    = (tile % TILESX) * 16;
    const int HW     = H * W;
    const float* feat = (lvl == 0) ? f0 : (lvl == 1) ? f1 : (lvl == 2) ? f2 : (lvl == 3) ? f3 : f4;
    const float* fb = feat + (size_t)b * 256 * HW;

    __shared__ __align__(16) char uni[39424];
    ushort* halo = (ushort*)uni;                 // [2pl][5760] u16 = 23040 B
    ushort* ldsB = (ushort*)(uni + 23040);       // [2pl][8nt][64lane][8e] = 16384 B
    float*  tS   = (float*)uni;                  // 32768 B (aliases halo, conv done)
    float*  hw2  = (float*)(uni + 32768);        // 4096 B
    double* houtD= (double*)uni;                 // 16384 B (aliases tS, slabs done)

    const int lane = tid & 63, wave = tid >> 6;
    const int wm = wave >> 1, wn = wave & 1;
    const int g = lane >> 4, col = lane & 15;
    const int laneA = g * 1440 + col * 8;        // u16 idx, lane-constant part

    // halo staging coords (icblk-invariant): 5760 elems / 512 threads = 12 slots
    int  hdst[12]; int hoff[12]; bool hval[12];
#pragma unroll
    for (int j = 0; j < 12; ++j) {
        int e = tid + j * 512;
        hdst[j] = -1; hoff[j] = 0; hval[j] = false;
        if (e < 5760) {
            int ic = e / 180, rem = e - ic * 180;
            int hrow = rem / 18, hcol = rem - hrow * 18;
            int gy = ty0 + hrow - 1, gx = tx0 + hcol - 1;
            hdst[j] = (((ic >> 3) * 10 + hrow) * 18 + hcol) * 8 + (ic & 7);
            if (gy >= 0 && gy < H && gx >= 0 && gx < W) {
                hval[j] = true; hoff[j] = ic * HW + gy * W + gx;
            }
        }
    }

    double hacc[4] = {0,0,0,0};   // per-thread f64 head accumulators (4 heads)

    // B prefetch registers (2 x uint4 per thread = 16 KB slab at 512 threads)
    uint4 Br0, Br1;
    {
        const uint4* gq = (const uint4*)wB;
        Br0 = gq[tid]; Br1 = gq[tid + 512];
    }

#pragma unroll 1
    for (int ocg = 0; ocg < 2; ++ocg) {
        f32x4 accH[2][4], accM[2][4];
#pragma unroll
        for (int mi = 0; mi < 2; ++mi)
#pragma unroll
            for (int ni = 0; ni < 4; ++ni) {
                accH[mi][ni] = (f32x4){0.f, 0.f, 0.f, 0.f};
                accM[mi][ni] = (f32x4){0.f, 0.f, 0.f, 0.f};
            }

#pragma unroll 1
        for (int s = 0; s < 72; ++s) {
            const int icblk = s / 9;
            const int dydx  = s - icblk * 9;
            const int dy = dydx / 3, dx = dydx - dy * 3;

            __syncthreads();   // prior step's halo/ldsB reads (and epilogue reads) done
            // ---- stage halo at icblk start: batch-issue 12 loads, then convert+write ----
            if (dydx == 0) {
                float hv[12];
                const float* fcb = fb + (size_t)icblk * 32 * HW;
#pragma unroll
                for (int j = 0; j < 12; ++j)
                    hv[j] = hval[j] ? fcb[hoff[j]] : 0.f;
#pragma unroll
                for (int j = 0; j < 12; ++j) {
                    if (hdst[j] >= 0) {
                        float v = hv[j];
                        __half h = __float2half(v);
                        float r = (v - __half2float(h)) * 1024.0f;
                        __half m = __float2half(r);
                        int li = hdst[j];
                        halo[li] = h2u(h); halo[5760 + li] = h2u(m);
                    }
                }
            }
            // ---- write prefetched B slab to LDS ----
            {
                uint4* lq = (uint4*)ldsB;
                lq[tid] = Br0; lq[tid + 512] = Br1;
            }
            __syncthreads();   // halo + B visible
            // ---- issue next step's B loads (hidden under MFMA phase) ----
            {
                int gstep = ocg * 72 + s + 1;
                if (gstep < 144) {
                    int s2 = gstep % 72, og2 = gstep / 72;
                    const uint4* gq = (const uint4*)(wB + ((size_t)(s2 * 2 + og2)) * 8192);
                    Br0 = gq[tid]; Br1 = gq[tid + 512];
                }
            }
            // ---- A fragments (2 planes x 2 m-tiles) ----
            f16x8 Ah[2], Am[2];
            const int abase = laneA + dx * 8 + (2 * wm + dy) * 144;
#pragma unroll
            for (int mi = 0; mi < 2; ++mi) {
                Ah[mi] = *(const f16x8*)(halo + abase + mi * 144);
                Am[mi] = *(const f16x8*)(halo + 5760 + abase + mi * 144);
            }
            // ---- MFMAs: per nt read B 2 planes, 3 products x 2 mi ----
#pragma unroll
            for (int ni = 0; ni < 4; ++ni) {
                const int nt = 4 * wn + ni;
                f16x8 Bh = *(const f16x8*)(ldsB + ((0 * 8 + nt) * 64 + lane) * 8);
                f16x8 Bm = *(const f16x8*)(ldsB + ((1 * 8 + nt) * 64 + lane) * 8);
#pragma unroll
                for (int mi = 0; mi < 2; ++mi) {
                    f32x4 cH = accH[mi][ni];
                    f32x4 cM = accM[mi][ni];
                    cH = __builtin_amdgcn_mfma_f32_16x16x32_f16(Ah[mi], Bh, cH, 0, 0, 0);
                    cM = __builtin_amdgcn_mfma_f32_16x16x32_f16(Ah[mi], Bm, cM, 0, 0, 0);
                    cM = __builtin_amdgcn_mfma_f32_16x16x32_f16(Am[mi], Bh, cM, 0, 0, 0);
                    accH[mi][ni] = cH;
                    accM[mi][ni] = cM;
                }
            }
        }
        __syncthreads();   // all halo/ldsB reads done -> tS may overwrite
        // ---- writeout + f64 head contraction, 2 slabs of 64 oc (oc ascending) ----
        float cb[4];
#pragma unroll
        for (int ni = 0; ni < 4; ++ni)
            cb[ni] = conv_b[ocg * 128 + (4 * wn + ni) * 16 + col];

#pragma unroll 1
        for (int s2 = 0; s2 < 2; ++s2) {
            if (wn == s2) {
#pragma unroll
                for (int mi = 0; mi < 2; ++mi) {
#pragma unroll
                    for (int r = 0; r < 4; ++r) {
                        int px = (2 * wm + mi) * 16 + 4 * g + r;
                        int sw = px & 15;
#pragma unroll
                        for (int ni = 0; ni < 4; ++ni) {
                            int slot = (ni * 4 + (col >> 2)) ^ sw;
                            float val = accH[mi][ni][r] + accM[mi][ni][r] * 0.0009765625f;
                            tS[px * 64 + slot * 4 + (col & 3)] =
                                fmaxf(val + cb[ni], 0.f);
                        }
                    }
                }
            }
            // stage head weights for this 64-oc slab (threads 0..255)
            if (tid < 256) {
                const int oc2 = tid >> 2;
                const int h0  = (tid & 3) * 4;
                const int oc  = ocg * 128 + s2 * 64 + oc2;
                float vv[4];
#pragma unroll
                for (int q = 0; q < 4; ++q) {
                    int h = h0 + q;
                    vv[q] = (h < 3) ? cls_w[h * 256 + oc]
                          : (h < 15) ? box_w[(h - 3) * 256 + oc] : 0.f;
                }
                *(float4*)&hw2[oc2 * 16 + h0] = make_float4(vv[0], vv[1], vv[2], vv[3]);
            }
            __syncthreads();
            // accumulate: px = tid&127, head-quarter = tid>>7 (oc ascending within slab)
            {
                const int px = tid & 127;
                const int hh = tid >> 7;           // 0..3, heads hh*4..hh*4+3
                const int sw = px & 15;
#pragma unroll 1
                for (int j4 = 0; j4 < 16; ++j4) {
                    float4 t4 = *(const float4*)&tS[px * 64 + (j4 ^ sw) * 4];
                    float tv[4] = {t4.x, t4.y, t4.z, t4.w};
#pragma unroll
                    for (int jj = 0; jj < 4; ++jj) {
                        const float* hb = &hw2[(j4 * 4 + jj) * 16 + hh * 4];
                        float4 h0 = *(const float4*)hb;
                        double tv_d = (double)tv[jj];
                        hacc[0] += tv_d * (double)h0.x;
                        hacc[1] += tv_d * (double)h0.y;
                        hacc[2] += tv_d * (double)h0.z;
                        hacc[3] += tv_d * (double)h0.w;
                    }
                }
            }
            __syncthreads();   // slab reads done before next slab overwrites tS
        }
    }

    // ---- write head outputs to LDS (f64) ----
    {
        const int px = tid & 127;
        const int hh = tid >> 7;
#pragma unroll
        for (int j = 0; j < 4; ++j) houtD[px * 16 + hh * 4 + j] = hacc[j];
    }
    __syncthreads();

    // ---- decode + clip in f64, store f32 (unchanged from passing config) ----
    if (tid < 128) {
        const int px = tid;
        const int gy = ty0 + (px >> 4);
        const int gx = tx0 + (px & 15);
        if (gy < H && gx < W) {
            const int STRIDE = dStrideC[lvl];
            const int SZ     = dSizeC[lvl];
            const int LOFF   = dLoff[lvl];
#pragma unroll 1
            for (int a = 0; a < 3; ++a) {
                double score = houtD[px * 16 + a] + (double)cls_b[a];
                double rg0 = houtD[px * 16 + 3 + a * 4 + 0] + (double)box_b[a * 4 + 0];
                double rg1 = houtD[px * 16 + 3 + a * 4 + 1] + (double)box_b[a * 4 + 1];
                double rg2 = houtD[px * 16 + 3 + a * 4 + 2] + (double)box_b[a * 4 + 2];
                double rg3 = houtD[px * 16 + 3 + a * 4 + 3] + (double)box_b[a * 4 + 3];
                double ratio = (a == 0) ? 0.5 : ((a == 1) ? 1.0 : 2.0);
                double hr = sqrt(ratio), wr = 1.0 / hr;
                double wsd = wr * (double)SZ, hsd = hr * (double)SZ;
                double sx = (double)(gx * STRIDE), sy = (double)(gy * STRIDE);
                float ax0 = (float)(sx - 0.5 * wsd);
                float ay0 = (float)(sy - 0.5 * hsd);
                float ax1 = (float)(sx + 0.5 * wsd);
                float ay1 = (float)(sy + 0.5 * hsd);
                double wa = (double)ax1 - (double)ax0, ha = (double)ay1 - (double)ay0;
                double cxa = (double)ax0 + 0.5 * wa, cya = (double)ay0 + 0.5 * ha;
                double dwv = fmin(rg2, 4.135166556742356);
                double dhv = fmin(rg3, 4.135166556742356);
                double cx = rg0 * wa + cxa, cy = rg1 * ha + cya;
                double w = exp(dwv) * wa, h = exp(dhv) * ha;
                double x0 = cx - 0.5 * w, y0 = cy - 0.5 * h;
                double x1 = cx + 0.5 * w, y1 = cy + 0.5 * h;
                x0 = fmin(fmax(x0, 0.0), 1216.0);
                y0 = fmin(fmax(y0, 0.0), 800.0);
                x1 = fmin(fmax(x1, 0.0), 1216.0);
                y1 = fmin(fmax(y1, 0.0), 800.0);
                int gidx = LOFF + (gy * W + gx) * 3 + a;
                scoresA[(size_t)b * ATOTAL + gidx] = (float)score;
                float4 bx = make_float4((float)x0, (float)y0, (float)x1, (float)y1);
                *(float4*)&boxesA[((size_t)b * ATOTAL + gidx) * 4] = bx;
            }
        }
    }
}

// ---------------- per-(batch,level) top-k via 3-pass radix threshold (1024 thr) ----------------
__global__ __launch_bounds__(1024) void topk_kernel(
    const float* __restrict__ scoresA, const float* __restrict__ boxesA,
    float* __restrict__ selScore, float* __restrict__ selBox,
    int* __restrict__ selValid, int* __restrict__ selAnchor)
{
    const int lvl = blockIdx.x, b = blockIdx.y;
    const int n = dCount[lvl], loff = dLoff[lvl], seg = dSeg[lvl], k = dSegK[lvl];
    const float* sc = scoresA + (size_t)b * ATOTAL + loff;
    const int tid = threadIdx.x;

    float* oS = selScore + b * KSEL;
    float* oB = selBox + (size_t)b * KSEL * 4;
    int* oV = selValid + b * KSEL;
    int* oA = selAnchor + b * KSEL;

    auto emit = [&](int slot, int i) {
        int g = loff + i;
        float s = sc[i];
        float4 bx = *(const float4*)&boxesA[((size_t)b * ATOTAL + g) * 4];
        oS[seg + slot] = s;
        *(float4*)&oB[(size_t)(seg + slot) * 4] = bx;
        oV[seg + slot] = ((bx.z - bx.x) >= 1e-3f && (bx.w - bx.y) >= 1e-3f) ? 1 : 0;
        oA[seg + slot] = g;
    };

    if (n <= k) {
        for (int i = tid; i < n; i += 1024) emit(i, i);
        return;
    }

    __shared__ uint hist[2048];
    __shared__ uint sh_bin, sh_krem;
    __shared__ uint cntG, cntE;
    __shared__ int stash[64];

    uint krem = (uint)k;
    uint prefix = 0;
    for (int pass = 0; pass < 3; ++pass) {
        for (int e = tid; e < 2048; e += 1024) hist[e] = 0;
        __syncthreads();
        for (int i = tid; i < n; i += 1024) {
            uint key = fkey(sc[i]);
            uint bin; bool sel;
            if (pass == 0)      { sel = true;                      bin = key >> 21; }
            else if (pass == 1) { sel = ((key >> 21) == prefix);   bin = (key >> 10) & 0x7FFu; }
            else                { sel = ((key >> 10) == prefix);   bin = key & 0x3FFu; }
            if (sel) atomicAdd(&hist[bin], 1u);
        }
        __syncthreads();
        if (tid == 0) {
            int nb = (pass == 2) ? 1024 : 2048;
            uint c = 0;
            for (int x = nb - 1; x >= 0; --x) {
                uint h = hist[x];
                if (c + h >= krem) { sh_bin = (uint)x; sh_krem = krem - c; break; }
                c += h;
            }
        }
        __syncthreads();
        uint bin = sh_bin; krem = sh_krem;
        if (pass == 0)      prefix = bin;
        else if (pass == 1) prefix = (prefix << 11) | bin;
        else                prefix = (prefix << 10) | bin;
        __syncthreads();
    }
    const uint T = prefix;
    const uint need_eq = krem;
    if (tid == 0) { cntG = 0; cntE = 0; }
    __syncthreads();
    for (int i = tid; i < n; i += 1024) {
        uint key = fkey(sc[i]);
        if (key > T) {
            uint pos = atomicAdd(&cntG, 1u);
            emit((int)pos, i);
        } else if (key == T) {
            uint e = atomicAdd(&cntE, 1u);
            if (e < 64) stash[e] = i;
        }
    }
    __syncthreads();
    if (tid == 0) {
        uint ne = cntE < 64u ? cntE : 64u;
        uint base = cntG;   // == k - need_eq
        for (uint t2 = 0; t2 < need_eq; ++t2) {
            int best = -1, bj = -1;
            for (uint j2 = 0; j2 < ne; ++j2) {
                int v = stash[j2];
                if (v >= 0 && (best < 0 || v < best)) { best = v; bj = j2; }
            }
            if (bj >= 0) { stash[bj] = -1; emit((int)(base + t2), best); }
            else emit((int)(base + t2), 0);
        }
    }
}

// ---------------- per-batch descending sort (score, then anchor-idx asc) ----------------
__global__ __launch_bounds__(1024) void sort_kernel(
    const float* __restrict__ selScore, const float* __restrict__ selBox,
    const int* __restrict__ selValid, const int* __restrict__ selAnchor,
    int* __restrict__ sortedSlot, float* __restrict__ sortedBoxOff,
    ull* __restrict__ validMask)
{
    const int b = blockIdx.x, tid = threadIdx.x;
    __shared__ ull  skey[8192];
    __shared__ uint spay[8192];
    __shared__ ull  svm[NW];

    for (int i = tid; i < 8192; i += 1024) {
        ull kk2; uint pp;
        if (i < KSEL) {
            float s = selScore[b * KSEL + i];
            int v = selValid[b * KSEL + i];
            uint k32 = v ? fkey(s) : 0x007FFFFFu;
            uint a32 = 0xFFFFFFFFu - (uint)selAnchor[b * KSEL + i];
            kk2 = ((ull)k32 << 32) | a32; pp = (uint)i;
        } else { kk2 = 0ull; pp = 0xFFFFFFFFu; }
        skey[i] = kk2; spay[i] = pp;
    }
    __syncthreads();
    for (uint kk = 2; kk <= 8192; kk <<= 1) {
        for (uint j = kk >> 1; j > 0; j >>= 1) {
            for (int i = tid; i < 8192; i += 1024) {
                uint ixj = (uint)i ^ j;
                if (ixj > (uint)i) {
                    bool up = ((((uint)i) & kk) == 0);
                    ull a = skey[i], c = skey[ixj];
                    bool sw = up ? (a < c) : (a > c);
                    if (sw) {
                        skey[i] = c; skey[ixj] = a;
                        uint tp = spay[i]; spay[i] = spay[ixj]; spay[ixj] = tp;
                    }
                }
            }
            __syncthreads();
        }
    }
    for (int i = tid; i < NW; i += 1024) svm[i] = 0ull;
    __syncthreads();
    for (int i = tid; i < KSEL; i += 1024) {
        uint slot = spay[i];
        sortedSlot[b * KSEL + i] = (int)slot;
        int v = selValid[b * KSEL + slot];
        if (v) atomicOr(&svm[i >> 6], 1ull << (i & 63));
        int lvl = (int)slot / 1000;
        float off = 1217.0f * (float)lvl;
        float4 bx = *(const float4*)&selBox[((size_t)b * KSEL + slot) * 4];
        bx.x += off; bx.y += off; bx.z += off; bx.w += off;
        *(float4*)&sortedBoxOff[((size_t)b * KSEL + i) * 4] = bx;
    }
    __syncthreads();
    for (int i = tid; i < NW; i += 1024) validMask[b * NW + i] = svm[i];
}

// ---------------- NMS pairwise suppression bitmask ----------------
__global__ __launch_bounds__(64) void nms_mask(const float* __restrict__ sortedBoxOff,
                                               ull* __restrict__ mat)
{
    const int jb = blockIdx.x, ib = blockIdx.y, b = blockIdx.z;
    const int tid = threadIdx.x;
    __shared__ float4 bj[64];
    __shared__ float  aj[64];
    const int j0 = jb * 64;
    const int jn = (KSEL - j0) < 64 ? (KSEL - j0) : 64;
    if (tid < jn) {
        float4 v = *(const float4*)&sortedBoxOff[((size_t)b * KSEL + j0 + tid) * 4];
        bj[tid] = v; aj[tid] = (v.z - v.x) * (v.w - v.y);
    }
    __syncthreads();
    const int i = ib * 64 + tid;
    if (i >= KSEL) return;
    float4 bi = *(const float4*)&sortedBoxOff[((size_t)b * KSEL + i) * 4];
    float ai = (bi.z - bi.x) * (bi.w - bi.y);
    ull m = 0ull;
    for (int jj = 0; jj < jn; ++jj) {
        int j = j0 + jj;
        if (j <= i) continue;
        float4 bb = bj[jj];
        float ltx = fmaxf(bi.x, bb.x), lty = fmaxf(bi.y, bb.y);
        float rbx = fminf(bi.z, bb.z), rby = fminf(bi.w, bb.w);
        float wx = fmaxf(rbx - ltx, 0.f), wy = fmaxf(rby - lty, 0.f);
        float inter = wx * wy;
        float iou = inter / (ai + aj[jj] - inter + 1e-9f);
        if (iou > 0.7f) m |= (1ull << jj);
    }
    mat[((size_t)b * KSEL + i) * NW + jb] = m;
}

// ---------------- greedy scan (1 wave/batch, double-buffered 16-row prefetch) ----------------
#define LOADG(RA, RB, G) { int base0 = (G) * 16; \
    _Pragma("unroll") for (int d = 0; d < 16; ++d) { int i = base0 + d; \
        RA[d] = (i < KSEL) ? mb[(size_t)i * NW + lane] : 0ull; \
        RB[d] = (hasHi && i < KSEL) ? mb[(size_t)i * NW + 64 + lane] : 0ull; } }
#define PROCG(RA, RB, G) { int base0 = (G) * 16; \
    _Pragma("unroll") for (int d = 0; d < 16; ++d) { int i = base0 + d; \
        if (i < KSEL) { int wi = i >> 6; \
            ull act0 = v0 & ~s0, act1 = v1 & ~s1; \
            ull aw = (wi < 64) ? __shfl(act0, wi, 64) : __shfl(act1, wi - 64, 64); \
            if ((aw >> (i & 63)) & 1ull) { \
                s0 |= RA[d]; s1 |= RB[d]; \
                if (lane == 0) keptPos[b * POST_NMS + nk] = i; \
                ++nk; \
                if (nk == POST_NMS) { if (lane == 0) nkOut[b] = nk; return; } } } } }

__global__ __launch_bounds__(64) void nms_scan(const ull* __restrict__ mat,
                                               const ull* __restrict__ validMask,
                                               int* __restrict__ keptPos,
                                               int* __restrict__ nkOut)
{
    const int b = blockIdx.x, lane = threadIdx.x;
    const bool hasHi = lane < NW - 64;
    ull v0 = validMask[b * NW + lane];
    ull v1 = hasHi ? validMask[b * NW + 64 + lane] : 0ull;
    ull s0 = 0ull, s1 = 0ull;
    int nk = 0;
    const ull* mb = mat + (size_t)b * KSEL * NW;
    const int NG = (KSEL + 15) / 16;   // 297

    ull A0[16], B0[16], A1[16], B1[16];
    LOADG(A0, B0, 0);
    for (int g = 0; g < NG; g += 2) {
        if (g + 1 < NG) LOADG(A1, B1, g + 1);
        PROCG(A0, B0, g);
        if (g + 2 < NG) LOADG(A0, B0, g + 2);
        if (g + 1 < NG) PROCG(A1, B1, g + 1);
    }
    if (lane == 0) nkOut[b] = nk;
}

// ---------------- final output ----------------
__global__ __launch_bounds__(256) void out_kernel(
    const int* __restrict__ keptPos, const int* __restrict__ nkOut,
    const int* __restrict__ sortedSlot,
    const float* __restrict__ selBox, const float* __restrict__ selScore,
    float* __restrict__ out)
{
    int t = blockIdx.x * 256 + threadIdx.x;
    if (t >= BATCH * POST_NMS) return;
    int b = t / POST_NMS, row = t - b * POST_NMS;
    float4 bx = make_float4(0.f, 0.f, 0.f, 0.f);
    float sc = -1e9f;
    if (row < nkOut[b]) {
        int i = keptPos[b * POST_NMS + row];
        int slot = sortedSlot[b * KSEL + i];
        bx = *(const float4*)&selBox[((size_t)b * KSEL + slot) * 4];
        sc = selScore[b * KSEL + slot];
    }
    *(float4*)&out[(size_t)t * 4] = bx;
    out[BATCH * POST_NMS * 4 + t] = sc;
}

// ---------------- host launch ----------------
extern "C" void kernel_launch(void* const* d_in, const int* in_sizes, int n_in,
                              void* d_out, int out_size, void* d_ws, size_t ws_size,
                              hipStream_t stream)
{
    (void)in_sizes; (void)n_in; (void)out_size; (void)ws_size;
    const float* feat[5] = {(const float*)d_in[0], (const float*)d_in[1],
                            (const float*)d_in[2], (const float*)d_in[3],
                            (const float*)d_in[4]};
    const float* conv_w = (const float*)d_in[5];
    const float* conv_b = (const float*)d_in[6];
    const float* cls_w  = (const float*)d_in[7];
    const float* cls_b  = (const float*)d_in[8];
    const float* box_w  = (const float*)d_in[9];
    const float* box_b  = (const float*)d_in[10];
    float* out = (float*)d_out;

    char* ws = (char*)d_ws;
    size_t off = 0;
    auto carve = [&](size_t bytes) -> void* {
        void* p = (void*)(ws + off);
        off += (bytes + 255) & ~(size_t)255;
        return p;
    };
    ushort* wB         = (ushort*)carve((size_t)WB_ELEMS * 2);
    float* scoresA     = (float*)carve((size_t)BATCH * ATOTAL * 4);
    float* boxesA      = (float*)carve((size_t)BATCH * ATOTAL * 16);
    float* selScore    = (float*)carve((size_t)BATCH * KSEL * 4);
    float* selBox      = (float*)carve((size_t)BATCH * KSEL * 16);
    int*   selValid    = (int*)  carve((size_t)BATCH * KSEL * 4);
    int*   selAnchor   = (int*)  carve((size_t)BATCH * KSEL * 4);
    int*   sortedSlot  = (int*)  carve((size_t)BATCH * KSEL * 4);
    float* sortedBoxOff= (float*)carve((size_t)BATCH * KSEL * 16);
    ull*   validMask   = (ull*)  carve((size_t)BATCH * NW * 8);
    ull*   mat         = (ull*)  carve((size_t)BATCH * KSEL * NW * 8);
    int*   keptPos     = (int*)  carve((size_t)BATCH * POST_NMS * 4);
    int*   nkOut       = (int*)  carve(64);

    wt_kernel<<<(WB_ELEMS + 255) / 256, 256, 0, stream>>>(conv_w, wB);

    conv_mfma_all<<<dim3(656, BATCH), 512, 0, stream>>>(
        feat[0], feat[1], feat[2], feat[3], feat[4], wB, conv_b,
        cls_w, cls_b, box_w, box_b, scoresA, boxesA);

    topk_kernel<<<dim3(5, BATCH), 1024, 0, stream>>>(scoresA, boxesA, selScore, selBox, selValid, selAnchor);
    sort_kernel<<<dim3(BATCH), 1024, 0, stream>>>(selScore, selBox, selValid, selAnchor, sortedSlot, sortedBoxOff, validMask);
    nms_mask<<<dim3(NW, NW, BATCH), 64, 0, stream>>>(sortedBoxOff, mat);
    nms_scan<<<dim3(BATCH), 64, 0, stream>>>(mat, validMask, keptPos, nkOut);
    out_kernel<<<dim3((BATCH * POST_NMS + 255) / 256), 256, 0, stream>>>(keptPos, nkOut, sortedSlot, selBox, selScore, out);
}

// Round 11
// 1527.273 us; speedup vs baseline: 24.3260x; 1.0463x over previous
//
#include <hip/hip_runtime.h>
#include <hip/hip_fp16.h>
#include <stdint.h>
#include <math.h>

typedef unsigned int uint;
typedef unsigned short ushort;
typedef unsigned long long ull;
typedef __attribute__((ext_vector_type(8))) _Float16 f16x8;
typedef __attribute__((ext_vector_type(4))) float f32x4;

#define BATCH 2
#define ATOTAL 242991
#define KSEL 4741
#define NW 75
#define POST_NMS 1000
#define WB_ELEMS (2*8*3*3*2*8*64*8)   // 1,179,648 u16 = 2.25 MB
#define NPAIRS 2850                   // 75*76/2 upper-triangle block pairs

// runtime-indexed device copies
__device__ __constant__ int dLoff[5]  = {0,182400,228000,239400,242250};
__device__ __constant__ int dCount[5] = {182400,45600,11400,2850,741};
__device__ __constant__ int dSeg[5]   = {0,1000,2000,3000,4000};
__device__ __constant__ int dSegK[5]  = {1000,1000,1000,1000,741};
__device__ __constant__ int dHc[5]     = {200,100,50,25,13};
__device__ __constant__ int dWc[5]     = {304,152,76,38,19};
__device__ __constant__ int dTilesX[5] = {19,10,5,3,2};
__device__ __constant__ int dCumT[6]   = {0,475,605,640,652,656};
__device__ __constant__ int dStrideC[5]= {4,8,16,32,64};
__device__ __constant__ int dSizeC[5]  = {32,64,128,256,512};

__device__ __forceinline__ uint fkey(float f) {
    uint u = __float_as_uint(f);
    return (u & 0x80000000u) ? ~u : (u | 0x80000000u);
}
__device__ __forceinline__ ushort h2u(__half h) {
    union { __half h; ushort u; } x; x.h = h; return x.u;
}

// ---------------- weight gen: conv_w -> wB fp16 (h, m*1024), slab-contiguous per (ocg,icblk,dy) ----
// layout: [ocg2][icblk8][dy3][dx3][pl2][nt8][lane64][e8] u16  (one (ocg,icblk,dy) slab = 24576 u16)
__global__ __launch_bounds__(256) void wt_kernel(const float* __restrict__ conv_w,
                                                 ushort* __restrict__ wB) {
    int t = blockIdx.x * 256 + threadIdx.x;
    if (t >= WB_ELEMS) return;
    int e    = t & 7;
    int lane = (t >> 3) & 63;
    int nt   = (t >> 9) & 7;
    int pl   = (t >> 12) & 1;
    int r    = t >> 13;            // dx + 3*(dy + 3*(icblk + 8*ocg))
    int dx = r % 3; r /= 3;
    int dy = r % 3; r /= 3;
    int icblk = r & 7;
    int ocg = r >> 3;
    int oc = ocg * 128 + nt * 16 + (lane & 15);
    int ic = icblk * 32 + ((lane >> 4) << 3) + e;
    float v = conv_w[(size_t)oc * 2304 + ic * 9 + dy * 3 + dx];
    __half h = __float2half(v);
    float rr = (v - __half2float(h)) * 1024.0f;   // scaled residual stays fp16-normal
    __half m = __float2half(rr);
    wB[t] = (pl == 0) ? h2u(h) : h2u(m);
}

// ---------------- MFMA conv3x3 (fp16x2 scaled-m split) + f64 heads/decode ----
// grid (656, 2), 512 threads = 8 waves. tile 8 rows x 16 cols = 128 px.
// Round-11: step = (icblk, dy) covering all 3 dx -> 48 steps (was 144), 48KB B-slab
// single-buffered + reg-prefetch. 3x bigger compute window per barrier pair.
// MFMA order per accumulator (dy-major, dx-ascending) bit-identical to round 10.
__global__ __launch_bounds__(512) void conv_mfma_all(
    const float* __restrict__ f0, const float* __restrict__ f1,
    const float* __restrict__ f2, const float* __restrict__ f3,
    const float* __restrict__ f4, const ushort* __restrict__ wB,
    const float* __restrict__ conv_b,
    const float* __restrict__ cls_w, const float* __restrict__ cls_b,
    const float* __restrict__ box_w, const float* __restrict__ box_b,
    float* __restrict__ scoresA, float* __restrict__ boxesA)
{
    const int bidx = blockIdx.x;
    const int b    = blockIdx.y;
    const int tid  = threadIdx.x;

    int lvl = 0;
#pragma unroll
    for (int l = 1; l < 5; ++l) if (bidx >= dCumT[l]) lvl = l;
    const int tile   = bidx - dCumT[lvl];
    const int H      = dHc[lvl], W = dWc[lvl];
    const int TILESX = dTilesX[lvl];
    const int ty0    = (tile / TILESX) * 8;
    const int tx0    = (tile % TILESX) * 16;
    const int HW     = H * W;
    const float* feat = (lvl == 0) ? f0 : (lvl == 1) ? f1 : (lvl == 2) ? f2 : (lvl == 3) ? f3 : f4;
    const float* fb = feat + (size_t)b * 256 * HW;

    __shared__ __align__(16) char uni[72192];
    ushort* halo = (ushort*)uni;                 // [2pl][5760] u16 = 23040 B
    ushort* ldsB = (ushort*)(uni + 23040);       // [3dx][2pl][8nt][64lane][8e] = 49152 B
    float*  tS   = (float*)uni;                  // 32768 B (aliases halo+B head, conv done)
    float*  hw2  = (float*)(uni + 32768);        // 4096 B (inside B region, conv done)
    double* houtD= (double*)uni;                 // 16384 B (aliases tS, slabs done)

    const int lane = tid & 63, wave = tid >> 6;
    const int wm = wave >> 1, wn = wave & 1;
    const int g = lane >> 4, col = lane & 15;
    const int laneA = g * 1440 + col * 8;        // u16 idx, lane-constant part

    // halo staging coords (icblk-invariant): 5760 elems / 512 threads = 12 slots
    int  hdst[12]; int hoff[12]; bool hval[12];
#pragma unroll
    for (int j = 0; j < 12; ++j) {
        int e = tid + j * 512;
        hdst[j] = -1; hoff[j] = 0; hval[j] = false;
        if (e < 5760) {
            int ic = e / 180, rem = e - ic * 180;
            int hrow = rem / 18, hcol = rem - hrow * 18;
            int gy = ty0 + hrow - 1, gx = tx0 + hcol - 1;
            hdst[j] = (((ic >> 3) * 10 + hrow) * 18 + hcol) * 8 + (ic & 7);
            if (gy >= 0 && gy < H && gx >= 0 && gx < W) {
                hval[j] = true; hoff[j] = ic * HW + gy * W + gx;
            }
        }
    }

    double hacc[4] = {0,0,0,0};   // per-thread f64 head accumulators (4 heads)

    // B prefetch registers (6 x uint4 per thread = 48 KB slab at 512 threads)
    uint4 Br0, Br1, Br2, Br3, Br4, Br5;
    {
        const uint4* gq = (const uint4*)wB;
        Br0 = gq[tid];        Br1 = gq[tid + 512];
        Br2 = gq[tid + 1024]; Br3 = gq[tid + 1536];
        Br4 = gq[tid + 2048]; Br5 = gq[tid + 2560];
    }

#pragma unroll 1
    for (int ocg = 0; ocg < 2; ++ocg) {
        f32x4 accH[2][4], accM[2][4];
#pragma unroll
        for (int mi = 0; mi < 2; ++mi)
#pragma unroll
            for (int ni = 0; ni < 4; ++ni) {
                accH[mi][ni] = (f32x4){0.f, 0.f, 0.f, 0.f};
                accM[mi][ni] = (f32x4){0.f, 0.f, 0.f, 0.f};
            }

#pragma unroll 1
        for (int s = 0; s < 24; ++s) {        // step = (icblk, dy)
            const int icblk = s / 3;
            const int dy    = s - icblk * 3;

            __syncthreads();   // prior step's halo/ldsB reads (and epilogue reads) done
            // ---- stage halo at icblk start: batch-issue 12 loads, then convert+write ----
            if (dy == 0) {
                float hv[12];
                const float* fcb = fb + (size_t)icblk * 32 * HW;
#pragma unroll
                for (int j = 0; j < 12; ++j)
                    hv[j] = hval[j] ? fcb[hoff[j]] : 0.f;
#pragma unroll
                for (int j = 0; j < 12; ++j) {
                    if (hdst[j] >= 0) {
                        float v = hv[j];
                        __half h = __float2half(v);
                        float rr = (v - __half2float(h)) * 1024.0f;
                        __half m = __float2half(rr);
                        int li = hdst[j];
                        halo[li] = h2u(h); halo[5760 + li] = h2u(m);
                    }
                }
            }
            // ---- write prefetched B slab (48 KB) to LDS ----
            {
                uint4* lq = (uint4*)ldsB;
                lq[tid] = Br0;         lq[tid + 512]  = Br1;
                lq[tid + 1024] = Br2;  lq[tid + 1536] = Br3;
                lq[tid + 2048] = Br4;  lq[tid + 2560] = Br5;
            }
            __syncthreads();   // halo + B visible
            // ---- issue next slab's loads (hidden under MFMA phase) ----
            {
                int gstep = ocg * 24 + s + 1;
                if (gstep < 48) {
                    const uint4* gq = (const uint4*)(wB + (size_t)gstep * 24576);
                    Br0 = gq[tid];        Br1 = gq[tid + 512];
                    Br2 = gq[tid + 1024]; Br3 = gq[tid + 1536];
                    Br4 = gq[tid + 2048]; Br5 = gq[tid + 2560];
                }
            }
            // ---- compute: 3 dx sub-steps, 72 MFMAs per wave ----
#pragma unroll 1
            for (int dx = 0; dx < 3; ++dx) {
                f16x8 Ah[2], Am[2];
                const int abase = laneA + dx * 8 + (2 * wm + dy) * 144;
#pragma unroll
                for (int mi = 0; mi < 2; ++mi) {
                    Ah[mi] = *(const f16x8*)(halo + abase + mi * 144);
                    Am[mi] = *(const f16x8*)(halo + 5760 + abase + mi * 144);
                }
#pragma unroll
                for (int ni = 0; ni < 4; ++ni) {
                    const int nt = 4 * wn + ni;
                    f16x8 Bh = *(const f16x8*)(ldsB + (size_t)(dx * 16 + nt) * 512 + lane * 8);
                    f16x8 Bm = *(const f16x8*)(ldsB + (size_t)(dx * 16 + 8 + nt) * 512 + lane * 8);
#pragma unroll
                    for (int mi = 0; mi < 2; ++mi) {
                        f32x4 cH = accH[mi][ni];
                        f32x4 cM = accM[mi][ni];
                        cH = __builtin_amdgcn_mfma_f32_16x16x32_f16(Ah[mi], Bh, cH, 0, 0, 0);
                        cM = __builtin_amdgcn_mfma_f32_16x16x32_f16(Ah[mi], Bm, cM, 0, 0, 0);
                        cM = __builtin_amdgcn_mfma_f32_16x16x32_f16(Am[mi], Bh, cM, 0, 0, 0);
                        accH[mi][ni] = cH;
                        accM[mi][ni] = cM;
                    }
                }
            }
        }
        __syncthreads();   // all halo/ldsB reads done -> tS may overwrite
        // ---- writeout + f64 head contraction, 2 slabs of 64 oc (oc ascending) ----
        float cb[4];
#pragma unroll
        for (int ni = 0; ni < 4; ++ni)
            cb[ni] = conv_b[ocg * 128 + (4 * wn + ni) * 16 + col];

#pragma unroll 1
        for (int s2 = 0; s2 < 2; ++s2) {
            if (wn == s2) {
#pragma unroll
                for (int mi = 0; mi < 2; ++mi) {
#pragma unroll
                    for (int r = 0; r < 4; ++r) {
                        int px = (2 * wm + mi) * 16 + 4 * g + r;
                        int sw = px & 15;
#pragma unroll
                        for (int ni = 0; ni < 4; ++ni) {
                            int slot = (ni * 4 + (col >> 2)) ^ sw;
                            float val = accH[mi][ni][r] + accM[mi][ni][r] * 0.0009765625f;
                            tS[px * 64 + slot * 4 + (col & 3)] =
                                fmaxf(val + cb[ni], 0.f);
                        }
                    }
                }
            }
            // stage head weights for this 64-oc slab (threads 0..255)
            if (tid < 256) {
                const int oc2 = tid >> 2;
                const int h0  = (tid & 3) * 4;
                const int oc  = ocg * 128 + s2 * 64 + oc2;
                float vv[4];
#pragma unroll
                for (int q = 0; q < 4; ++q) {
                    int h = h0 + q;
                    vv[q] = (h < 3) ? cls_w[h * 256 + oc]
                          : (h < 15) ? box_w[(h - 3) * 256 + oc] : 0.f;
                }
                *(float4*)&hw2[oc2 * 16 + h0] = make_float4(vv[0], vv[1], vv[2], vv[3]);
            }
            __syncthreads();
            // accumulate: px = tid&127, head-quarter = tid>>7 (oc ascending within slab)
            {
                const int px = tid & 127;
                const int hh = tid >> 7;           // 0..3, heads hh*4..hh*4+3
                const int sw = px & 15;
#pragma unroll 1
                for (int j4 = 0; j4 < 16; ++j4) {
                    float4 t4 = *(const float4*)&tS[px * 64 + (j4 ^ sw) * 4];
                    float tv[4] = {t4.x, t4.y, t4.z, t4.w};
#pragma unroll
                    for (int jj = 0; jj < 4; ++jj) {
                        const float* hb = &hw2[(j4 * 4 + jj) * 16 + hh * 4];
                        float4 h0 = *(const float4*)hb;
                        double tv_d = (double)tv[jj];
                        hacc[0] += tv_d * (double)h0.x;
                        hacc[1] += tv_d * (double)h0.y;
                        hacc[2] += tv_d * (double)h0.z;
                        hacc[3] += tv_d * (double)h0.w;
                    }
                }
            }
            __syncthreads();   // slab reads done before next slab overwrites tS
        }
    }

    // ---- write head outputs to LDS (f64) ----
    {
        const int px = tid & 127;
        const int hh = tid >> 7;
#pragma unroll
        for (int j = 0; j < 4; ++j) houtD[px * 16 + hh * 4 + j] = hacc[j];
    }
    __syncthreads();

    // ---- decode + clip in f64, store f32 (unchanged from passing config) ----
    if (tid < 128) {
        const int px = tid;
        const int gy = ty0 + (px >> 4);
        const int gx = tx0 + (px & 15);
        if (gy < H && gx < W) {
            const int STRIDE = dStrideC[lvl];
            const int SZ     = dSizeC[lvl];
            const int LOFF   = dLoff[lvl];
#pragma unroll 1
            for (int a = 0; a < 3; ++a) {
                double score = houtD[px * 16 + a] + (double)cls_b[a];
                double rg0 = houtD[px * 16 + 3 + a * 4 + 0] + (double)box_b[a * 4 + 0];
                double rg1 = houtD[px * 16 + 3 + a * 4 + 1] + (double)box_b[a * 4 + 1];
                double rg2 = houtD[px * 16 + 3 + a * 4 + 2] + (double)box_b[a * 4 + 2];
                double rg3 = houtD[px * 16 + 3 + a * 4 + 3] + (double)box_b[a * 4 + 3];
                double ratio = (a == 0) ? 0.5 : ((a == 1) ? 1.0 : 2.0);
                double hr = sqrt(ratio), wr = 1.0 / hr;
                double wsd = wr * (double)SZ, hsd = hr * (double)SZ;
                double sx = (double)(gx * STRIDE), sy = (double)(gy * STRIDE);
                float ax0 = (float)(sx - 0.5 * wsd);
                float ay0 = (float)(sy - 0.5 * hsd);
                float ax1 = (float)(sx + 0.5 * wsd);
                float ay1 = (float)(sy + 0.5 * hsd);
                double wa = (double)ax1 - (double)ax0, ha = (double)ay1 - (double)ay0;
                double cxa = (double)ax0 + 0.5 * wa, cya = (double)ay0 + 0.5 * ha;
                double dwv = fmin(rg2, 4.135166556742356);
                double dhv = fmin(rg3, 4.135166556742356);
                double cx = rg0 * wa + cxa, cy = rg1 * ha + cya;
                double w = exp(dwv) * wa, h = exp(dhv) * ha;
                double x0 = cx - 0.5 * w, y0 = cy - 0.5 * h;
                double x1 = cx + 0.5 * w, y1 = cy + 0.5 * h;
                x0 = fmin(fmax(x0, 0.0), 1216.0);
                y0 = fmin(fmax(y0, 0.0), 800.0);
                x1 = fmin(fmax(x1, 0.0), 1216.0);
                y1 = fmin(fmax(y1, 0.0), 800.0);
                int gidx = LOFF + (gy * W + gx) * 3 + a;
                scoresA[(size_t)b * ATOTAL + gidx] = (float)score;
                float4 bx = make_float4((float)x0, (float)y0, (float)x1, (float)y1);
                *(float4*)&boxesA[((size_t)b * ATOTAL + gidx) * 4] = bx;
            }
        }
    }
}

// ---------------- per-(batch,level) top-k via 3-pass radix threshold (1024 thr) ----------------
__global__ __launch_bounds__(1024) void topk_kernel(
    const float* __restrict__ scoresA, const float* __restrict__ boxesA,
    float* __restrict__ selScore, float* __restrict__ selBox,
    int* __restrict__ selValid, int* __restrict__ selAnchor)
{
    const int lvl = blockIdx.x, b = blockIdx.y;
    const int n = dCount[lvl], loff = dLoff[lvl], seg = dSeg[lvl], k = dSegK[lvl];
    const float* sc = scoresA + (size_t)b * ATOTAL + loff;
    const int tid = threadIdx.x;

    float* oS = selScore + b * KSEL;
    float* oB = selBox + (size_t)b * KSEL * 4;
    int* oV = selValid + b * KSEL;
    int* oA = selAnchor + b * KSEL;

    auto emit = [&](int slot, int i) {
        int g = loff + i;
        float s = sc[i];
        float4 bx = *(const float4*)&boxesA[((size_t)b * ATOTAL + g) * 4];
        oS[seg + slot] = s;
        *(float4*)&oB[(size_t)(seg + slot) * 4] = bx;
        oV[seg + slot] = ((bx.z - bx.x) >= 1e-3f && (bx.w - bx.y) >= 1e-3f) ? 1 : 0;
        oA[seg + slot] = g;
    };

    if (n <= k) {
        for (int i = tid; i < n; i += 1024) emit(i, i);
        return;
    }

    __shared__ uint hist[2048];
    __shared__ uint sh_bin, sh_krem;
    __shared__ uint cntG, cntE;
    __shared__ int stash[64];

    uint krem = (uint)k;
    uint prefix = 0;
    for (int pass = 0; pass < 3; ++pass) {
        for (int e = tid; e < 2048; e += 1024) hist[e] = 0;
        __syncthreads();
        for (int i = tid; i < n; i += 1024) {
            uint key = fkey(sc[i]);
            uint bin; bool sel;
            if (pass == 0)      { sel = true;                      bin = key >> 21; }
            else if (pass == 1) { sel = ((key >> 21) == prefix);   bin = (key >> 10) & 0x7FFu; }
            else                { sel = ((key >> 10) == prefix);   bin = key & 0x3FFu; }
            if (sel) atomicAdd(&hist[bin], 1u);
        }
        __syncthreads();
        if (tid == 0) {
            int nb = (pass == 2) ? 1024 : 2048;
            uint c = 0;
            for (int x = nb - 1; x >= 0; --x) {
                uint h = hist[x];
                if (c + h >= krem) { sh_bin = (uint)x; sh_krem = krem - c; break; }
                c += h;
            }
        }
        __syncthreads();
        uint bin = sh_bin; krem = sh_krem;
        if (pass == 0)      prefix = bin;
        else if (pass == 1) prefix = (prefix << 11) | bin;
        else                prefix = (prefix << 10) | bin;
        __syncthreads();
    }
    const uint T = prefix;
    const uint need_eq = krem;
    if (tid == 0) { cntG = 0; cntE = 0; }
    __syncthreads();
    for (int i = tid; i < n; i += 1024) {
        uint key = fkey(sc[i]);
        if (key > T) {
            uint pos = atomicAdd(&cntG, 1u);
            emit((int)pos, i);
        } else if (key == T) {
            uint e = atomicAdd(&cntE, 1u);
            if (e < 64) stash[e] = i;
        }
    }
    __syncthreads();
    if (tid == 0) {
        uint ne = cntE < 64u ? cntE : 64u;
        uint base = cntG;   // == k - need_eq
        for (uint t2 = 0; t2 < need_eq; ++t2) {
            int best = -1, bj = -1;
            for (uint j2 = 0; j2 < ne; ++j2) {
                int v = stash[j2];
                if (v >= 0 && (best < 0 || v < best)) { best = v; bj = j2; }
            }
            if (bj >= 0) { stash[bj] = -1; emit((int)(base + t2), best); }
            else emit((int)(base + t2), 0);
        }
    }
}

// ---------------- per-batch descending sort (score, then anchor-idx asc) ----------------
__global__ __launch_bounds__(1024) void sort_kernel(
    const float* __restrict__ selScore, const float* __restrict__ selBox,
    const int* __restrict__ selValid, const int* __restrict__ selAnchor,
    int* __restrict__ sortedSlot, float* __restrict__ sortedBoxOff,
    ull* __restrict__ validMask)
{
    const int b = blockIdx.x, tid = threadIdx.x;
    __shared__ ull  skey[8192];
    __shared__ uint spay[8192];
    __shared__ ull  svm[NW];

    for (int i = tid; i < 8192; i += 1024) {
        ull kk2; uint pp;
        if (i < KSEL) {
            float s = selScore[b * KSEL + i];
            int v = selValid[b * KSEL + i];
            uint k32 = v ? fkey(s) : 0x007FFFFFu;
            uint a32 = 0xFFFFFFFFu - (uint)selAnchor[b * KSEL + i];
            kk2 = ((ull)k32 << 32) | a32; pp = (uint)i;
        } else { kk2 = 0ull; pp = 0xFFFFFFFFu; }
        skey[i] = kk2; spay[i] = pp;
    }
    __syncthreads();
    for (uint kk = 2; kk <= 8192; kk <<= 1) {
        for (uint j = kk >> 1; j > 0; j >>= 1) {
            for (int i = tid; i < 8192; i += 1024) {
                uint ixj = (uint)i ^ j;
                if (ixj > (uint)i) {
                    bool up = ((((uint)i) & kk) == 0);
                    ull a = skey[i], c = skey[ixj];
                    bool sw = up ? (a < c) : (a > c);
                    if (sw) {
                        skey[i] = c; skey[ixj] = a;
                        uint tp = spay[i]; spay[i] = spay[ixj]; spay[ixj] = tp;
                    }
                }
            }
            __syncthreads();
        }
    }
    for (int i = tid; i < NW; i += 1024) svm[i] = 0ull;
    __syncthreads();
    for (int i = tid; i < KSEL; i += 1024) {
        uint slot = spay[i];
        sortedSlot[b * KSEL + i] = (int)slot;
        int v = selValid[b * KSEL + slot];
        if (v) atomicOr(&svm[i >> 6], 1ull << (i & 63));
        int lvl = (int)slot / 1000;
        float off = 1217.0f * (float)lvl;
        float4 bx = *(const float4*)&selBox[((size_t)b * KSEL + slot) * 4];
        bx.x += off; bx.y += off; bx.z += off; bx.w += off;
        *(float4*)&sortedBoxOff[((size_t)b * KSEL + i) * 4] = bx;
    }
    __syncthreads();
    for (int i = tid; i < NW; i += 1024) validMask[b * NW + i] = svm[i];
}

// ---------------- NMS pairwise suppression bitmask (upper-triangle launch) ----------------
__global__ __launch_bounds__(64) void nms_mask(const float* __restrict__ sortedBoxOff,
                                               ull* __restrict__ mat)
{
    const int b = blockIdx.y;
    const int tid = threadIdx.x;
    // decode linear pair index -> (ib, jb) with jb >= ib
    int rem = blockIdx.x, ib = 0;
    while (rem >= NW - ib) { rem -= NW - ib; ++ib; }
    const int jb = ib + rem;

    __shared__ float4 bj[64];
    __shared__ float  aj[64];
    const int j0 = jb * 64;
    const int jn = (KSEL - j0) < 64 ? (KSEL - j0) : 64;
    if (tid < jn) {
        float4 v = *(const float4*)&sortedBoxOff[((size_t)b * KSEL + j0 + tid) * 4];
        bj[tid] = v; aj[tid] = (v.z - v.x) * (v.w - v.y);
    }
    __syncthreads();
    const int i = ib * 64 + tid;
    if (i >= KSEL) return;
    float4 bi = *(const float4*)&sortedBoxOff[((size_t)b * KSEL + i) * 4];
    float ai = (bi.z - bi.x) * (bi.w - bi.y);
    ull m = 0ull;
    for (int jj = 0; jj < jn; ++jj) {
        int j = j0 + jj;
        if (j <= i) continue;
        float4 bb = bj[jj];
        float ltx = fmaxf(bi.x, bb.x), lty = fmaxf(bi.y, bb.y);
        float rbx = fminf(bi.z, bb.z), rby = fminf(bi.w, bb.w);
        float wx = fmaxf(rbx - ltx, 0.f), wy = fmaxf(rby - lty, 0.f);
        float inter = wx * wy;
        float iou = inter / (ai + aj[jj] - inter + 1e-9f);
        if (iou > 0.7f) m |= (1ull << jj);
    }
    mat[((size_t)b * KSEL + i) * NW + jb] = m;
}

// ---------------- greedy scan (1 wave/batch, double-buffered 16-row prefetch) ----------------
// lower-triangle words (lane < i>>6) are never written by the triangular nms_mask ->
// masked to 0 at use (they were explicit zeros before; result identical).
#define LOADG(RA, RB, G) { int base0 = (G) * 16; \
    _Pragma("unroll") for (int d = 0; d < 16; ++d) { int i = base0 + d; \
        RA[d] = (i < KSEL) ? mb[(size_t)i * NW + lane] : 0ull; \
        RB[d] = (hasHi && i < KSEL) ? mb[(size_t)i * NW + 64 + lane] : 0ull; } }
#define PROCG(RA, RB, G) { int base0 = (G) * 16; \
    _Pragma("unroll") for (int d = 0; d < 16; ++d) { int i = base0 + d; \
        if (i < KSEL) { int wi = i >> 6; \
            ull act0 = v0 & ~s0, act1 = v1 & ~s1; \
            ull aw = (wi < 64) ? __shfl(act0, wi, 64) : __shfl(act1, wi - 64, 64); \
            if ((aw >> (i & 63)) & 1ull) { \
                s0 |= (lane >= wi) ? RA[d] : 0ull; \
                s1 |= (lane + 64 >= wi) ? RB[d] : 0ull; \
                if (lane == 0) keptPos[b * POST_NMS + nk] = i; \
                ++nk; \
                if (nk == POST_NMS) { if (lane == 0) nkOut[b] = nk; return; } } } } }

__global__ __launch_bounds__(64) void nms_scan(const ull* __restrict__ mat,
                                               const ull* __restrict__ validMask,
                                               int* __restrict__ keptPos,
                                               int* __restrict__ nkOut)
{
    const int b = blockIdx.x, lane = threadIdx.x;
    const bool hasHi = lane < NW - 64;
    ull v0 = validMask[b * NW + lane];
    ull v1 = hasHi ? validMask[b * NW + 64 + lane] : 0ull;
    ull s0 = 0ull, s1 = 0ull;
    int nk = 0;
    const ull* mb = mat + (size_t)b * KSEL * NW;
    const int NG = (KSEL + 15) / 16;   // 297

    ull A0[16], B0[16], A1[16], B1[16];
    LOADG(A0, B0, 0);
    for (int g = 0; g < NG; g += 2) {
        if (g + 1 < NG) LOADG(A1, B1, g + 1);
        PROCG(A0, B0, g);
        if (g + 2 < NG) LOADG(A0, B0, g + 2);
        if (g + 1 < NG) PROCG(A1, B1, g + 1);
    }
    if (lane == 0) nkOut[b] = nk;
}

// ---------------- final output ----------------
__global__ __launch_bounds__(256) void out_kernel(
    const int* __restrict__ keptPos, const int* __restrict__ nkOut,
    const int* __restrict__ sortedSlot,
    const float* __restrict__ selBox, const float* __restrict__ selScore,
    float* __restrict__ out)
{
    int t = blockIdx.x * 256 + threadIdx.x;
    if (t >= BATCH * POST_NMS) return;
    int b = t / POST_NMS, row = t - b * POST_NMS;
    float4 bx = make_float4(0.f, 0.f, 0.f, 0.f);
    float sc = -1e9f;
    if (row < nkOut[b]) {
        int i = keptPos[b * POST_NMS + row];
        int slot = sortedSlot[b * KSEL + i];
        bx = *(const float4*)&selBox[((size_t)b * KSEL + slot) * 4];
        sc = selScore[b * KSEL + slot];
    }
    *(float4*)&out[(size_t)t * 4] = bx;
    out[BATCH * POST_NMS * 4 + t] = sc;
}

// ---------------- host launch ----------------
extern "C" void kernel_launch(void* const* d_in, const int* in_sizes, int n_in,
                              void* d_out, int out_size, void* d_ws, size_t ws_size,
                              hipStream_t stream)
{
    (void)in_sizes; (void)n_in; (void)out_size; (void)ws_size;
    const float* feat[5] = {(const float*)d_in[0], (const float*)d_in[1],
                            (const float*)d_in[2], (const float*)d_in[3],
                            (const float*)d_in[4]};
    const float* conv_w = (const float*)d_in[5];
    const float* conv_b = (const float*)d_in[6];
    const float* cls_w  = (const float*)d_in[7];
    const float* cls_b  = (const float*)d_in[8];
    const float* box_w  = (const float*)d_in[9];
    const float* box_b  = (const float*)d_in[10];
    float* out = (float*)d_out;

    char* ws = (char*)d_ws;
    size_t off = 0;
    auto carve = [&](size_t bytes) -> void* {
        void* p = (void*)(ws + off);
        off += (bytes + 255) & ~(size_t)255;
        return p;
    };
    ushort* wB         = (ushort*)carve((size_t)WB_ELEMS * 2);
    float* scoresA     = (float*)carve((size_t)BATCH * ATOTAL * 4);
    float* boxesA      = (float*)carve((size_t)BATCH * ATOTAL * 16);
    float* selScore    = (float*)carve((size_t)BATCH * KSEL * 4);
    float* selBox      = (float*)carve((size_t)BATCH * KSEL * 16);
    int*   selValid    = (int*)  carve((size_t)BATCH * KSEL * 4);
    int*   selAnchor   = (int*)  carve((size_t)BATCH * KSEL * 4);
    int*   sortedSlot  = (int*)  carve((size_t)BATCH * KSEL * 4);
    float* sortedBoxOff= (float*)carve((size_t)BATCH * KSEL * 16);
    ull*   validMask   = (ull*)  carve((size_t)BATCH * NW * 8);
    ull*   mat         = (ull*)  carve((size_t)BATCH * KSEL * NW * 8);
    int*   keptPos     = (int*)  carve((size_t)BATCH * POST_NMS * 4);
    int*   nkOut       = (int*)  carve(64);

    wt_kernel<<<(WB_ELEMS + 255) / 256, 256, 0, stream>>>(conv_w, wB);

    conv_mfma_all<<<dim3(656, BATCH), 512, 0, stream>>>(
        feat[0], feat[1], feat[2], feat[3], feat[4], wB, conv_b,
        cls_w, cls_b, box_w, box_b, scoresA, boxesA);

    topk_kernel<<<dim3(5, BATCH), 1024, 0, stream>>>(scoresA, boxesA, selScore, selBox, selValid, selAnchor);
    sort_kernel<<<dim3(BATCH), 1024, 0, stream>>>(selScore, selBox, selValid, selAnchor, sortedSlot, sortedBoxOff, validMask);
    nms_mask<<<dim3(NPAIRS, BATCH), 64, 0, stream>>>(sortedBoxOff, mat);
    nms_scan<<<dim3(BATCH), 64, 0, stream>>>(mat, validMask, keptPos, nkOut);
    out_kernel<<<dim3((BATCH * POST_NMS + 255) / 256), 256, 0, stream>>>(keptPos, nkOut, sortedSlot, selBox, selScore, out);
}

// Round 12
// 1479.339 us; speedup vs baseline: 25.1142x; 1.0324x over previous
//
#include <hip/hip_runtime.h>
#include <hip/hip_fp16.h>
#include <stdint.h>
#include <math.h>

typedef unsigned int uint;
typedef unsigned short ushort;
typedef unsigned long long ull;
typedef __attribute__((ext_vector_type(8))) _Float16 f16x8;
typedef __attribute__((ext_vector_type(4))) float f32x4;

#define BATCH 2
#define ATOTAL 242991
#define KSEL 4741
#define NW 75
#define POST_NMS 1000
#define WB_ELEMS (2*8*3*3*2*8*64*8)   // 1,179,648 u16 = 2.25 MB
#define NPAIRS 2850                   // 75*76/2 upper-triangle block pairs

// runtime-indexed device copies
__device__ __constant__ int dLoff[5]  = {0,182400,228000,239400,242250};
__device__ __constant__ int dCount[5] = {182400,45600,11400,2850,741};
__device__ __constant__ int dSeg[5]   = {0,1000,2000,3000,4000};
__device__ __constant__ int dSegK[5]  = {1000,1000,1000,1000,741};
__device__ __constant__ int dHc[5]     = {200,100,50,25,13};
__device__ __constant__ int dWc[5]     = {304,152,76,38,19};
__device__ __constant__ int dTilesX[5] = {19,10,5,3,2};
__device__ __constant__ int dCumT[6]   = {0,475,605,640,652,656};
__device__ __constant__ int dStrideC[5]= {4,8,16,32,64};
__device__ __constant__ int dSizeC[5]  = {32,64,128,256,512};

__device__ __forceinline__ uint fkey(float f) {
    uint u = __float_as_uint(f);
    return (u & 0x80000000u) ? ~u : (u | 0x80000000u);
}
__device__ __forceinline__ ushort h2u(__half h) {
    union { __half h; ushort u; } x; x.h = h; return x.u;
}

// ---------------- weight gen: conv_w -> wB fp16 (h, m*1024), slab-contiguous per (ocg,icblk,dy) ----
// layout: [ocg2][icblk8][dy3][dx3][pl2][nt8][lane64][e8] u16  (one (ocg,icblk,dy) slab = 24576 u16)
__global__ __launch_bounds__(256) void wt_kernel(const float* __restrict__ conv_w,
                                                 ushort* __restrict__ wB) {
    int t = blockIdx.x * 256 + threadIdx.x;
    if (t >= WB_ELEMS) return;
    int e    = t & 7;
    int lane = (t >> 3) & 63;
    int nt   = (t >> 9) & 7;
    int pl   = (t >> 12) & 1;
    int r    = t >> 13;            // dx + 3*(dy + 3*(icblk + 8*ocg))
    int dx = r % 3; r /= 3;
    int dy = r % 3; r /= 3;
    int icblk = r & 7;
    int ocg = r >> 3;
    int oc = ocg * 128 + nt * 16 + (lane & 15);
    int ic = icblk * 32 + ((lane >> 4) << 3) + e;
    float v = conv_w[(size_t)oc * 2304 + ic * 9 + dy * 3 + dx];
    __half h = __float2half(v);
    float rr = (v - __half2float(h)) * 1024.0f;   // scaled residual stays fp16-normal
    __half m = __float2half(rr);
    wB[t] = (pl == 0) ? h2u(h) : h2u(m);
}

// ---------------- MFMA conv3x3 (fp16x2 scaled-m split) + f64 heads/decode ----
// grid (656, 2), 512 threads = 8 waves. tile 8 rows x 16 cols = 128 px.
// Round-12: + s_setprio(1) around MFMA clusters (T5; 8-wave barrier phases give the
// role diversity setprio needs). Math order bit-identical to rounds 10/11.
__global__ __launch_bounds__(512) void conv_mfma_all(
    const float* __restrict__ f0, const float* __restrict__ f1,
    const float* __restrict__ f2, const float* __restrict__ f3,
    const float* __restrict__ f4, const ushort* __restrict__ wB,
    const float* __restrict__ conv_b,
    const float* __restrict__ cls_w, const float* __restrict__ cls_b,
    const float* __restrict__ box_w, const float* __restrict__ box_b,
    float* __restrict__ scoresA, float* __restrict__ boxesA)
{
    const int bidx = blockIdx.x;
    const int b    = blockIdx.y;
    const int tid  = threadIdx.x;

    int lvl = 0;
#pragma unroll
    for (int l = 1; l < 5; ++l) if (bidx >= dCumT[l]) lvl = l;
    const int tile   = bidx - dCumT[lvl];
    const int H      = dHc[lvl], W = dWc[lvl];
    const int TILESX = dTilesX[lvl];
    const int ty0    = (tile / TILESX) * 8;
    const int tx0    = (tile % TILESX) * 16;
    const int HW     = H * W;
    const float* feat = (lvl == 0) ? f0 : (lvl == 1) ? f1 : (lvl == 2) ? f2 : (lvl == 3) ? f3 : f4;
    const float* fb = feat + (size_t)b * 256 * HW;

    __shared__ __align__(16) char uni[72192];
    ushort* halo = (ushort*)uni;                 // [2pl][5760] u16 = 23040 B
    ushort* ldsB = (ushort*)(uni + 23040);       // [3dx][2pl][8nt][64lane][8e] = 49152 B
    float*  tS   = (float*)uni;                  // 32768 B (aliases halo+B head, conv done)
    float*  hw2  = (float*)(uni + 32768);        // 4096 B (inside B region, conv done)
    double* houtD= (double*)uni;                 // 16384 B (aliases tS, slabs done)

    const int lane = tid & 63, wave = tid >> 6;
    const int wm = wave >> 1, wn = wave & 1;
    const int g = lane >> 4, col = lane & 15;
    const int laneA = g * 1440 + col * 8;        // u16 idx, lane-constant part

    // halo staging coords (icblk-invariant): 5760 elems / 512 threads = 12 slots
    int  hdst[12]; int hoff[12]; bool hval[12];
#pragma unroll
    for (int j = 0; j < 12; ++j) {
        int e = tid + j * 512;
        hdst[j] = -1; hoff[j] = 0; hval[j] = false;
        if (e < 5760) {
            int ic = e / 180, rem = e - ic * 180;
            int hrow = rem / 18, hcol = rem - hrow * 18;
            int gy = ty0 + hrow - 1, gx = tx0 + hcol - 1;
            hdst[j] = (((ic >> 3) * 10 + hrow) * 18 + hcol) * 8 + (ic & 7);
            if (gy >= 0 && gy < H && gx >= 0 && gx < W) {
                hval[j] = true; hoff[j] = ic * HW + gy * W + gx;
            }
        }
    }

    double hacc[4] = {0,0,0,0};   // per-thread f64 head accumulators (4 heads)

    // B prefetch registers (6 x uint4 per thread = 48 KB slab at 512 threads)
    uint4 Br0, Br1, Br2, Br3, Br4, Br5;
    {
        const uint4* gq = (const uint4*)wB;
        Br0 = gq[tid];        Br1 = gq[tid + 512];
        Br2 = gq[tid + 1024]; Br3 = gq[tid + 1536];
        Br4 = gq[tid + 2048]; Br5 = gq[tid + 2560];
    }

#pragma unroll 1
    for (int ocg = 0; ocg < 2; ++ocg) {
        f32x4 accH[2][4], accM[2][4];
#pragma unroll
        for (int mi = 0; mi < 2; ++mi)
#pragma unroll
            for (int ni = 0; ni < 4; ++ni) {
                accH[mi][ni] = (f32x4){0.f, 0.f, 0.f, 0.f};
                accM[mi][ni] = (f32x4){0.f, 0.f, 0.f, 0.f};
            }

#pragma unroll 1
        for (int s = 0; s < 24; ++s) {        // step = (icblk, dy)
            const int icblk = s / 3;
            const int dy    = s - icblk * 3;

            __syncthreads();   // prior step's halo/ldsB reads (and epilogue reads) done
            // ---- stage halo at icblk start: batch-issue 12 loads, then convert+write ----
            if (dy == 0) {
                float hv[12];
                const float* fcb = fb + (size_t)icblk * 32 * HW;
#pragma unroll
                for (int j = 0; j < 12; ++j)
                    hv[j] = hval[j] ? fcb[hoff[j]] : 0.f;
#pragma unroll
                for (int j = 0; j < 12; ++j) {
                    if (hdst[j] >= 0) {
                        float v = hv[j];
                        __half h = __float2half(v);
                        float rr = (v - __half2float(h)) * 1024.0f;
                        __half m = __float2half(rr);
                        int li = hdst[j];
                        halo[li] = h2u(h); halo[5760 + li] = h2u(m);
                    }
                }
            }
            // ---- write prefetched B slab (48 KB) to LDS ----
            {
                uint4* lq = (uint4*)ldsB;
                lq[tid] = Br0;         lq[tid + 512]  = Br1;
                lq[tid + 1024] = Br2;  lq[tid + 1536] = Br3;
                lq[tid + 2048] = Br4;  lq[tid + 2560] = Br5;
            }
            __syncthreads();   // halo + B visible
            // ---- issue next slab's loads (hidden under MFMA phase) ----
            {
                int gstep = ocg * 24 + s + 1;
                if (gstep < 48) {
                    const uint4* gq = (const uint4*)(wB + (size_t)gstep * 24576);
                    Br0 = gq[tid];        Br1 = gq[tid + 512];
                    Br2 = gq[tid + 1024]; Br3 = gq[tid + 1536];
                    Br4 = gq[tid + 2048]; Br5 = gq[tid + 2560];
                }
            }
            // ---- compute: 3 dx sub-steps, 72 MFMAs per wave ----
#pragma unroll 1
            for (int dx = 0; dx < 3; ++dx) {
                f16x8 Ah[2], Am[2];
                const int abase = laneA + dx * 8 + (2 * wm + dy) * 144;
#pragma unroll
                for (int mi = 0; mi < 2; ++mi) {
                    Ah[mi] = *(const f16x8*)(halo + abase + mi * 144);
                    Am[mi] = *(const f16x8*)(halo + 5760 + abase + mi * 144);
                }
#pragma unroll
                for (int ni = 0; ni < 4; ++ni) {
                    const int nt = 4 * wn + ni;
                    f16x8 Bh = *(const f16x8*)(ldsB + (size_t)(dx * 16 + nt) * 512 + lane * 8);
                    f16x8 Bm = *(const f16x8*)(ldsB + (size_t)(dx * 16 + 8 + nt) * 512 + lane * 8);
                    __builtin_amdgcn_s_setprio(1);
#pragma unroll
                    for (int mi = 0; mi < 2; ++mi) {
                        f32x4 cH = accH[mi][ni];
                        f32x4 cM = accM[mi][ni];
                        cH = __builtin_amdgcn_mfma_f32_16x16x32_f16(Ah[mi], Bh, cH, 0, 0, 0);
                        cM = __builtin_amdgcn_mfma_f32_16x16x32_f16(Ah[mi], Bm, cM, 0, 0, 0);
                        cM = __builtin_amdgcn_mfma_f32_16x16x32_f16(Am[mi], Bh, cM, 0, 0, 0);
                        accH[mi][ni] = cH;
                        accM[mi][ni] = cM;
                    }
                    __builtin_amdgcn_s_setprio(0);
                }
            }
        }
        __syncthreads();   // all halo/ldsB reads done -> tS may overwrite
        // ---- writeout + f64 head contraction, 2 slabs of 64 oc (oc ascending) ----
        float cb[4];
#pragma unroll
        for (int ni = 0; ni < 4; ++ni)
            cb[ni] = conv_b[ocg * 128 + (4 * wn + ni) * 16 + col];

#pragma unroll 1
        for (int s2 = 0; s2 < 2; ++s2) {
            if (wn == s2) {
#pragma unroll
                for (int mi = 0; mi < 2; ++mi) {
#pragma unroll
                    for (int r = 0; r < 4; ++r) {
                        int px = (2 * wm + mi) * 16 + 4 * g + r;
                        int sw = px & 15;
#pragma unroll
                        for (int ni = 0; ni < 4; ++ni) {
                            int slot = (ni * 4 + (col >> 2)) ^ sw;
                            float val = accH[mi][ni][r] + accM[mi][ni][r] * 0.0009765625f;
                            tS[px * 64 + slot * 4 + (col & 3)] =
                                fmaxf(val + cb[ni], 0.f);
                        }
                    }
                }
            }
            // stage head weights for this 64-oc slab (threads 0..255)
            if (tid < 256) {
                const int oc2 = tid >> 2;
                const int h0  = (tid & 3) * 4;
                const int oc  = ocg * 128 + s2 * 64 + oc2;
                float vv[4];
#pragma unroll
                for (int q = 0; q < 4; ++q) {
                    int h = h0 + q;
                    vv[q] = (h < 3) ? cls_w[h * 256 + oc]
                          : (h < 15) ? box_w[(h - 3) * 256 + oc] : 0.f;
                }
                *(float4*)&hw2[oc2 * 16 + h0] = make_float4(vv[0], vv[1], vv[2], vv[3]);
            }
            __syncthreads();
            // accumulate: px = tid&127, head-quarter = tid>>7 (oc ascending within slab)
            {
                const int px = tid & 127;
                const int hh = tid >> 7;           // 0..3, heads hh*4..hh*4+3
                const int sw = px & 15;
#pragma unroll 1
                for (int j4 = 0; j4 < 16; ++j4) {
                    float4 t4 = *(const float4*)&tS[px * 64 + (j4 ^ sw) * 4];
                    float tv[4] = {t4.x, t4.y, t4.z, t4.w};
#pragma unroll
                    for (int jj = 0; jj < 4; ++jj) {
                        const float* hb = &hw2[(j4 * 4 + jj) * 16 + hh * 4];
                        float4 h0 = *(const float4*)hb;
                        double tv_d = (double)tv[jj];
                        hacc[0] += tv_d * (double)h0.x;
                        hacc[1] += tv_d * (double)h0.y;
                        hacc[2] += tv_d * (double)h0.z;
                        hacc[3] += tv_d * (double)h0.w;
                    }
                }
            }
            __syncthreads();   // slab reads done before next slab overwrites tS
        }
    }

    // ---- write head outputs to LDS (f64) ----
    {
        const int px = tid & 127;
        const int hh = tid >> 7;
#pragma unroll
        for (int j = 0; j < 4; ++j) houtD[px * 16 + hh * 4 + j] = hacc[j];
    }
    __syncthreads();

    // ---- decode + clip in f64, store f32 (unchanged from passing config) ----
    if (tid < 128) {
        const int px = tid;
        const int gy = ty0 + (px >> 4);
        const int gx = tx0 + (px & 15);
        if (gy < H && gx < W) {
            const int STRIDE = dStrideC[lvl];
            const int SZ     = dSizeC[lvl];
            const int LOFF   = dLoff[lvl];
#pragma unroll 1
            for (int a = 0; a < 3; ++a) {
                double score = houtD[px * 16 + a] + (double)cls_b[a];
                double rg0 = houtD[px * 16 + 3 + a * 4 + 0] + (double)box_b[a * 4 + 0];
                double rg1 = houtD[px * 16 + 3 + a * 4 + 1] + (double)box_b[a * 4 + 1];
                double rg2 = houtD[px * 16 + 3 + a * 4 + 2] + (double)box_b[a * 4 + 2];
                double rg3 = houtD[px * 16 + 3 + a * 4 + 3] + (double)box_b[a * 4 + 3];
                double ratio = (a == 0) ? 0.5 : ((a == 1) ? 1.0 : 2.0);
                double hr = sqrt(ratio), wr = 1.0 / hr;
                double wsd = wr * (double)SZ, hsd = hr * (double)SZ;
                double sx = (double)(gx * STRIDE), sy = (double)(gy * STRIDE);
                float ax0 = (float)(sx - 0.5 * wsd);
                float ay0 = (float)(sy - 0.5 * hsd);
                float ax1 = (float)(sx + 0.5 * wsd);
                float ay1 = (float)(sy + 0.5 * hsd);
                double wa = (double)ax1 - (double)ax0, ha = (double)ay1 - (double)ay0;
                double cxa = (double)ax0 + 0.5 * wa, cya = (double)ay0 + 0.5 * ha;
                double dwv = fmin(rg2, 4.135166556742356);
                double dhv = fmin(rg3, 4.135166556742356);
                double cx = rg0 * wa + cxa, cy = rg1 * ha + cya;
                double w = exp(dwv) * wa, h = exp(dhv) * ha;
                double x0 = cx - 0.5 * w, y0 = cy - 0.5 * h;
                double x1 = cx + 0.5 * w, y1 = cy + 0.5 * h;
                x0 = fmin(fmax(x0, 0.0), 1216.0);
                y0 = fmin(fmax(y0, 0.0), 800.0);
                x1 = fmin(fmax(x1, 0.0), 1216.0);
                y1 = fmin(fmax(y1, 0.0), 800.0);
                int gidx = LOFF + (gy * W + gx) * 3 + a;
                scoresA[(size_t)b * ATOTAL + gidx] = (float)score;
                float4 bx = make_float4((float)x0, (float)y0, (float)x1, (float)y1);
                *(float4*)&boxesA[((size_t)b * ATOTAL + gidx) * 4] = bx;
            }
        }
    }
}

// ---------------- per-(batch,level) top-k via 3-pass radix threshold (1024 thr) ----------------
// Round-12: serial tid==0 bin-scan (dependent LDS reads, ~100us) replaced by parallel
// pair-sum + 10-step suffix scan. Selection result identical (unique bin satisfies).
__global__ __launch_bounds__(1024) void topk_kernel(
    const float* __restrict__ scoresA, const float* __restrict__ boxesA,
    float* __restrict__ selScore, float* __restrict__ selBox,
    int* __restrict__ selValid, int* __restrict__ selAnchor)
{
    const int lvl = blockIdx.x, b = blockIdx.y;
    const int n = dCount[lvl], loff = dLoff[lvl], seg = dSeg[lvl], k = dSegK[lvl];
    const float* sc = scoresA + (size_t)b * ATOTAL + loff;
    const int tid = threadIdx.x;

    float* oS = selScore + b * KSEL;
    float* oB = selBox + (size_t)b * KSEL * 4;
    int* oV = selValid + b * KSEL;
    int* oA = selAnchor + b * KSEL;

    auto emit = [&](int slot, int i) {
        int g = loff + i;
        float s = sc[i];
        float4 bx = *(const float4*)&boxesA[((size_t)b * ATOTAL + g) * 4];
        oS[seg + slot] = s;
        *(float4*)&oB[(size_t)(seg + slot) * 4] = bx;
        oV[seg + slot] = ((bx.z - bx.x) >= 1e-3f && (bx.w - bx.y) >= 1e-3f) ? 1 : 0;
        oA[seg + slot] = g;
    };

    if (n <= k) {
        for (int i = tid; i < n; i += 1024) emit(i, i);
        return;
    }

    __shared__ uint hist[2048];
    __shared__ uint suf[2][1024];
    __shared__ uint sh_bin, sh_krem;
    __shared__ uint cntG, cntE;
    __shared__ int stash[64];

    uint krem = (uint)k;
    uint prefix = 0;
    for (int pass = 0; pass < 3; ++pass) {
        for (int e = tid; e < 2048; e += 1024) hist[e] = 0;
        __syncthreads();
        for (int i = tid; i < n; i += 1024) {
            uint key = fkey(sc[i]);
            uint bin; bool sel;
            if (pass == 0)      { sel = true;                      bin = key >> 21; }
            else if (pass == 1) { sel = ((key >> 21) == prefix);   bin = (key >> 10) & 0x7FFu; }
            else                { sel = ((key >> 10) == prefix);   bin = key & 0x3FFu; }
            if (sel) atomicAdd(&hist[bin], 1u);
        }
        __syncthreads();
        // ---- parallel bin selection: pair-sum + inclusive suffix scan (10 steps) ----
        {
            const int nb = (pass == 2) ? 1024 : 2048;
            uint pv = 0;
            if (2 * tid < nb)     pv += hist[2 * tid];
            if (2 * tid + 1 < nb) pv += hist[2 * tid + 1];
            suf[0][tid] = pv;
            __syncthreads();
            int src = 0;
#pragma unroll
            for (int off2 = 1; off2 < 1024; off2 <<= 1) {
                uint v = suf[src][tid] + ((tid + off2 < 1024) ? suf[src][tid + off2] : 0u);
                suf[src ^ 1][tid] = v;
                __syncthreads();
                src ^= 1;
            }
            // SUF[t] = suf[src][t] (inclusive from-top pair suffix); SUF[1024] = 0
            uint SUFt1 = (tid + 1 < 1024) ? suf[src][tid + 1] : 0u;
            uint h1 = (2 * tid + 1 < nb) ? hist[2 * tid + 1] : 0u;
            // bin 2t+1: elements above = SUFt1
            if (2 * tid + 1 < nb && SUFt1 < krem && SUFt1 + h1 >= krem) {
                sh_bin = (uint)(2 * tid + 1); sh_krem = krem - SUFt1;
            }
            // bin 2t: elements above = SUFt1 + h1
            uint S0 = SUFt1 + h1;
            if (2 * tid < nb) {
                uint h0 = hist[2 * tid];
                if (S0 < krem && S0 + h0 >= krem) {
                    sh_bin = (uint)(2 * tid); sh_krem = krem - S0;
                }
            }
        }
        __syncthreads();
        uint bin = sh_bin; krem = sh_krem;
        if (pass == 0)      prefix = bin;
        else if (pass == 1) prefix = (prefix << 11) | bin;
        else                prefix = (prefix << 10) | bin;
        __syncthreads();
    }
    const uint T = prefix;
    const uint need_eq = krem;
    if (tid == 0) { cntG = 0; cntE = 0; }
    __syncthreads();
    for (int i = tid; i < n; i += 1024) {
        uint key = fkey(sc[i]);
        if (key > T) {
            uint pos = atomicAdd(&cntG, 1u);
            emit((int)pos, i);
        } else if (key == T) {
            uint e = atomicAdd(&cntE, 1u);
            if (e < 64) stash[e] = i;
        }
    }
    __syncthreads();
    if (tid == 0) {
        uint ne = cntE < 64u ? cntE : 64u;
        uint base = cntG;   // == k - need_eq
        for (uint t2 = 0; t2 < need_eq; ++t2) {
            int best = -1, bj = -1;
            for (uint j2 = 0; j2 < ne; ++j2) {
                int v = stash[j2];
                if (v >= 0 && (best < 0 || v < best)) { best = v; bj = j2; }
            }
            if (bj >= 0) { stash[bj] = -1; emit((int)(base + t2), best); }
            else emit((int)(base + t2), 0);
        }
    }
}

// ---------------- per-batch descending sort (score, then anchor-idx asc) ----------------
__global__ __launch_bounds__(1024) void sort_kernel(
    const float* __restrict__ selScore, const float* __restrict__ selBox,
    const int* __restrict__ selValid, const int* __restrict__ selAnchor,
    int* __restrict__ sortedSlot, float* __restrict__ sortedBoxOff,
    ull* __restrict__ validMask)
{
    const int b = blockIdx.x, tid = threadIdx.x;
    __shared__ ull  skey[8192];
    __shared__ uint spay[8192];
    __shared__ ull  svm[NW];

    for (int i = tid; i < 8192; i += 1024) {
        ull kk2; uint pp;
        if (i < KSEL) {
            float s = selScore[b * KSEL + i];
            int v = selValid[b * KSEL + i];
            uint k32 = v ? fkey(s) : 0x007FFFFFu;
            uint a32 = 0xFFFFFFFFu - (uint)selAnchor[b * KSEL + i];
            kk2 = ((ull)k32 << 32) | a32; pp = (uint)i;
        } else { kk2 = 0ull; pp = 0xFFFFFFFFu; }
        skey[i] = kk2; spay[i] = pp;
    }
    __syncthreads();
    for (uint kk = 2; kk <= 8192; kk <<= 1) {
        for (uint j = kk >> 1; j > 0; j >>= 1) {
            for (int i = tid; i < 8192; i += 1024) {
                uint ixj = (uint)i ^ j;
                if (ixj > (uint)i) {
                    bool up = ((((uint)i) & kk) == 0);
                    ull a = skey[i], c = skey[ixj];
                    bool sw = up ? (a < c) : (a > c);
                    if (sw) {
                        skey[i] = c; skey[ixj] = a;
                        uint tp = spay[i]; spay[i] = spay[ixj]; spay[ixj] = tp;
                    }
                }
            }
            __syncthreads();
        }
    }
    for (int i = tid; i < NW; i += 1024) svm[i] = 0ull;
    __syncthreads();
    for (int i = tid; i < KSEL; i += 1024) {
        uint slot = spay[i];
        sortedSlot[b * KSEL + i] = (int)slot;
        int v = selValid[b * KSEL + slot];
        if (v) atomicOr(&svm[i >> 6], 1ull << (i & 63));
        int lvl = (int)slot / 1000;
        float off = 1217.0f * (float)lvl;
        float4 bx = *(const float4*)&selBox[((size_t)b * KSEL + slot) * 4];
        bx.x += off; bx.y += off; bx.z += off; bx.w += off;
        *(float4*)&sortedBoxOff[((size_t)b * KSEL + i) * 4] = bx;
    }
    __syncthreads();
    for (int i = tid; i < NW; i += 1024) validMask[b * NW + i] = svm[i];
}

// ---------------- NMS pairwise suppression bitmask (upper-triangle launch) ----------------
__global__ __launch_bounds__(64) void nms_mask(const float* __restrict__ sortedBoxOff,
                                               ull* __restrict__ mat)
{
    const int b = blockIdx.y;
    const int tid = threadIdx.x;
    // decode linear pair index -> (ib, jb) with jb >= ib
    int rem = blockIdx.x, ib = 0;
    while (rem >= NW - ib) { rem -= NW - ib; ++ib; }
    const int jb = ib + rem;

    __shared__ float4 bj[64];
    __shared__ float  aj[64];
    const int j0 = jb * 64;
    const int jn = (KSEL - j0) < 64 ? (KSEL - j0) : 64;
    if (tid < jn) {
        float4 v = *(const float4*)&sortedBoxOff[((size_t)b * KSEL + j0 + tid) * 4];
        bj[tid] = v; aj[tid] = (v.z - v.x) * (v.w - v.y);
    }
    __syncthreads();
    const int i = ib * 64 + tid;
    if (i >= KSEL) return;
    float4 bi = *(const float4*)&sortedBoxOff[((size_t)b * KSEL + i) * 4];
    float ai = (bi.z - bi.x) * (bi.w - bi.y);
    ull m = 0ull;
    for (int jj = 0; jj < jn; ++jj) {
        int j = j0 + jj;
        if (j <= i) continue;
        float4 bb = bj[jj];
        float ltx = fmaxf(bi.x, bb.x), lty = fmaxf(bi.y, bb.y);
        float rbx = fminf(bi.z, bb.z), rby = fminf(bi.w, bb.w);
        float wx = fmaxf(rbx - ltx, 0.f), wy = fmaxf(rby - lty, 0.f);
        float inter = wx * wy;
        float iou = inter / (ai + aj[jj] - inter + 1e-9f);
        if (iou > 0.7f) m |= (1ull << jj);
    }
    mat[((size_t)b * KSEL + i) * NW + jb] = m;
}

// ---------------- greedy scan (1 wave/batch, double-buffered 16-row prefetch) ----------------
// lower-triangle words (lane < i>>6) are never written by the triangular nms_mask ->
// masked to 0 at use (they were explicit zeros before; result identical).
#define LOADG(RA, RB, G) { int base0 = (G) * 16; \
    _Pragma("unroll") for (int d = 0; d < 16; ++d) { int i = base0 + d; \
        RA[d] = (i < KSEL) ? mb[(size_t)i * NW + lane] : 0ull; \
        RB[d] = (hasHi && i < KSEL) ? mb[(size_t)i * NW + 64 + lane] : 0ull; } }
#define PROCG(RA, RB, G) { int base0 = (G) * 16; \
    _Pragma("unroll") for (int d = 0; d < 16; ++d) { int i = base0 + d; \
        if (i < KSEL) { int wi = i >> 6; \
            ull act0 = v0 & ~s0, act1 = v1 & ~s1; \
            ull aw = (wi < 64) ? __shfl(act0, wi, 64) : __shfl(act1, wi - 64, 64); \
            if ((aw >> (i & 63)) & 1ull) { \
                s0 |= (lane >= wi) ? RA[d] : 0ull; \
                s1 |= (lane + 64 >= wi) ? RB[d] : 0ull; \
                if (lane == 0) keptPos[b * POST_NMS + nk] = i; \
                ++nk; \
                if (nk == POST_NMS) { if (lane == 0) nkOut[b] = nk; return; } } } } }

__global__ __launch_bounds__(64) void nms_scan(const ull* __restrict__ mat,
                                               const ull* __restrict__ validMask,
                                               int* __restrict__ keptPos,
                                               int* __restrict__ nkOut)
{
    const int b = blockIdx.x, lane = threadIdx.x;
    const bool hasHi = lane < NW - 64;
    ull v0 = validMask[b * NW + lane];
    ull v1 = hasHi ? validMask[b * NW + 64 + lane] : 0ull;
    ull s0 = 0ull, s1 = 0ull;
    int nk = 0;
    const ull* mb = mat + (size_t)b * KSEL * NW;
    const int NG = (KSEL + 15) / 16;   // 297

    ull A0[16], B0[16], A1[16], B1[16];
    LOADG(A0, B0, 0);
    for (int g = 0; g < NG; g += 2) {
        if (g + 1 < NG) LOADG(A1, B1, g + 1);
        PROCG(A0, B0, g);
        if (g + 2 < NG) LOADG(A0, B0, g + 2);
        if (g + 1 < NG) PROCG(A1, B1, g + 1);
    }
    if (lane == 0) nkOut[b] = nk;
}

// ---------------- final output ----------------
__global__ __launch_bounds__(256) void out_kernel(
    const int* __restrict__ keptPos, const int* __restrict__ nkOut,
    const int* __restrict__ sortedSlot,
    const float* __restrict__ selBox, const float* __restrict__ selScore,
    float* __restrict__ out)
{
    int t = blockIdx.x * 256 + threadIdx.x;
    if (t >= BATCH * POST_NMS) return;
    int b = t / POST_NMS, row = t - b * POST_NMS;
    float4 bx = make_float4(0.f, 0.f, 0.f, 0.f);
    float sc = -1e9f;
    if (row < nkOut[b]) {
        int i = keptPos[b * POST_NMS + row];
        int slot = sortedSlot[b * KSEL + i];
        bx = *(const float4*)&selBox[((size_t)b * KSEL + slot) * 4];
        sc = selScore[b * KSEL + slot];
    }
    *(float4*)&out[(size_t)t * 4] = bx;
    out[BATCH * POST_NMS * 4 + t] = sc;
}

// ---------------- host launch ----------------
extern "C" void kernel_launch(void* const* d_in, const int* in_sizes, int n_in,
                              void* d_out, int out_size, void* d_ws, size_t ws_size,
                              hipStream_t stream)
{
    (void)in_sizes; (void)n_in; (void)out_size; (void)ws_size;
    const float* feat[5] = {(const float*)d_in[0], (const float*)d_in[1],
                            (const float*)d_in[2], (const float*)d_in[3],
                            (const float*)d_in[4]};
    const float* conv_w = (const float*)d_in[5];
    const float* conv_b = (const float*)d_in[6];
    const float* cls_w  = (const float*)d_in[7];
    const float* cls_b  = (const float*)d_in[8];
    const float* box_w  = (const float*)d_in[9];
    const float* box_b  = (const float*)d_in[10];
    float* out = (float*)d_out;

    char* ws = (char*)d_ws;
    size_t off = 0;
    auto carve = [&](size_t bytes) -> void* {
        void* p = (void*)(ws + off);
        off += (bytes + 255) & ~(size_t)255;
        return p;
    };
    ushort* wB         = (ushort*)carve((size_t)WB_ELEMS * 2);
    float* scoresA     = (float*)carve((size_t)BATCH * ATOTAL * 4);
    float* boxesA      = (float*)carve((size_t)BATCH * ATOTAL * 16);
    float* selScore    = (float*)carve((size_t)BATCH * KSEL * 4);
    float* selBox      = (float*)carve((size_t)BATCH * KSEL * 16);
    int*   selValid    = (int*)  carve((size_t)BATCH * KSEL * 4);
    int*   selAnchor   = (int*)  carve((size_t)BATCH * KSEL * 4);
    int*   sortedSlot  = (int*)  carve((size_t)BATCH * KSEL * 4);
    float* sortedBoxOff= (float*)carve((size_t)BATCH * KSEL * 16);
    ull*   validMask   = (ull*)  carve((size_t)BATCH * NW * 8);
    ull*   mat         = (ull*)  carve((size_t)BATCH * KSEL * NW * 8);
    int*   keptPos     = (int*)  carve((size_t)BATCH * POST_NMS * 4);
    int*   nkOut       = (int*)  carve(64);

    wt_kernel<<<(WB_ELEMS + 255) / 256, 256, 0, stream>>>(conv_w, wB);

    conv_mfma_all<<<dim3(656, BATCH), 512, 0, stream>>>(
        feat[0], feat[1], feat[2], feat[3], feat[4], wB, conv_b,
        cls_w, cls_b, box_w, box_b, scoresA, boxesA);

    topk_kernel<<<dim3(5, BATCH), 1024, 0, stream>>>(scoresA, boxesA, selScore, selBox, selValid, selAnchor);
    sort_kernel<<<dim3(BATCH), 1024, 0, stream>>>(selScore, selBox, selValid, selAnchor, sortedSlot, sortedBoxOff, validMask);
    nms_mask<<<dim3(NPAIRS, BATCH), 64, 0, stream>>>(sortedBoxOff, mat);
    nms_scan<<<dim3(BATCH), 64, 0, stream>>>(mat, validMask, keptPos, nkOut);
    out_kernel<<<dim3((BATCH * POST_NMS + 255) / 256), 256, 0, stream>>>(keptPos, nkOut, sortedSlot, selBox, selScore, out);
}